// Round 7
// baseline (1557.235 us; speedup 1.0000x reference)
//
#include <hip/hip_runtime.h>

#define S 16384
#define PI_F 3.14159265358979f

struct Ptrs { const float* p[43]; };

// ---- workspace layout (float offsets) ----
enum : int {
  O_SBDC=0, O_SB1=256, O_SB2=512, O_SB3=768, O_SB4=1024, O_SB5=1280,
  O_SBWA=1536, O_SBF=1792, O_SBOA=2048,
  O_M=2304, O_C5=2816, O_NRM=3072, O_GRAM=3328, O_ATT2=7424, O_BEFF=11520,
  O_WB=16384,        // packed hi/lo bf16 weights for dil/oa convs (504 KB)
  O_PART=147456,     // gram/norm partials [256][80]
  O_A=524288,        // [4][128][S]  xd, later concat(of,ol)
  O_FIN=8912896,     // [4][256][S]  c1 | F2 | F3 | F4
  O_CC=25690112,     // [4][64][S]   c2/c3/c4, later fused; conv_dc WH/WL live here early
  O_DRE=29884416, O_DIMG=34078720,   // f (complex, SoA); XT lives here pre-FFT
  O_ERE=38273024, O_EIM=42467328,    // scratch complex; dil/oa XP lives here transiently
  O_G=46661632       // [4][64][S]   gate; later t (oa out, 32ch)
};

typedef short bfrag __attribute__((ext_vector_type(8)));   // 8 bf16 = 4 VGPR
typedef float ffrag __attribute__((ext_vector_type(4)));   // 4 fp32 acc

__device__ __forceinline__ float bf2f(unsigned short u){
  union { unsigned int i; float f; } v; v.i = ((unsigned int)u) << 16; return v.f;
}
__device__ __forceinline__ unsigned short f2bf(float f){
  unsigned int x = __float_as_uint(f);
  unsigned int r = x + 0x7fffu + ((x >> 16) & 1u);
  return (unsigned short)(r >> 16);
}

// ---------------- param prep: fold BN (eval-mode) into scale/bias ----------------
__global__ void prep_sb_kernel(Ptrs P, float* ws){
  const float r = rsqrtf(1.0f + 1e-5f);
  int bi=0, si=0, oi=0, C=0, dst=0;
  switch (blockIdx.x){
    case 0: bi=2; si=3; oi=4; C=128; dst=O_SBDC; break;
    case 1: bi=6; si=7; oi=8; C=64; dst=O_SB1; break;
    case 2: bi=10; si=11; oi=12; C=64; dst=O_SB2; break;
    case 3: bi=14; si=15; oi=16; C=64; dst=O_SB3; break;
    case 4: bi=18; si=19; oi=20; C=64; dst=O_SB4; break;
    case 5: bi=22; si=23; oi=24; C=64; dst=O_SB5; break;
    case 6: bi=28; si=29; oi=30; C=4;  dst=O_SBWA; break;
    case 7: bi=34; si=35; oi=36; C=64; dst=O_SBF; break;
    default: bi=38; si=39; oi=40; C=32; dst=O_SBOA; break;
  }
  for (int c = threadIdx.x; c < C; c += 256){
    float bb = P.p[bi][c], ss = P.p[si][c], oo = P.p[oi][c];
    float sc = ss * r;
    ws[dst + c] = sc;
    ws[dst + C + c] = bb * sc + oo;
  }
}

// ---------------- conv_dc prepacks ----------------
// Xt[b][130][130][256] bf16 NHWC, zero halo (pad=1)
__global__ __launch_bounds__(256) void xpad_kernel(const float* __restrict__ x,
    unsigned short* __restrict__ XT){
  int yy = blockIdx.x, b = blockIdx.y;
  long obase = ((long)(b*130) + yy) * (130L*256);
  int tid = threadIdx.x;
  if (yy == 0 || yy == 129){
    uint4 z; z.x=0; z.y=0; z.z=0; z.w=0;
    for (int i = tid; i < 130*256/8; i += 256)
      *(uint4*)(XT + obase + (long)i*8) = z;
    return;
  }
  __shared__ float LT[64][129];
  int y = yy - 1;
  for (int c0 = 0; c0 < 256; c0 += 64){
    for (int idx = tid; idx < 64*128; idx += 256){
      int ci = idx >> 7, xx = idx & 127;
      LT[ci][xx] = x[((long)(b*256 + c0 + ci)*128 + y)*128 + xx];
    }
    __syncthreads();
    for (int idx = tid; idx < 128*16; idx += 256){
      int xp = idx >> 4, c4 = (idx & 15)*4;
      ushort4 v;
      v.x = f2bf(LT[c4][xp]);   v.y = f2bf(LT[c4+1][xp]);
      v.z = f2bf(LT[c4+2][xp]); v.w = f2bf(LT[c4+3][xp]);
      *(ushort4*)(XT + obase + (long)(xp+1)*256 + c0 + c4) = v;
    }
    __syncthreads();
  }
  if (tid < 64){
    ushort4 z; z.x=0; z.y=0; z.z=0; z.w=0;
    *(ushort4*)(XT + obase + tid*4) = z;
    *(ushort4*)(XT + obase + 129L*256 + tid*4) = z;
  }
}

// conv_dc W split hi/lo bf16: WH/WL[sh][kc][co][ci32]
__global__ void wt_kernel(const float* __restrict__ w, unsigned short* __restrict__ WH,
    unsigned short* __restrict__ WL){
  for (int e = blockIdx.x*256 + threadIdx.x; e < 294912; e += gridDim.x*256){
    int c32 = e & 31, co = (e >> 5) & 127, kc = (e >> 12) & 7, sh = e >> 15;
    int ky = sh / 3, kx = sh - ky*3;
    int ci = kc*32 + c32;
    float v = w[((long)(co*256 + ci)*3 + ky)*3 + kx];
    unsigned short h = f2bf(v);
    WH[e] = h;
    WL[e] = f2bf(v - bf2f(h));
  }
}

// 64-cin 3x3 weights (w2/w3/w4/w_oa) -> packed [sh][kc][co][32] hi|lo at WB offsets
__global__ void wtg_kernel(Ptrs P, unsigned short* __restrict__ WB){
  const float* w; int cout; long off;
  switch (blockIdx.y){
    case 0: w = P.p[9];  cout = 64; off = 0;      break;
    case 1: w = P.p[13]; cout = 64; off = 73728;  break;
    case 2: w = P.p[17]; cout = 64; off = 147456; break;
    default: w = P.p[37]; cout = 32; off = 221184; break;
  }
  int total = 576*cout;
  unsigned short* WH = WB + off;
  unsigned short* WL = WH + total;
  for (int e = blockIdx.x*256 + threadIdx.x; e < total; e += gridDim.x*256){
    int c32 = e & 31;
    int co = (e >> 5) & (cout - 1);
    int kc = (e / (32*cout)) & 1;
    int sh = e / (64*cout);
    int ky = sh/3, kx = sh - ky*3;
    int ci = kc*32 + c32;
    float v = w[((long)(co*64 + ci)*3 + ky)*3 + kx];
    unsigned short h = f2bf(v);
    WH[e] = h;
    WL[e] = f2bf(v - bf2f(h));
  }
}

// dil/oa input prepack: NCHW fp32 (optionally sum of two) -> XP[b][TW][TW][64] bf16, halo DIL
template<int DIL>
__global__ __launch_bounds__(256) void xpad64_kernel(const float* __restrict__ in1,
    const float* __restrict__ in2, long in_bs, unsigned short* __restrict__ XP){
  constexpr int TW = 128 + 2*DIL;
  int yy = blockIdx.x, b = blockIdx.y;
  long obase = (long)(b*TW + yy) * TW * 64;
  int tid = threadIdx.x;
  if (yy < DIL || yy >= 128 + DIL){
    uint4 z; z.x=0; z.y=0; z.z=0; z.w=0;
    for (int i = tid; i < TW*8; i += 256)
      *(uint4*)(XP + obase + (long)i*8) = z;
    return;
  }
  __shared__ float LT[64][129];
  int y = yy - DIL;
  const float* p1 = in1 + (long)b*in_bs + (long)y*128;
  const float* p2 = in2 ? in2 + (long)b*in_bs + (long)y*128 : nullptr;
  for (int idx = tid; idx < 64*128; idx += 256){
    int ci = idx >> 7, xx = idx & 127;
    float v = p1[(long)ci*S + xx];
    if (p2) v += p2[(long)ci*S + xx];
    LT[ci][xx] = v;
  }
  __syncthreads();
  for (int i = tid; i < 2*DIL*16; i += 256){
    int side = i / (DIL*16);
    int r = i - side*(DIL*16);
    int xcol = side ? (128 + DIL + (r >> 4)) : (r >> 4);
    ushort4 z; z.x=0; z.y=0; z.z=0; z.w=0;
    *(ushort4*)(XP + obase + (long)xcol*64 + (r & 15)*4) = z;
  }
  for (int idx = tid; idx < 128*16; idx += 256){
    int xp = idx >> 4, c4 = (idx & 15)*4;
    ushort4 v;
    v.x = f2bf(LT[c4][xp]);   v.y = f2bf(LT[c4+1][xp]);
    v.z = f2bf(LT[c4+2][xp]); v.w = f2bf(LT[c4+3][xp]);
    *(ushort4*)(XP + obase + (long)(xp + DIL)*64 + c4) = v;
  }
}

// ---------------- unified 3x3 conv via MFMA implicit GEMM, reg-prefetch pipeline ------
// 1-D grid, XCD-aware y swizzle: y=(bid&7)*16+((bid>>3)&15), b=(bid>>7)&3, n2=bid>>9
template<int DIL, int KC, int NBLK>
__global__ __launch_bounds__(256) void conv3x3_mfma_kernel(
    const unsigned short* __restrict__ XP,
    const unsigned short* __restrict__ WH, const unsigned short* __restrict__ WL,
    const float* __restrict__ scbi, float* __restrict__ out){
  constexpr int CIN = KC*32;
  constexpr int TW = 128 + 2*DIL;
  constexpr int STEPS = 9*KC;
  constexpr int MI = (NBLK == 64) ? 4 : 2;
  __shared__ unsigned short Als[128*32];
  __shared__ unsigned short BHs[NBLK*32];
  __shared__ unsigned short BLs[NBLK*32];
  int bid = blockIdx.x;
  int y = (bid & 7)*16 + ((bid >> 3) & 15);
  int b = (bid >> 7) & 3;
  int n2 = bid >> 9;
  int nb = gridDim.x >> 9; if (nb == 0) nb = 1;
  int coutTotal = nb * NBLK;
  int tid = threadIdx.x, wv = tid >> 6, lane = tid & 63;
  int mt0 = (NBLK == 64) ? (wv & 1)*4 : wv*2;
  int nt0 = (NBLK == 64) ? (wv >> 1)*2 : 0;
  ffrag acc[MI][2];
  #pragma unroll
  for (int i = 0; i < MI; i++)
    #pragma unroll
    for (int j = 0; j < 2; j++)
      #pragma unroll
      for (int r = 0; r < 4; r++) acc[i][j][r] = 0.f;

  int pixq = tid >> 2, qq = tid & 3;
  int kq = (lane >> 4)*8, rown = lane & 15;

  uint4 A0, A1, BHr, BLr;
  {
    long abase = ((long)(b*TW + y)*TW)*CIN + qq*8;
    A0 = *(const uint4*)(XP + abase + (long)pixq*CIN);
    A1 = *(const uint4*)(XP + abase + (long)(pixq + 64)*CIN);
    long gw = (long)n2*NBLK*32;
    if (NBLK == 64 || tid < 128){
      BHr = *(const uint4*)(WH + gw + tid*8);
      BLr = *(const uint4*)(WL + gw + tid*8);
    }
  }
  for (int step = 0; step < STEPS; step++){
    __syncthreads();
    *(uint4*)&Als[tid*8]        = A0;
    *(uint4*)&Als[2048 + tid*8] = A1;
    if (NBLK == 64 || tid < 128){
      *(uint4*)&BHs[tid*8] = BHr;
      *(uint4*)&BLs[tid*8] = BLr;
    }
    __syncthreads();
    if (step + 1 < STEPS){
      int s2 = step + 1;
      int sh = s2 / KC, kc = s2 - sh*KC;
      int ky = sh / 3, kx = sh - ky*3;
      long abase = ((long)(b*TW + y + ky*DIL)*TW + kx*DIL)*CIN + kc*32 + qq*8;
      A0 = *(const uint4*)(XP + abase + (long)pixq*CIN);
      A1 = *(const uint4*)(XP + abase + (long)(pixq + 64)*CIN);
      long gw = ((long)s2*coutTotal + n2*NBLK)*32;
      if (NBLK == 64 || tid < 128){
        BHr = *(const uint4*)(WH + gw + tid*8);
        BLr = *(const uint4*)(WL + gw + tid*8);
      }
    }
    bfrag af[MI], bhf[2], blf[2];
    #pragma unroll
    for (int i = 0; i < MI; i++)
      af[i] = *(const bfrag*)&Als[((mt0 + i)*16 + rown)*32 + kq];
    #pragma unroll
    for (int j = 0; j < 2; j++){
      bhf[j] = *(const bfrag*)&BHs[((nt0 + j)*16 + rown)*32 + kq];
      blf[j] = *(const bfrag*)&BLs[((nt0 + j)*16 + rown)*32 + kq];
    }
    #pragma unroll
    for (int i = 0; i < MI; i++)
      #pragma unroll
      for (int j = 0; j < 2; j++){
        acc[i][j] = __builtin_amdgcn_mfma_f32_16x16x32_bf16(af[i], blf[j], acc[i][j], 0, 0, 0);
        acc[i][j] = __builtin_amdgcn_mfma_f32_16x16x32_bf16(af[i], bhf[j], acc[i][j], 0, 0, 0);
      }
  }
  #pragma unroll
  for (int i = 0; i < MI; i++){
    int pixel = (mt0 + i)*16 + (lane >> 4)*4;
    #pragma unroll
    for (int j = 0; j < 2; j++){
      int co = n2*NBLK + (nt0 + j)*16 + (lane & 15);
      float sc = scbi[co], bb = scbi[coutTotal + co];
      float* op = out + ((long)(b*coutTotal + co))*S + y*128 + pixel;
      #pragma unroll
      for (int r = 0; r < 4; r++)
        op[r] = fmaxf(acc[i][j][r]*sc + bb, 0.f);
    }
  }
}

// ---------------- generic 1x1 conv ----------------
template<int MODE>
__global__ __launch_bounds__(256) void conv1x1_kernel(const float* __restrict__ in, int in_bs,
    const float* __restrict__ W, int cin, int wstride, const float* __restrict__ scbi,
    const float* __restrict__ beff, const float* __restrict__ res, int res_bs,
    float* __restrict__ out, int out_bs){
  int b = blockIdx.z, cog = blockIdx.y;
  int px = blockIdx.x*1024 + (threadIdx.x & 63)*4 + (threadIdx.x >> 6)*256;
  const float* ib = in + (long)b*in_bs + px;
  float4 acc[16];
  #pragma unroll
  for (int i = 0; i < 16; i++){ acc[i].x = 0.f; acc[i].y = 0.f; acc[i].z = 0.f; acc[i].w = 0.f; }
  for (int c4 = 0; c4 < cin/4; c4++){
    float4 x0 = *(const float4*)(ib + (long)(c4*4+0)*S);
    float4 x1 = *(const float4*)(ib + (long)(c4*4+1)*S);
    float4 x2 = *(const float4*)(ib + (long)(c4*4+2)*S);
    float4 x3 = *(const float4*)(ib + (long)(c4*4+3)*S);
    const float* wr = W + (long)cog*16*wstride + c4*4;
    #pragma unroll
    for (int co = 0; co < 16; co++){
      float4 w = *(const float4*)(wr + (long)co*wstride);
      acc[co].x += w.x*x0.x + w.y*x1.x + w.z*x2.x + w.w*x3.x;
      acc[co].y += w.x*x0.y + w.y*x1.y + w.z*x2.y + w.w*x3.y;
      acc[co].z += w.x*x0.z + w.y*x1.z + w.z*x2.z + w.w*x3.z;
      acc[co].w += w.x*x0.w + w.y*x1.w + w.z*x2.w + w.w*x3.w;
    }
  }
  int cout = gridDim.y * 16;
  #pragma unroll
  for (int co = 0; co < 16; co++){
    int c = cog*16 + co;
    float4 v = acc[co];
    if (MODE == 0){
      float sc = scbi[c], bb = scbi[cout + c];
      v.x = fmaxf(v.x*sc + bb, 0.f); v.y = fmaxf(v.y*sc + bb, 0.f);
      v.z = fmaxf(v.z*sc + bb, 0.f); v.w = fmaxf(v.w*sc + bb, 0.f);
    } else if (MODE == 1){
      float4 r = *(const float4*)(res + (long)b*res_bs + (long)c*S + px);
      v.x += r.x; v.y += r.y; v.z += r.z; v.w += r.w;
    } else {
      float sc = scbi[c], bb = beff[b*64 + c];
      v.x = fmaxf(v.x*sc + bb, 0.f); v.y = fmaxf(v.y*sc + bb, 0.f);
      v.z = fmaxf(v.z*sc + bb, 0.f); v.w = fmaxf(v.w*sc + bb, 0.f);
    }
    *(float4*)(out + (long)b*out_bs + (long)c*S + px) = v;
  }
}

// ---------------- FFT-128 with hoisted lane twiddles ----------------
__device__ __forceinline__ void fft128_mk_tw(float (&tws)[8], float (&twc)[8],
                                             float sign, int lane){
  float a0 = sign * (2.0f*PI_F/128.0f) * (float)lane;
  __sincosf(a0, &tws[0], &twc[0]);
  int i = 1;
  #pragma unroll
  for (int h = 32; h >= 1; h >>= 1, i++){
    int j = lane & (h - 1);
    float a = sign * (2.0f*PI_F/128.0f) * (float)(j * (64/h));
    __sincosf(a, &tws[i], &twc[i]);
  }
}

__device__ __forceinline__ void fft128(float& z0r, float& z0i, float& z1r, float& z1i,
    const float (&tws)[8], const float (&twc)[8], int lane){
  {
    float ar = z0r, ai = z0i, br = z1r, bi = z1i;
    z0r = ar + br; z0i = ai + bi;
    float dr = ar - br, di = ai - bi;
    float s = tws[0], c = twc[0];
    z1r = dr*c - di*s; z1i = dr*s + di*c;
  }
  int idx = 1;
  #pragma unroll
  for (int h = 32; h >= 1; h >>= 1, idx++){
    float s = tws[idx], c = twc[idx];
    bool up = (lane & h) != 0;
    float pr, pi, nr, ni;
    pr = __shfl_xor(z0r, h, 64); pi = __shfl_xor(z0i, h, 64);
    if (!up){ nr = z0r + pr; ni = z0i + pi; }
    else { float dr = pr - z0r, di = pi - z0i; nr = dr*c - di*s; ni = dr*s + di*c; }
    z0r = nr; z0i = ni;
    pr = __shfl_xor(z1r, h, 64); pi = __shfl_xor(z1i, 64 == 64 ? h : h, 64); // (identical)
    if (!up){ nr = z1r + pr; ni = z1i + pi; }
    else { float dr = pr - z1r, di = pi - z1i; nr = dr*c - di*s; ni = dr*s + di*c; }
    z1r = nr; z1i = ni;
  }
}

// ---------------- fused whole-plane 2D FFT kernels (132 KB LDS, 1 block/CU) ----------
// forward fft2: real input -> DRE/DIM
__global__ __launch_bounds__(256) void fft2_fwd_kernel(const float* __restrict__ in,
    float* __restrict__ outRe, float* __restrict__ outIm){
  __shared__ float lre[128][129];
  __shared__ float lim[128][129];
  int plane = blockIdx.x;
  long pbase = (long)plane * S;
  int tid = threadIdx.x, wv = tid >> 6, lane = tid & 63;
  float tws[8], twc[8];
  fft128_mk_tw(tws, twc, -1.0f, lane);
  for (int rr = 0; rr < 32; rr++){
    int row = wv*32 + rr;
    float z0r = in[pbase + row*128 + lane], z0i = 0.f;
    float z1r = in[pbase + row*128 + lane + 64], z1i = 0.f;
    fft128(z0r, z0i, z1r, z1i, tws, twc, lane);
    int k = __brev(lane) >> 25;
    lre[row][k] = z0r;     lim[row][k] = z0i;
    lre[row][k + 1] = z1r; lim[row][k + 1] = z1i;
  }
  __syncthreads();
  for (int cc = 0; cc < 32; cc++){
    int c = wv*32 + cc;
    float z0r = lre[lane][c], z0i = lim[lane][c];
    float z1r = lre[lane + 64][c], z1i = lim[lane + 64][c];
    fft128(z0r, z0i, z1r, z1i, tws, twc, lane);
    int k = __brev(lane) >> 25;
    lre[k][c] = z0r;     lim[k][c] = z0i;
    lre[k + 1][c] = z1r; lim[k + 1][c] = z1i;
  }
  __syncthreads();
  for (int i = tid; i < S; i += 256){
    outRe[pbase + i] = lre[i >> 7][i & 127];
    outIm[pbase + i] = lim[i >> 7][i & 127];
  }
}

// ol = |ifft2(g*f)| -> A channels [64,128)
__global__ __launch_bounds__(256) void ifft2_abs_ol_kernel(const float* __restrict__ inRe,
    const float* __restrict__ inIm, const float* __restrict__ G, float* __restrict__ A){
  __shared__ float lre[128][129];
  __shared__ float lim[128][129];
  int plane = blockIdx.x;
  long pbase = (long)plane * S;
  int tid = threadIdx.x, wv = tid >> 6, lane = tid & 63;
  float tws[8], twc[8];
  fft128_mk_tw(tws, twc, 1.0f, lane);
  for (int i = tid; i < S; i += 256){
    float g = G[pbase + i];
    lre[i >> 7][i & 127] = inRe[pbase + i] * g;
    lim[i >> 7][i & 127] = inIm[pbase + i] * g;
  }
  __syncthreads();
  for (int cc = 0; cc < 32; cc++){
    int c = wv*32 + cc;
    float z0r = lre[lane][c], z0i = lim[lane][c];
    float z1r = lre[lane + 64][c], z1i = lim[lane + 64][c];
    fft128(z0r, z0i, z1r, z1i, tws, twc, lane);
    int k = __brev(lane) >> 25;
    lre[k][c] = z0r;     lim[k][c] = z0i;
    lre[k + 1][c] = z1r; lim[k + 1][c] = z1i;
  }
  __syncthreads();
  for (int rr = 0; rr < 32; rr++){
    int row = wv*32 + rr;
    float z0r = lre[row][lane], z0i = lim[row][lane];
    float z1r = lre[row][lane + 64], z1i = lim[row][lane + 64];
    fft128(z0r, z0i, z1r, z1i, tws, twc, lane);
    int k = __brev(lane) >> 25;
    lim[row][k]     = sqrtf(z0r*z0r + z0i*z0i) * (1.0f/16384.0f);
    lim[row][k + 1] = sqrtf(z1r*z1r + z1i*z1i) * (1.0f/16384.0f);
  }
  __syncthreads();
  int b = plane >> 6, ch = plane & 63;
  float* out = A + ((long)(b*128 + 64 + ch)) * S;
  for (int i = tid; i < S; i += 256)
    out[i] = lim[i >> 7][i & 127];
}

// of = |ifft_{16384}| via 4-step: col-IFFT + twiddle + row-IFFT + abs, transposed out
__global__ __launch_bounds__(256) void ifft2_abs_ofT_kernel(const float* __restrict__ inRe,
    const float* __restrict__ inIm, float* __restrict__ A){
  __shared__ float lre[128][129];
  __shared__ float lim[128][129];
  int plane = blockIdx.x;
  long pbase = (long)plane * S;
  int tid = threadIdx.x, wv = tid >> 6, lane = tid & 63;
  float tws[8], twc[8];
  fft128_mk_tw(tws, twc, 1.0f, lane);
  for (int i = tid; i < S; i += 256){
    lre[i >> 7][i & 127] = inRe[pbase + i];
    lim[i >> 7][i & 127] = inIm[pbase + i];
  }
  __syncthreads();
  for (int cc = 0; cc < 32; cc++){
    int c = wv*32 + cc;
    float z0r = lre[lane][c], z0i = lim[lane][c];
    float z1r = lre[lane + 64][c], z1i = lim[lane + 64][c];
    fft128(z0r, z0i, z1r, z1i, tws, twc, lane);
    int k = __brev(lane) >> 25;
    // 4-step twiddle: e^{+i 2pi/16384 * n2 * k}, n2 = c
    float s, co;
    float a0 = (2.0f*PI_F/16384.0f) * (float)(c * k);
    __sincosf(a0, &s, &co);
    float t = z0r*co - z0i*s; z0i = z0r*s + z0i*co; z0r = t;
    float a1 = (2.0f*PI_F/16384.0f) * (float)(c * (k + 1));
    __sincosf(a1, &s, &co);
    t = z1r*co - z1i*s; z1i = z1r*s + z1i*co; z1r = t;
    lre[k][c] = z0r;     lim[k][c] = z0i;
    lre[k + 1][c] = z1r; lim[k + 1][c] = z1i;
  }
  __syncthreads();
  // row IFFTs with register-held |.| results (LDS still input for other waves)
  float res0[32], res1[32];
  #pragma unroll
  for (int rr = 0; rr < 32; rr++){
    int row = wv*32 + rr;
    float z0r = lre[row][lane], z0i = lim[row][lane];
    float z1r = lre[row][lane + 64], z1i = lim[row][lane + 64];
    fft128(z0r, z0i, z1r, z1i, tws, twc, lane);
    res0[rr] = sqrtf(z0r*z0r + z0i*z0i) * (1.0f/16384.0f);
    res1[rr] = sqrtf(z1r*z1r + z1i*z1i) * (1.0f/16384.0f);
  }
  __syncthreads();
  int kk = __brev(lane) >> 25;
  #pragma unroll
  for (int rr = 0; rr < 32; rr++){
    int k1 = wv*32 + rr;
    lim[kk][k1]     = res0[rr];
    lim[kk + 1][k1] = res1[rr];
  }
  __syncthreads();
  int b = plane >> 6, ch = plane & 63;
  float* out = A + ((long)(b*128 + ch)) * S;
  for (int i = tid; i < S; i += 256)
    out[i] = lim[i >> 7][i & 127];
}

// ---------------- attention stats: fused norms+gram partials ----------------
__global__ __launch_bounds__(256) void gram_part_kernel(const float* __restrict__ Dre,
    const float* __restrict__ Dim, float* __restrict__ PART){
  int bh = blockIdx.x, slab = blockIdx.y;
  long base = (long)bh * 8 * S;
  int n0 = slab * 2048;
  float accr[36], acci[36], nsq[8];
  #pragma unroll
  for (int i = 0; i < 36; i++){ accr[i] = 0.f; acci[i] = 0.f; }
  #pragma unroll
  for (int i = 0; i < 8; i++) nsq[i] = 0.f;
  for (int it = 0; it < 8; it++){
    int n = n0 + it*256 + threadIdx.x;
    float xr[8], xi[8];
    #pragma unroll
    for (int c = 0; c < 8; c++){
      xr[c] = Dre[base + (long)c*S + n];
      xi[c] = Dim[base + (long)c*S + n];
      nsq[c] += xr[c]*xr[c] + xi[c]*xi[c];
    }
    int t = 0;
    #pragma unroll
    for (int c = 0; c < 8; c++)
      #pragma unroll
      for (int d = c; d < 8; d++){
        accr[t] += xr[c]*xr[d] - xi[c]*xi[d];
        acci[t] += xr[c]*xi[d] + xi[c]*xr[d];
        t++;
      }
  }
  __shared__ float red[4][80];
  int wv = threadIdx.x >> 6, lane = threadIdx.x & 63;
  #pragma unroll
  for (int i = 0; i < 80; i++){
    float v = (i < 36) ? accr[i] : (i < 72) ? acci[i - 36] : nsq[i - 72];
    #pragma unroll
    for (int o = 32; o; o >>= 1) v += __shfl_xor(v, o, 64);
    if (lane == 0) red[wv][i] = v;
  }
  __syncthreads();
  if (threadIdx.x < 80){
    int i = threadIdx.x;
    PART[(long)(bh*8 + slab)*80 + i] = red[0][i] + red[1][i] + red[2][i] + red[3][i];
  }
}

// reduce PART slabs -> SUMS[32][80]
__global__ void attred_kernel(const float* __restrict__ PART, float* __restrict__ SUMS){
  int bh = blockIdx.x, t = threadIdx.x;
  if (t >= 80) return;
  float s = 0.f;
  for (int i = 0; i < 8; i++) s += PART[(long)(bh*8 + i)*80 + t];
  SUMS[bh*80 + t] = s;
}

// attn2: one wave per bh, lane=(c,d); softmax over d in 8-lane groups; F8^{-1} via LDS
__global__ void attn2f_kernel(const float* __restrict__ SUMS,
    const float* __restrict__ temp, float* __restrict__ ATT2){
  __shared__ float sar[64], sai[64];
  int bh = blockIdx.x;
  int lane = threadIdx.x;
  int c = lane >> 3, d = lane & 7;
  const float* s = SUMS + bh*80;
  int lo = min(c, d), hi = max(c, d);
  int t2 = lo*8 - lo*(lo - 1)/2 + (hi - lo);
  float nnc = fmaxf(sqrtf(s[72 + c]), 1e-12f);
  float nnd = fmaxf(sqrtf(s[72 + d]), 1e-12f);
  float inv = temp[bh & 7] / (nnc * nnd);
  float ar = s[t2] * inv, ai = s[36 + t2] * inv;
  float m = ar;
  m = fmaxf(m, __shfl_xor(m, 1, 64)); m = fmaxf(m, __shfl_xor(m, 2, 64)); m = fmaxf(m, __shfl_xor(m, 4, 64));
  float e = __expf(ar - m);
  float su = e;
  su += __shfl_xor(su, 1, 64); su += __shfl_xor(su, 2, 64); su += __shfl_xor(su, 4, 64);
  ar = e / su;
  m = ai;
  m = fmaxf(m, __shfl_xor(m, 1, 64)); m = fmaxf(m, __shfl_xor(m, 2, 64)); m = fmaxf(m, __shfl_xor(m, 4, 64));
  e = __expf(ai - m);
  su = e;
  su += __shfl_xor(su, 1, 64); su += __shfl_xor(su, 2, 64); su += __shfl_xor(su, 4, 64);
  ai = e / su;
  sar[lane] = ar; sai[lane] = ai;
  __syncthreads();
  const float ct[8] = {1.f, 0.70710678f, 0.f, -0.70710678f, -1.f, -0.70710678f, 0.f, 0.70710678f};
  const float st[8] = {0.f, 0.70710678f, 1.f, 0.70710678f, 0.f, -0.70710678f, -1.f, -0.70710678f};
  int cp = c;
  float sr = 0.f, si = 0.f;
  #pragma unroll
  for (int cc = 0; cc < 8; cc++){
    int k = (cc * cp) & 7;
    float a = sar[cc*8 + d], b2 = sai[cc*8 + d];
    sr += ct[k]*a - st[k]*b2;
    si += ct[k]*b2 + st[k]*a;
  }
  float2 v; v.x = sr * 0.125f; v.y = si * 0.125f;
  ((float2*)ATT2)[bh*64 + lane] = v;
}

__global__ __launch_bounds__(256) void apply_attn_kernel(const float* __restrict__ Dre,
    const float* __restrict__ Dim, const float* __restrict__ ATT2,
    float* __restrict__ Ere, float* __restrict__ Eim){
  int bh = blockIdx.y;
  int px = blockIdx.x*1024 + (threadIdx.x & 63)*4 + (threadIdx.x >> 6)*256;
  long base = (long)bh * 8 * S + px;
  float4 ar[8], ai[8];
  #pragma unroll
  for (int i = 0; i < 8; i++){
    ar[i].x = ar[i].y = ar[i].z = ar[i].w = 0.f;
    ai[i].x = ai[i].y = ai[i].z = ai[i].w = 0.f;
  }
  #pragma unroll
  for (int d = 0; d < 8; d++){
    float4 xr = *(const float4*)(Dre + base + (long)d*S);
    float4 xi = *(const float4*)(Dim + base + (long)d*S);
    #pragma unroll
    for (int cp = 0; cp < 8; cp++){
      float wr = ATT2[bh*128 + (cp*8 + d)*2];
      float wi = ATT2[bh*128 + (cp*8 + d)*2 + 1];
      ar[cp].x += wr*xr.x - wi*xi.x;  ai[cp].x += wr*xi.x + wi*xr.x;
      ar[cp].y += wr*xr.y - wi*xi.y;  ai[cp].y += wr*xi.y + wi*xr.y;
      ar[cp].z += wr*xr.z - wi*xi.z;  ai[cp].z += wr*xi.z + wi*xr.z;
      ar[cp].w += wr*xr.w - wi*xi.w;  ai[cp].w += wr*xi.w + wi*xr.w;
    }
  }
  #pragma unroll
  for (int cp = 0; cp < 8; cp++){
    *(float4*)(Ere + base + (long)cp*S) = ar[cp];
    *(float4*)(Eim + base + (long)cp*S) = ai[cp];
  }
}

// gate = sigmoid(wb @ bn_relu(wa @ f.real))
__global__ __launch_bounds__(256) void gate_kernel(const float* __restrict__ Dre,
    const float* __restrict__ wa, const float* __restrict__ sbwa,
    const float* __restrict__ wb, const float* __restrict__ bwb, float* __restrict__ G){
  int b = blockIdx.y;
  int px = blockIdx.x*256 + threadIdx.x;
  long base = (long)b * 64 * S + px;
  float h0 = 0.f, h1 = 0.f, h2 = 0.f, h3 = 0.f;
  for (int ci = 0; ci < 64; ci++){
    float x = Dre[base + (long)ci*S];
    h0 += wa[ci]*x; h1 += wa[64 + ci]*x; h2 += wa[128 + ci]*x; h3 += wa[192 + ci]*x;
  }
  h0 = fmaxf(h0*sbwa[0] + sbwa[4], 0.f);
  h1 = fmaxf(h1*sbwa[1] + sbwa[5], 0.f);
  h2 = fmaxf(h2*sbwa[2] + sbwa[6], 0.f);
  h3 = fmaxf(h3*sbwa[3] + sbwa[7], 0.f);
  for (int co = 0; co < 64; co++){
    float a = bwb[co] + wb[co*4]*h0 + wb[co*4 + 1]*h1 + wb[co*4 + 2]*h2 + wb[co*4 + 3]*h3;
    G[base + (long)co*S] = 1.0f / (1.0f + __expf(-a));
  }
}

// ---------------- small kernels ----------------
__global__ __launch_bounds__(256) void mean_kernel(const float* __restrict__ A, float* __restrict__ M){
  int p = blockIdx.x;
  long base = (long)p * S;
  float s = 0.f;
  for (int n = threadIdx.x; n < S; n += 256) s += A[base + n];
  #pragma unroll
  for (int o = 32; o; o >>= 1) s += __shfl_xor(s, o, 64);
  __shared__ float sm[4];
  if ((threadIdx.x & 63) == 0) sm[threadIdx.x >> 6] = s;
  __syncthreads();
  if (threadIdx.x == 0) M[p] = (sm[0] + sm[1] + sm[2] + sm[3]) * (1.0f/16384.0f);
}

__global__ void c5_kernel(const float* __restrict__ W5, const float* __restrict__ sb5,
    const float* __restrict__ M, float* __restrict__ C5){
  int t = threadIdx.x;
  if (t >= 256) return;
  int b = t >> 6, co = t & 63;
  float s = 0.f;
  for (int ci = 0; ci < 128; ci++) s += W5[co*128 + ci] * M[b*128 + ci];
  C5[t] = fmaxf(s * sb5[co] + sb5[64 + co], 0.f);
}

__global__ void beff_kernel(const float* __restrict__ WF, const float* __restrict__ sbf,
    const float* __restrict__ C5, float* __restrict__ BEFF){
  int t = threadIdx.x;
  if (t >= 256) return;
  int b = t >> 6, co = t & 63;
  float s = 0.f;
  for (int j = 0; j < 64; j++) s += WF[co*320 + 256 + j] * C5[b*64 + j];
  BEFF[t] = s * sbf[co] + sbf[64 + co];
}

// output is FLOAT32 — write float4
__global__ __launch_bounds__(256) void ob_kernel(const float* __restrict__ Tin,
    const float* __restrict__ wob, const float* __restrict__ bob, float* __restrict__ out){
  int b = blockIdx.y;
  int px = blockIdx.x*1024 + (threadIdx.x & 63)*4 + (threadIdx.x >> 6)*256;
  float b0 = bob[0];
  float4 a; a.x = b0; a.y = b0; a.z = b0; a.w = b0;
  for (int ci = 0; ci < 32; ci++){
    float4 v = *(const float4*)(Tin + ((long)b*32 + ci)*S + px);
    float w = wob[ci];
    a.x += w*v.x; a.y += w*v.y; a.z += w*v.z; a.w += w*v.w;
  }
  *(float4*)(out + (long)b*S + px) = a;
}

// ---------------- launch ----------------
extern "C" void kernel_launch(void* const* d_in, const int* in_sizes, int n_in,
                              void* d_out, int out_size, void* d_ws, size_t ws_size,
                              hipStream_t stream){
  float* ws = (float*)d_ws;
  Ptrs P;
  for (int i = 0; i < 43 && i < n_in; i++) P.p[i] = (const float*)d_in[i];
  float* out = (float*)d_out;

  float* A   = ws + O_A;
  float* FIN = ws + O_FIN;
  float* CC  = ws + O_CC;
  float* DRE = ws + O_DRE;
  float* DIMp= ws + O_DIMG;
  float* ERE = ws + O_ERE;
  float* EIM = ws + O_EIM;
  float* G   = ws + O_G;
  float* SUMS = ws + O_GRAM;

  unsigned short* XT  = (unsigned short*)(ws + O_DRE);
  unsigned short* WHd = (unsigned short*)(ws + O_CC);
  unsigned short* WLd = (unsigned short*)(ws + O_CC + 147456);
  unsigned short* WB  = (unsigned short*)(ws + O_WB);
  unsigned short* XP  = (unsigned short*)(ws + O_ERE);

  prep_sb_kernel<<<dim3(9), dim3(256), 0, stream>>>(P, ws);
  xpad_kernel<<<dim3(130, 4), dim3(256), 0, stream>>>(P.p[0], XT);
  wt_kernel<<<dim3(128), dim3(256), 0, stream>>>(P.p[1], WHd, WLd);
  wtg_kernel<<<dim3(16, 4), dim3(256), 0, stream>>>(P, WB);

  conv3x3_mfma_kernel<1,8,64><<<dim3(1024), dim3(256), 0, stream>>>(
      XT, WHd, WLd, ws + O_SBDC, A);

  mean_kernel<<<dim3(512), dim3(256), 0, stream>>>(A, ws + O_M);
  c5_kernel<<<dim3(1), dim3(256), 0, stream>>>(P.p[21], ws + O_SB5, ws + O_M, ws + O_C5);
  beff_kernel<<<dim3(1), dim3(256), 0, stream>>>(P.p[33], ws + O_SBF, ws + O_C5, ws + O_BEFF);

  conv1x1_kernel<0><<<dim3(16, 4, 4), dim3(256), 0, stream>>>(
      A, 128*S, P.p[5], 128, 128, ws + O_SB1, nullptr, nullptr, 0, FIN, 256*S);

  for (int k = 0; k < 3; k++){
    const float* sb = ws + (k == 0 ? O_SB2 : k == 1 ? O_SB3 : O_SB4);
    const float* in2 = (k == 0) ? nullptr : FIN + (long)(64*k)*S;
    unsigned short* wh = WB + (k == 0 ? 0 : k == 1 ? 73728 : 147456);
    if (k == 0){
      xpad64_kernel<3><<<dim3(134, 4), dim3(256), 0, stream>>>(FIN, in2, 256*S, XP);
      conv3x3_mfma_kernel<3,2,64><<<dim3(512), dim3(256), 0, stream>>>(
          XP, wh, wh + 36864, sb, CC);
    } else if (k == 1){
      xpad64_kernel<5><<<dim3(138, 4), dim3(256), 0, stream>>>(FIN, in2, 256*S, XP);
      conv3x3_mfma_kernel<5,2,64><<<dim3(512), dim3(256), 0, stream>>>(
          XP, wh, wh + 36864, sb, CC);
    } else {
      xpad64_kernel<7><<<dim3(142, 4), dim3(256), 0, stream>>>(FIN, in2, 256*S, XP);
      conv3x3_mfma_kernel<7,2,64><<<dim3(512), dim3(256), 0, stream>>>(
          XP, wh, wh + 36864, sb, CC);
    }

    // f = fft2(c) — fused rows+cols per plane
    fft2_fwd_kernel<<<dim3(256), dim3(256), 0, stream>>>(CC, DRE, DIMp);
    // attention stats
    gram_part_kernel<<<dim3(32, 8), dim3(256), 0, stream>>>(DRE, DIMp, ws + O_PART);
    attred_kernel<<<dim3(32), dim3(128), 0, stream>>>(ws + O_PART, SUMS);
    attn2f_kernel<<<dim3(32), dim3(64), 0, stream>>>(SUMS, P.p[25], ws + O_ATT2);
    // gate (from f.real)
    gate_kernel<<<dim3(64, 4), dim3(256), 0, stream>>>(DRE, P.p[27], ws + O_SBWA, P.p[31], P.p[32], G);
    // ol = |ifft2(g*f)| -> A channels [64,128)  (fused)
    ifft2_abs_ol_kernel<<<dim3(256), dim3(256), 0, stream>>>(DRE, DIMp, G, A);
    // of = |ifft_{c,n}(attn @ qkv)| -> A channels [0,64)  (fused 4-step)
    apply_attn_kernel<<<dim3(16, 32), dim3(256), 0, stream>>>(DRE, DIMp, ws + O_ATT2, ERE, EIM);
    ifft2_abs_ofT_kernel<<<dim3(256), dim3(256), 0, stream>>>(ERE, EIM, A);
    // F_k = w_po @ concat(of, ol) + c
    conv1x1_kernel<1><<<dim3(16, 4, 4), dim3(256), 0, stream>>>(
        A, 128*S, P.p[26], 128, 128, nullptr, nullptr, CC, 64*S,
        FIN + (long)(64*(k + 1))*S, 256*S);
  }

  conv1x1_kernel<2><<<dim3(16, 4, 4), dim3(256), 0, stream>>>(
      FIN, 256*S, P.p[33], 256, 320, ws + O_SBF, ws + O_BEFF, nullptr, 0, CC, 64*S);
  xpad64_kernel<1><<<dim3(130, 4), dim3(256), 0, stream>>>(CC, nullptr, 64*S, XP);
  conv3x3_mfma_kernel<1,2,32><<<dim3(512), dim3(256), 0, stream>>>(
      XP, WB + 221184, WB + 221184 + 18432, ws + O_SBOA, G);
  ob_kernel<<<dim3(16, 4), dim3(256), 0, stream>>>(G, P.p[41], P.p[42], out);
}

// Round 8
// 1322.010 us; speedup vs baseline: 1.1779x; 1.1779x over previous
//
#include <hip/hip_runtime.h>

#define S 16384
#define PI_F 3.14159265358979f

struct Ptrs { const float* p[43]; };

// ---- workspace layout (float offsets) ----
enum : int {
  O_SBDC=0, O_SB1=256, O_SB2=512, O_SB3=768, O_SB4=1024, O_SB5=1280,
  O_SBWA=1536, O_SBF=1792, O_SBOA=2048,
  O_M=2304, O_C5=2816, O_NRM=3072, O_GRAM=3328, O_ATT2=7424, O_BEFF=11520,
  O_WB=16384,        // packed hi/lo bf16 weights for dil/oa convs
  O_PART=147456,     // gram/norm partials [256][80]
  O_A=524288,        // [4][128][S]  xd, later concat(of,ol)
  O_FIN=8912896,     // [4][256][S]  c1 | F2 | F3 | F4
  O_CC=25690112,     // [4][64][S]   c2/c3/c4, later fused; conv_dc WH/WL live here early
  O_DRE=29884416, O_DIMG=34078720,   // f (complex, SoA); XT lives here pre-FFT
  O_ERE=38273024, O_EIM=42467328,    // scratch complex; dil/oa XP lives here transiently
  O_G=46661632       // [4][64][S]   gate; later t (oa out, 32ch)
};

typedef short bfrag __attribute__((ext_vector_type(8)));   // 8 bf16 = 4 VGPR
typedef float ffrag __attribute__((ext_vector_type(4)));   // 4 fp32 acc

__device__ __forceinline__ float bf2f(unsigned short u){
  union { unsigned int i; float f; } v; v.i = ((unsigned int)u) << 16; return v.f;
}
__device__ __forceinline__ unsigned short f2bf(float f){
  unsigned int x = __float_as_uint(f);
  unsigned int r = x + 0x7fffu + ((x >> 16) & 1u);
  return (unsigned short)(r >> 16);
}

// ---------------- param prep: fold BN (eval-mode) into scale/bias ----------------
__global__ void prep_sb_kernel(Ptrs P, float* ws){
  const float r = rsqrtf(1.0f + 1e-5f);
  int bi=0, si=0, oi=0, C=0, dst=0;
  switch (blockIdx.x){
    case 0: bi=2; si=3; oi=4; C=128; dst=O_SBDC; break;
    case 1: bi=6; si=7; oi=8; C=64; dst=O_SB1; break;
    case 2: bi=10; si=11; oi=12; C=64; dst=O_SB2; break;
    case 3: bi=14; si=15; oi=16; C=64; dst=O_SB3; break;
    case 4: bi=18; si=19; oi=20; C=64; dst=O_SB4; break;
    case 5: bi=22; si=23; oi=24; C=64; dst=O_SB5; break;
    case 6: bi=28; si=29; oi=30; C=4;  dst=O_SBWA; break;
    case 7: bi=34; si=35; oi=36; C=64; dst=O_SBF; break;
    default: bi=38; si=39; oi=40; C=32; dst=O_SBOA; break;
  }
  for (int c = threadIdx.x; c < C; c += 256){
    float bb = P.p[bi][c], ss = P.p[si][c], oo = P.p[oi][c];
    float sc = ss * r;
    ws[dst + c] = sc;
    ws[dst + C + c] = bb * sc + oo;
  }
}

// ---------------- conv_dc prepacks ----------------
__global__ __launch_bounds__(256) void xpad_kernel(const float* __restrict__ x,
    unsigned short* __restrict__ XT){
  int yy = blockIdx.x, b = blockIdx.y;
  long obase = ((long)(b*130) + yy) * (130L*256);
  int tid = threadIdx.x;
  if (yy == 0 || yy == 129){
    uint4 z; z.x=0; z.y=0; z.z=0; z.w=0;
    for (int i = tid; i < 130*256/8; i += 256)
      *(uint4*)(XT + obase + (long)i*8) = z;
    return;
  }
  __shared__ float LT[64][129];
  int y = yy - 1;
  for (int c0 = 0; c0 < 256; c0 += 64){
    for (int idx = tid; idx < 64*128; idx += 256){
      int ci = idx >> 7, xx = idx & 127;
      LT[ci][xx] = x[((long)(b*256 + c0 + ci)*128 + y)*128 + xx];
    }
    __syncthreads();
    for (int idx = tid; idx < 128*16; idx += 256){
      int xp = idx >> 4, c4 = (idx & 15)*4;
      ushort4 v;
      v.x = f2bf(LT[c4][xp]);   v.y = f2bf(LT[c4+1][xp]);
      v.z = f2bf(LT[c4+2][xp]); v.w = f2bf(LT[c4+3][xp]);
      *(ushort4*)(XT + obase + (long)(xp+1)*256 + c0 + c4) = v;
    }
    __syncthreads();
  }
  if (tid < 64){
    ushort4 z; z.x=0; z.y=0; z.z=0; z.w=0;
    *(ushort4*)(XT + obase + tid*4) = z;
    *(ushort4*)(XT + obase + 129L*256 + tid*4) = z;
  }
}

__global__ void wt_kernel(const float* __restrict__ w, unsigned short* __restrict__ WH,
    unsigned short* __restrict__ WL){
  for (int e = blockIdx.x*256 + threadIdx.x; e < 294912; e += gridDim.x*256){
    int c32 = e & 31, co = (e >> 5) & 127, kc = (e >> 12) & 7, sh = e >> 15;
    int ky = sh / 3, kx = sh - ky*3;
    int ci = kc*32 + c32;
    float v = w[((long)(co*256 + ci)*3 + ky)*3 + kx];
    unsigned short h = f2bf(v);
    WH[e] = h;
    WL[e] = f2bf(v - bf2f(h));
  }
}

__global__ void wtg_kernel(Ptrs P, unsigned short* __restrict__ WB){
  const float* w; int cout; long off;
  switch (blockIdx.y){
    case 0: w = P.p[9];  cout = 64; off = 0;      break;
    case 1: w = P.p[13]; cout = 64; off = 73728;  break;
    case 2: w = P.p[17]; cout = 64; off = 147456; break;
    default: w = P.p[37]; cout = 32; off = 221184; break;
  }
  int total = 576*cout;
  unsigned short* WH = WB + off;
  unsigned short* WL = WH + total;
  for (int e = blockIdx.x*256 + threadIdx.x; e < total; e += gridDim.x*256){
    int c32 = e & 31;
    int co = (e >> 5) & (cout - 1);
    int kc = (e / (32*cout)) & 1;
    int sh = e / (64*cout);
    int ky = sh/3, kx = sh - ky*3;
    int ci = kc*32 + c32;
    float v = w[((long)(co*64 + ci)*3 + ky)*3 + kx];
    unsigned short h = f2bf(v);
    WH[e] = h;
    WL[e] = f2bf(v - bf2f(h));
  }
}

template<int DIL>
__global__ __launch_bounds__(256) void xpad64_kernel(const float* __restrict__ in1,
    const float* __restrict__ in2, long in_bs, unsigned short* __restrict__ XP){
  constexpr int TW = 128 + 2*DIL;
  int yy = blockIdx.x, b = blockIdx.y;
  long obase = (long)(b*TW + yy) * TW * 64;
  int tid = threadIdx.x;
  if (yy < DIL || yy >= 128 + DIL){
    uint4 z; z.x=0; z.y=0; z.z=0; z.w=0;
    for (int i = tid; i < TW*8; i += 256)
      *(uint4*)(XP + obase + (long)i*8) = z;
    return;
  }
  __shared__ float LT[64][129];
  int y = yy - DIL;
  const float* p1 = in1 + (long)b*in_bs + (long)y*128;
  const float* p2 = in2 ? in2 + (long)b*in_bs + (long)y*128 : nullptr;
  for (int idx = tid; idx < 64*128; idx += 256){
    int ci = idx >> 7, xx = idx & 127;
    float v = p1[(long)ci*S + xx];
    if (p2) v += p2[(long)ci*S + xx];
    LT[ci][xx] = v;
  }
  __syncthreads();
  for (int i = tid; i < 2*DIL*16; i += 256){
    int side = i / (DIL*16);
    int r = i - side*(DIL*16);
    int xcol = side ? (128 + DIL + (r >> 4)) : (r >> 4);
    ushort4 z; z.x=0; z.y=0; z.z=0; z.w=0;
    *(ushort4*)(XP + obase + (long)xcol*64 + (r & 15)*4) = z;
  }
  for (int idx = tid; idx < 128*16; idx += 256){
    int xp = idx >> 4, c4 = (idx & 15)*4;
    ushort4 v;
    v.x = f2bf(LT[c4][xp]);   v.y = f2bf(LT[c4+1][xp]);
    v.z = f2bf(LT[c4+2][xp]); v.w = f2bf(LT[c4+3][xp]);
    *(ushort4*)(XP + obase + (long)(xp + DIL)*64 + c4) = v;
  }
}

// ---------------- unified 3x3 conv via MFMA implicit GEMM ------
// LDS rows padded: 32 data shorts + 8 pad = 40 shorts (80 B = 20 banks) -> conflict-free
template<int DIL, int KC, int NBLK>
__global__ __launch_bounds__(256) void conv3x3_mfma_kernel(
    const unsigned short* __restrict__ XP,
    const unsigned short* __restrict__ WH, const unsigned short* __restrict__ WL,
    const float* __restrict__ scbi, float* __restrict__ out){
  constexpr int CIN = KC*32;
  constexpr int TW = 128 + 2*DIL;
  constexpr int STEPS = 9*KC;
  constexpr int MI = (NBLK == 64) ? 4 : 2;
  constexpr int LDA = 40;                 // padded row stride (shorts)
  __shared__ unsigned short Als[128*LDA];
  __shared__ unsigned short BHs[NBLK*LDA];
  __shared__ unsigned short BLs[NBLK*LDA];
  int bid = blockIdx.x;
  int y = (bid & 7)*16 + ((bid >> 3) & 15);
  int b = (bid >> 7) & 3;
  int n2 = bid >> 9;
  int nb = gridDim.x >> 9; if (nb == 0) nb = 1;
  int coutTotal = nb * NBLK;
  int tid = threadIdx.x, wv = tid >> 6, lane = tid & 63;
  int mt0 = (NBLK == 64) ? (wv & 1)*4 : wv*2;
  int nt0 = (NBLK == 64) ? (wv >> 1)*2 : 0;
  ffrag acc[MI][2];
  #pragma unroll
  for (int i = 0; i < MI; i++)
    #pragma unroll
    for (int j = 0; j < 2; j++)
      #pragma unroll
      for (int r = 0; r < 4; r++) acc[i][j][r] = 0.f;

  int pixq = tid >> 2, qq = tid & 3;
  int kq = (lane >> 4)*8, rown = lane & 15;
  int wrA0 = pixq*LDA + qq*8;
  int wrA1 = (pixq + 64)*LDA + qq*8;
  int wrB  = (tid >> 2)*LDA + qq*8;

  uint4 A0, A1, BHr, BLr;
  {
    long abase = ((long)(b*TW + y)*TW)*CIN + qq*8;
    A0 = *(const uint4*)(XP + abase + (long)pixq*CIN);
    A1 = *(const uint4*)(XP + abase + (long)(pixq + 64)*CIN);
    long gw = (long)n2*NBLK*32;
    if (NBLK == 64 || tid < 128){
      BHr = *(const uint4*)(WH + gw + tid*8);
      BLr = *(const uint4*)(WL + gw + tid*8);
    }
  }
  for (int step = 0; step < STEPS; step++){
    __syncthreads();
    *(uint4*)&Als[wrA0] = A0;
    *(uint4*)&Als[wrA1] = A1;
    if (NBLK == 64 || tid < 128){
      *(uint4*)&BHs[wrB] = BHr;
      *(uint4*)&BLs[wrB] = BLr;
    }
    __syncthreads();
    if (step + 1 < STEPS){
      int s2 = step + 1;
      int sh = s2 / KC, kc = s2 - sh*KC;
      int ky = sh / 3, kx = sh - ky*3;
      long abase = ((long)(b*TW + y + ky*DIL)*TW + kx*DIL)*CIN + kc*32 + qq*8;
      A0 = *(const uint4*)(XP + abase + (long)pixq*CIN);
      A1 = *(const uint4*)(XP + abase + (long)(pixq + 64)*CIN);
      long gw = ((long)s2*coutTotal + n2*NBLK)*32;
      if (NBLK == 64 || tid < 128){
        BHr = *(const uint4*)(WH + gw + tid*8);
        BLr = *(const uint4*)(WL + gw + tid*8);
      }
    }
    bfrag af[MI], bhf[2], blf[2];
    #pragma unroll
    for (int i = 0; i < MI; i++)
      af[i] = *(const bfrag*)&Als[((mt0 + i)*16 + rown)*LDA + kq];
    #pragma unroll
    for (int j = 0; j < 2; j++){
      bhf[j] = *(const bfrag*)&BHs[((nt0 + j)*16 + rown)*LDA + kq];
      blf[j] = *(const bfrag*)&BLs[((nt0 + j)*16 + rown)*LDA + kq];
    }
    #pragma unroll
    for (int i = 0; i < MI; i++)
      #pragma unroll
      for (int j = 0; j < 2; j++){
        acc[i][j] = __builtin_amdgcn_mfma_f32_16x16x32_bf16(af[i], blf[j], acc[i][j], 0, 0, 0);
        acc[i][j] = __builtin_amdgcn_mfma_f32_16x16x32_bf16(af[i], bhf[j], acc[i][j], 0, 0, 0);
      }
  }
  #pragma unroll
  for (int i = 0; i < MI; i++){
    int pixel = (mt0 + i)*16 + (lane >> 4)*4;
    #pragma unroll
    for (int j = 0; j < 2; j++){
      int co = n2*NBLK + (nt0 + j)*16 + (lane & 15);
      float sc = scbi[co], bb = scbi[coutTotal + co];
      float* op = out + ((long)(b*coutTotal + co))*S + y*128 + pixel;
      #pragma unroll
      for (int r = 0; r < 4; r++)
        op[r] = fmaxf(acc[i][j][r]*sc + bb, 0.f);
    }
  }
}

// ---------------- generic 1x1 conv ----------------
template<int MODE>
__global__ __launch_bounds__(256) void conv1x1_kernel(const float* __restrict__ in, int in_bs,
    const float* __restrict__ W, int cin, int wstride, const float* __restrict__ scbi,
    const float* __restrict__ beff, const float* __restrict__ res, int res_bs,
    float* __restrict__ out, int out_bs){
  int b = blockIdx.z, cog = blockIdx.y;
  int px = blockIdx.x*1024 + (threadIdx.x & 63)*4 + (threadIdx.x >> 6)*256;
  const float* ib = in + (long)b*in_bs + px;
  float4 acc[16];
  #pragma unroll
  for (int i = 0; i < 16; i++){ acc[i].x = 0.f; acc[i].y = 0.f; acc[i].z = 0.f; acc[i].w = 0.f; }
  for (int c4 = 0; c4 < cin/4; c4++){
    float4 x0 = *(const float4*)(ib + (long)(c4*4+0)*S);
    float4 x1 = *(const float4*)(ib + (long)(c4*4+1)*S);
    float4 x2 = *(const float4*)(ib + (long)(c4*4+2)*S);
    float4 x3 = *(const float4*)(ib + (long)(c4*4+3)*S);
    const float* wr = W + (long)cog*16*wstride + c4*4;
    #pragma unroll
    for (int co = 0; co < 16; co++){
      float4 w = *(const float4*)(wr + (long)co*wstride);
      acc[co].x += w.x*x0.x + w.y*x1.x + w.z*x2.x + w.w*x3.x;
      acc[co].y += w.x*x0.y + w.y*x1.y + w.z*x2.y + w.w*x3.y;
      acc[co].z += w.x*x0.z + w.y*x1.z + w.z*x2.z + w.w*x3.z;
      acc[co].w += w.x*x0.w + w.y*x1.w + w.z*x2.w + w.w*x3.w;
    }
  }
  int cout = gridDim.y * 16;
  #pragma unroll
  for (int co = 0; co < 16; co++){
    int c = cog*16 + co;
    float4 v = acc[co];
    if (MODE == 0){
      float sc = scbi[c], bb = scbi[cout + c];
      v.x = fmaxf(v.x*sc + bb, 0.f); v.y = fmaxf(v.y*sc + bb, 0.f);
      v.z = fmaxf(v.z*sc + bb, 0.f); v.w = fmaxf(v.w*sc + bb, 0.f);
    } else if (MODE == 1){
      float4 r = *(const float4*)(res + (long)b*res_bs + (long)c*S + px);
      v.x += r.x; v.y += r.y; v.z += r.z; v.w += r.w;
    } else {
      float sc = scbi[c], bb = beff[b*64 + c];
      v.x = fmaxf(v.x*sc + bb, 0.f); v.y = fmaxf(v.y*sc + bb, 0.f);
      v.z = fmaxf(v.z*sc + bb, 0.f); v.w = fmaxf(v.w*sc + bb, 0.f);
    }
    *(float4*)(out + (long)b*out_bs + (long)c*S + px) = v;
  }
}

// ---------------- FFT-128 with hoisted lane twiddles ----------------
__device__ __forceinline__ void fft128_mk_tw(float (&tws)[8], float (&twc)[8],
                                             float sign, int lane){
  float a0 = sign * (2.0f*PI_F/128.0f) * (float)lane;
  __sincosf(a0, &tws[0], &twc[0]);
  int i = 1;
  #pragma unroll
  for (int h = 32; h >= 1; h >>= 1, i++){
    int j = lane & (h - 1);
    float a = sign * (2.0f*PI_F/128.0f) * (float)(j * (64/h));
    __sincosf(a, &tws[i], &twc[i]);
  }
}

__device__ __forceinline__ void fft128(float& z0r, float& z0i, float& z1r, float& z1i,
    const float (&tws)[8], const float (&twc)[8], int lane){
  {
    float ar = z0r, ai = z0i, br = z1r, bi = z1i;
    z0r = ar + br; z0i = ai + bi;
    float dr = ar - br, di = ai - bi;
    float s = tws[0], c = twc[0];
    z1r = dr*c - di*s; z1i = dr*s + di*c;
  }
  int idx = 1;
  #pragma unroll
  for (int h = 32; h >= 1; h >>= 1, idx++){
    float s = tws[idx], c = twc[idx];
    bool up = (lane & h) != 0;
    float pr, pi, nr, ni;
    pr = __shfl_xor(z0r, h, 64); pi = __shfl_xor(z0i, h, 64);
    if (!up){ nr = z0r + pr; ni = z0i + pi; }
    else { float dr = pr - z0r, di = pi - z0i; nr = dr*c - di*s; ni = dr*s + di*c; }
    z0r = nr; z0i = ni;
    pr = __shfl_xor(z1r, h, 64); pi = __shfl_xor(z1i, h, 64);
    if (!up){ nr = z1r + pr; ni = z1i + pi; }
    else { float dr = pr - z1r, di = pi - z1i; nr = dr*c - di*s; ni = dr*s + di*c; }
    z1r = nr; z1i = ni;
  }
}

__global__ __launch_bounds__(256) void fft_rows_fwd_kernel(const float* __restrict__ in,
    float* __restrict__ outRe, float* __restrict__ outIm){
  int line = blockIdx.x*4 + (threadIdx.x >> 6);
  int lane = threadIdx.x & 63;
  float tws[8], twc[8];
  fft128_mk_tw(tws, twc, -1.0f, lane);
  long ib = (long)line * 128;
  float z0r = in[ib + lane], z0i = 0.f;
  float z1r = in[ib + lane + 64], z1i = 0.f;
  fft128(z0r, z0i, z1r, z1i, tws, twc, lane);
  int k = __brev(lane) >> 25;
  outRe[ib + k] = z0r;   outIm[ib + k] = z0i;
  outRe[ib + k + 1] = z1r; outIm[ib + k + 1] = z1i;
}

// MODE 0: fwd cols (sign -1). MODE 1: premul gate, ifft cols. MODE 2: ifft cols + 4-step twiddle.
template<int MODE>
__global__ __launch_bounds__(256) void fft_cols_kernel(const float* inRe, const float* inIm,
    float* outRe, float* outIm, const float* gate){
  __shared__ float lre[128][17];
  __shared__ float lim[128][17];
  int plane = blockIdx.y;
  int cb = blockIdx.x * 16;
  int tid = threadIdx.x;
  long pbase = (long)plane * S;
  #pragma unroll
  for (int i = 0; i < 8; i++){
    int idx = tid + i*256;
    int r = idx >> 4, c = idx & 15;
    long a = pbase + r*128 + cb + c;
    float re = inRe[a], im = inIm[a];
    if (MODE == 1){ float g = gate[a]; re *= g; im *= g; }
    lre[r][c] = re; lim[r][c] = im;
  }
  __syncthreads();
  int wv = tid >> 6, lane = tid & 63;
  const float sign = (MODE == 0) ? -1.0f : 1.0f;
  float tws[8], twc[8];
  fft128_mk_tw(tws, twc, sign, lane);
  #pragma unroll
  for (int cc = 0; cc < 4; cc++){
    int c = wv*4 + cc;
    float z0r = lre[lane][c], z0i = lim[lane][c];
    float z1r = lre[lane + 64][c], z1i = lim[lane + 64][c];
    fft128(z0r, z0i, z1r, z1i, tws, twc, lane);
    int k = __brev(lane) >> 25;
    if (MODE == 2){
      int n2 = cb + c;
      float s, co;
      float a0 = (2.0f*PI_F/16384.0f) * (float)(n2 * k);
      __sincosf(a0, &s, &co);
      float t = z0r*co - z0i*s; z0i = z0r*s + z0i*co; z0r = t;
      float a1 = (2.0f*PI_F/16384.0f) * (float)(n2 * (k + 1));
      __sincosf(a1, &s, &co);
      t = z1r*co - z1i*s; z1i = z1r*s + z1i*co; z1r = t;
    }
    lre[k][c] = z0r;     lim[k][c] = z0i;
    lre[k + 1][c] = z1r; lim[k + 1][c] = z1i;
  }
  __syncthreads();
  #pragma unroll
  for (int i = 0; i < 8; i++){
    int idx = tid + i*256;
    int r = idx >> 4, c = idx & 15;
    long a = pbase + r*128 + cb + c;
    outRe[a] = lre[r][c]; outIm[a] = lim[r][c];
  }
}

__global__ __launch_bounds__(256) void ifft_rows_abs_ol_kernel(const float* __restrict__ Ere,
    const float* __restrict__ Eim, float* __restrict__ A){
  int line = blockIdx.x*4 + (threadIdx.x >> 6);
  int lane = threadIdx.x & 63;
  float tws[8], twc[8];
  fft128_mk_tw(tws, twc, 1.0f, lane);
  int plane = line >> 7, row = line & 127;
  long ib = (long)plane*S + row*128;
  float z0r = Ere[ib + lane], z0i = Eim[ib + lane];
  float z1r = Ere[ib + lane + 64], z1i = Eim[ib + lane + 64];
  fft128(z0r, z0i, z1r, z1i, tws, twc, lane);
  int b = plane >> 6, ch = plane & 63;
  float* out = A + ((long)(b*128 + 64 + ch)) * S + row*128;
  int k = __brev(lane) >> 25;
  out[k]     = sqrtf(z0r*z0r + z0i*z0i) * (1.0f/16384.0f);
  out[k + 1] = sqrtf(z1r*z1r + z1i*z1i) * (1.0f/16384.0f);
}

__global__ __launch_bounds__(256) void ifft_rows_abs_ofT_kernel(const float* __restrict__ Ere,
    const float* __restrict__ Eim, float* __restrict__ A){
  __shared__ float T[128][17];
  int plane = blockIdx.y;       // b*64 + h*8 + c
  int r0 = blockIdx.x * 16;     // k1 base
  int wv = threadIdx.x >> 6, lane = threadIdx.x & 63;
  float tws[8], twc[8];
  fft128_mk_tw(tws, twc, 1.0f, lane);
  #pragma unroll
  for (int i = 0; i < 4; i++){
    int rl = wv*4 + i;
    int row = r0 + rl;
    long ib = (long)plane*S + row*128;
    float z0r = Ere[ib + lane], z0i = Eim[ib + lane];
    float z1r = Ere[ib + lane + 64], z1i = Eim[ib + lane + 64];
    fft128(z0r, z0i, z1r, z1i, tws, twc, lane);
    int k = __brev(lane) >> 25;
    T[k][rl]     = sqrtf(z0r*z0r + z0i*z0i) * (1.0f/16384.0f);
    T[k + 1][rl] = sqrtf(z1r*z1r + z1i*z1i) * (1.0f/16384.0f);
  }
  __syncthreads();
  int b = plane >> 6, ch = plane & 63;
  float* out = A + ((long)(b*128 + ch)) * S + r0;
  #pragma unroll
  for (int i = 0; i < 8; i++){
    int idx = threadIdx.x + i*256;
    int k2 = idx >> 4, rl = idx & 15;
    out[(long)k2*128 + rl] = T[k2][rl];
  }
}

// ---------------- attention stats: fused norms+gram partials ----------------
__global__ __launch_bounds__(256) void gram_part_kernel(const float* __restrict__ Dre,
    const float* __restrict__ Dim, float* __restrict__ PART){
  int bh = blockIdx.x, slab = blockIdx.y;
  long base = (long)bh * 8 * S;
  int n0 = slab * 2048;
  float accr[36], acci[36], nsq[8];
  #pragma unroll
  for (int i = 0; i < 36; i++){ accr[i] = 0.f; acci[i] = 0.f; }
  #pragma unroll
  for (int i = 0; i < 8; i++) nsq[i] = 0.f;
  for (int it = 0; it < 8; it++){
    int n = n0 + it*256 + threadIdx.x;
    float xr[8], xi[8];
    #pragma unroll
    for (int c = 0; c < 8; c++){
      xr[c] = Dre[base + (long)c*S + n];
      xi[c] = Dim[base + (long)c*S + n];
      nsq[c] += xr[c]*xr[c] + xi[c]*xi[c];
    }
    int t = 0;
    #pragma unroll
    for (int c = 0; c < 8; c++)
      #pragma unroll
      for (int d = c; d < 8; d++){
        accr[t] += xr[c]*xr[d] - xi[c]*xi[d];
        acci[t] += xr[c]*xi[d] + xi[c]*xr[d];
        t++;
      }
  }
  __shared__ float red[4][80];
  int wv = threadIdx.x >> 6, lane = threadIdx.x & 63;
  #pragma unroll
  for (int i = 0; i < 80; i++){
    float v = (i < 36) ? accr[i] : (i < 72) ? acci[i - 36] : nsq[i - 72];
    #pragma unroll
    for (int o = 32; o; o >>= 1) v += __shfl_xor(v, o, 64);
    if (lane == 0) red[wv][i] = v;
  }
  __syncthreads();
  if (threadIdx.x < 80){
    int i = threadIdx.x;
    PART[(long)(bh*8 + slab)*80 + i] = red[0][i] + red[1][i] + red[2][i] + red[3][i];
  }
}

__global__ void attred_kernel(const float* __restrict__ PART, float* __restrict__ SUMS){
  int bh = blockIdx.x, t = threadIdx.x;
  if (t >= 80) return;
  float s = 0.f;
  for (int i = 0; i < 8; i++) s += PART[(long)(bh*8 + i)*80 + t];
  SUMS[bh*80 + t] = s;
}

__global__ void attn2f_kernel(const float* __restrict__ SUMS,
    const float* __restrict__ temp, float* __restrict__ ATT2){
  __shared__ float sar[64], sai[64];
  int bh = blockIdx.x;
  int lane = threadIdx.x;
  int c = lane >> 3, d = lane & 7;
  const float* s = SUMS + bh*80;
  int lo = min(c, d), hi = max(c, d);
  int t2 = lo*8 - lo*(lo - 1)/2 + (hi - lo);
  float nnc = fmaxf(sqrtf(s[72 + c]), 1e-12f);
  float nnd = fmaxf(sqrtf(s[72 + d]), 1e-12f);
  float inv = temp[bh & 7] / (nnc * nnd);
  float ar = s[t2] * inv, ai = s[36 + t2] * inv;
  float m = ar;
  m = fmaxf(m, __shfl_xor(m, 1, 64)); m = fmaxf(m, __shfl_xor(m, 2, 64)); m = fmaxf(m, __shfl_xor(m, 4, 64));
  float e = __expf(ar - m);
  float su = e;
  su += __shfl_xor(su, 1, 64); su += __shfl_xor(su, 2, 64); su += __shfl_xor(su, 4, 64);
  ar = e / su;
  m = ai;
  m = fmaxf(m, __shfl_xor(m, 1, 64)); m = fmaxf(m, __shfl_xor(m, 2, 64)); m = fmaxf(m, __shfl_xor(m, 4, 64));
  e = __expf(ai - m);
  su = e;
  su += __shfl_xor(su, 1, 64); su += __shfl_xor(su, 2, 64); su += __shfl_xor(su, 4, 64);
  ai = e / su;
  sar[lane] = ar; sai[lane] = ai;
  __syncthreads();
  const float ct[8] = {1.f, 0.70710678f, 0.f, -0.70710678f, -1.f, -0.70710678f, 0.f, 0.70710678f};
  const float st[8] = {0.f, 0.70710678f, 1.f, 0.70710678f, 0.f, -0.70710678f, -1.f, -0.70710678f};
  int cp = c;
  float sr = 0.f, si = 0.f;
  #pragma unroll
  for (int cc = 0; cc < 8; cc++){
    int k = (cc * cp) & 7;
    float a = sar[cc*8 + d], b2 = sai[cc*8 + d];
    sr += ct[k]*a - st[k]*b2;
    si += ct[k]*b2 + st[k]*a;
  }
  float2 v; v.x = sr * 0.125f; v.y = si * 0.125f;
  ((float2*)ATT2)[bh*64 + lane] = v;
}

__global__ __launch_bounds__(256) void apply_attn_kernel(const float* __restrict__ Dre,
    const float* __restrict__ Dim, const float* __restrict__ ATT2,
    float* __restrict__ Ere, float* __restrict__ Eim){
  int bh = blockIdx.y;
  int px = blockIdx.x*1024 + (threadIdx.x & 63)*4 + (threadIdx.x >> 6)*256;
  long base = (long)bh * 8 * S + px;
  float4 ar[8], ai[8];
  #pragma unroll
  for (int i = 0; i < 8; i++){
    ar[i].x = ar[i].y = ar[i].z = ar[i].w = 0.f;
    ai[i].x = ai[i].y = ai[i].z = ai[i].w = 0.f;
  }
  #pragma unroll
  for (int d = 0; d < 8; d++){
    float4 xr = *(const float4*)(Dre + base + (long)d*S);
    float4 xi = *(const float4*)(Dim + base + (long)d*S);
    #pragma unroll
    for (int cp = 0; cp < 8; cp++){
      float wr = ATT2[bh*128 + (cp*8 + d)*2];
      float wi = ATT2[bh*128 + (cp*8 + d)*2 + 1];
      ar[cp].x += wr*xr.x - wi*xi.x;  ai[cp].x += wr*xi.x + wi*xr.x;
      ar[cp].y += wr*xr.y - wi*xi.y;  ai[cp].y += wr*xi.y + wi*xr.y;
      ar[cp].z += wr*xr.z - wi*xi.z;  ai[cp].z += wr*xi.z + wi*xr.z;
      ar[cp].w += wr*xr.w - wi*xi.w;  ai[cp].w += wr*xi.w + wi*xr.w;
    }
  }
  #pragma unroll
  for (int cp = 0; cp < 8; cp++){
    *(float4*)(Ere + base + (long)cp*S) = ar[cp];
    *(float4*)(Eim + base + (long)cp*S) = ai[cp];
  }
}

// gate = sigmoid(wb @ bn_relu(wa @ f.real))
__global__ __launch_bounds__(256) void gate_kernel(const float* __restrict__ Dre,
    const float* __restrict__ wa, const float* __restrict__ sbwa,
    const float* __restrict__ wb, const float* __restrict__ bwb, float* __restrict__ G){
  int b = blockIdx.y;
  int px = blockIdx.x*256 + threadIdx.x;
  long base = (long)b * 64 * S + px;
  float h0 = 0.f, h1 = 0.f, h2 = 0.f, h3 = 0.f;
  for (int ci = 0; ci < 64; ci++){
    float x = Dre[base + (long)ci*S];
    h0 += wa[ci]*x; h1 += wa[64 + ci]*x; h2 += wa[128 + ci]*x; h3 += wa[192 + ci]*x;
  }
  h0 = fmaxf(h0*sbwa[0] + sbwa[4], 0.f);
  h1 = fmaxf(h1*sbwa[1] + sbwa[5], 0.f);
  h2 = fmaxf(h2*sbwa[2] + sbwa[6], 0.f);
  h3 = fmaxf(h3*sbwa[3] + sbwa[7], 0.f);
  for (int co = 0; co < 64; co++){
    float a = bwb[co] + wb[co*4]*h0 + wb[co*4 + 1]*h1 + wb[co*4 + 2]*h2 + wb[co*4 + 3]*h3;
    G[base + (long)co*S] = 1.0f / (1.0f + __expf(-a));
  }
}

// ---------------- small kernels ----------------
__global__ __launch_bounds__(256) void mean_kernel(const float* __restrict__ A, float* __restrict__ M){
  int p = blockIdx.x;
  long base = (long)p * S;
  float s = 0.f;
  for (int n = threadIdx.x; n < S; n += 256) s += A[base + n];
  #pragma unroll
  for (int o = 32; o; o >>= 1) s += __shfl_xor(s, o, 64);
  __shared__ float sm[4];
  if ((threadIdx.x & 63) == 0) sm[threadIdx.x >> 6] = s;
  __syncthreads();
  if (threadIdx.x == 0) M[p] = (sm[0] + sm[1] + sm[2] + sm[3]) * (1.0f/16384.0f);
}

__global__ void c5_kernel(const float* __restrict__ W5, const float* __restrict__ sb5,
    const float* __restrict__ M, float* __restrict__ C5){
  int t = threadIdx.x;
  if (t >= 256) return;
  int b = t >> 6, co = t & 63;
  float s = 0.f;
  for (int ci = 0; ci < 128; ci++) s += W5[co*128 + ci] * M[b*128 + ci];
  C5[t] = fmaxf(s * sb5[co] + sb5[64 + co], 0.f);
}

__global__ void beff_kernel(const float* __restrict__ WF, const float* __restrict__ sbf,
    const float* __restrict__ C5, float* __restrict__ BEFF){
  int t = threadIdx.x;
  if (t >= 256) return;
  int b = t >> 6, co = t & 63;
  float s = 0.f;
  for (int j = 0; j < 64; j++) s += WF[co*320 + 256 + j] * C5[b*64 + j];
  BEFF[t] = s * sbf[co] + sbf[64 + co];
}

// output is FLOAT32 — write float4
__global__ __launch_bounds__(256) void ob_kernel(const float* __restrict__ Tin,
    const float* __restrict__ wob, const float* __restrict__ bob, float* __restrict__ out){
  int b = blockIdx.y;
  int px = blockIdx.x*1024 + (threadIdx.x & 63)*4 + (threadIdx.x >> 6)*256;
  float b0 = bob[0];
  float4 a; a.x = b0; a.y = b0; a.z = b0; a.w = b0;
  for (int ci = 0; ci < 32; ci++){
    float4 v = *(const float4*)(Tin + ((long)b*32 + ci)*S + px);
    float w = wob[ci];
    a.x += w*v.x; a.y += w*v.y; a.z += w*v.z; a.w += w*v.w;
  }
  *(float4*)(out + (long)b*S + px) = a;
}

// ---------------- launch ----------------
extern "C" void kernel_launch(void* const* d_in, const int* in_sizes, int n_in,
                              void* d_out, int out_size, void* d_ws, size_t ws_size,
                              hipStream_t stream){
  float* ws = (float*)d_ws;
  Ptrs P;
  for (int i = 0; i < 43 && i < n_in; i++) P.p[i] = (const float*)d_in[i];
  float* out = (float*)d_out;

  float* A   = ws + O_A;
  float* FIN = ws + O_FIN;
  float* CC  = ws + O_CC;
  float* DRE = ws + O_DRE;
  float* DIMp= ws + O_DIMG;
  float* ERE = ws + O_ERE;
  float* EIM = ws + O_EIM;
  float* G   = ws + O_G;
  float* SUMS = ws + O_GRAM;

  unsigned short* XT  = (unsigned short*)(ws + O_DRE);
  unsigned short* WHd = (unsigned short*)(ws + O_CC);
  unsigned short* WLd = (unsigned short*)(ws + O_CC + 147456);
  unsigned short* WB  = (unsigned short*)(ws + O_WB);
  unsigned short* XP  = (unsigned short*)(ws + O_ERE);

  prep_sb_kernel<<<dim3(9), dim3(256), 0, stream>>>(P, ws);
  xpad_kernel<<<dim3(130, 4), dim3(256), 0, stream>>>(P.p[0], XT);
  wt_kernel<<<dim3(128), dim3(256), 0, stream>>>(P.p[1], WHd, WLd);
  wtg_kernel<<<dim3(16, 4), dim3(256), 0, stream>>>(P, WB);

  conv3x3_mfma_kernel<1,8,64><<<dim3(1024), dim3(256), 0, stream>>>(
      XT, WHd, WLd, ws + O_SBDC, A);

  mean_kernel<<<dim3(512), dim3(256), 0, stream>>>(A, ws + O_M);
  c5_kernel<<<dim3(1), dim3(256), 0, stream>>>(P.p[21], ws + O_SB5, ws + O_M, ws + O_C5);
  beff_kernel<<<dim3(1), dim3(256), 0, stream>>>(P.p[33], ws + O_SBF, ws + O_C5, ws + O_BEFF);

  conv1x1_kernel<0><<<dim3(16, 4, 4), dim3(256), 0, stream>>>(
      A, 128*S, P.p[5], 128, 128, ws + O_SB1, nullptr, nullptr, 0, FIN, 256*S);

  for (int k = 0; k < 3; k++){
    const float* sb = ws + (k == 0 ? O_SB2 : k == 1 ? O_SB3 : O_SB4);
    const float* in2 = (k == 0) ? nullptr : FIN + (long)(64*k)*S;
    unsigned short* wh = WB + (k == 0 ? 0 : k == 1 ? 73728 : 147456);
    if (k == 0){
      xpad64_kernel<3><<<dim3(134, 4), dim3(256), 0, stream>>>(FIN, in2, 256*S, XP);
      conv3x3_mfma_kernel<3,2,64><<<dim3(512), dim3(256), 0, stream>>>(
          XP, wh, wh + 36864, sb, CC);
    } else if (k == 1){
      xpad64_kernel<5><<<dim3(138, 4), dim3(256), 0, stream>>>(FIN, in2, 256*S, XP);
      conv3x3_mfma_kernel<5,2,64><<<dim3(512), dim3(256), 0, stream>>>(
          XP, wh, wh + 36864, sb, CC);
    } else {
      xpad64_kernel<7><<<dim3(142, 4), dim3(256), 0, stream>>>(FIN, in2, 256*S, XP);
      conv3x3_mfma_kernel<7,2,64><<<dim3(512), dim3(256), 0, stream>>>(
          XP, wh, wh + 36864, sb, CC);
    }

    // f = fft2(c)
    fft_rows_fwd_kernel<<<dim3(8192), dim3(256), 0, stream>>>(CC, DRE, DIMp);
    fft_cols_kernel<0><<<dim3(8, 256), dim3(256), 0, stream>>>(DRE, DIMp, DRE, DIMp, nullptr);
    // attention stats
    gram_part_kernel<<<dim3(32, 8), dim3(256), 0, stream>>>(DRE, DIMp, ws + O_PART);
    attred_kernel<<<dim3(32), dim3(128), 0, stream>>>(ws + O_PART, SUMS);
    attn2f_kernel<<<dim3(32), dim3(64), 0, stream>>>(SUMS, P.p[25], ws + O_ATT2);
    // gate (from f.real)
    gate_kernel<<<dim3(64, 4), dim3(256), 0, stream>>>(DRE, P.p[27], ws + O_SBWA, P.p[31], P.p[32], G);
    // ol = |ifft2(g*f)| -> A channels [64,128)
    fft_cols_kernel<1><<<dim3(8, 256), dim3(256), 0, stream>>>(DRE, DIMp, ERE, EIM, G);
    ifft_rows_abs_ol_kernel<<<dim3(8192), dim3(256), 0, stream>>>(ERE, EIM, A);
    // of = |ifft_{c,n}(attn @ qkv)| -> A channels [0,64)
    apply_attn_kernel<<<dim3(16, 32), dim3(256), 0, stream>>>(DRE, DIMp, ws + O_ATT2, ERE, EIM);
    fft_cols_kernel<2><<<dim3(8, 256), dim3(256), 0, stream>>>(ERE, EIM, ERE, EIM, nullptr);
    ifft_rows_abs_ofT_kernel<<<dim3(8, 256), dim3(256), 0, stream>>>(ERE, EIM, A);
    // F_k = w_po @ concat(of, ol) + c
    conv1x1_kernel<1><<<dim3(16, 4, 4), dim3(256), 0, stream>>>(
        A, 128*S, P.p[26], 128, 128, nullptr, nullptr, CC, 64*S,
        FIN + (long)(64*(k + 1))*S, 256*S);
  }

  conv1x1_kernel<2><<<dim3(16, 4, 4), dim3(256), 0, stream>>>(
      FIN, 256*S, P.p[33], 256, 320, ws + O_SBF, ws + O_BEFF, nullptr, 0, CC, 64*S);
  xpad64_kernel<1><<<dim3(130, 4), dim3(256), 0, stream>>>(CC, nullptr, 64*S, XP);
  conv3x3_mfma_kernel<1,2,32><<<dim3(512), dim3(256), 0, stream>>>(
      XP, WB + 221184, WB + 221184 + 18432, ws + O_SBOA, G);
  ob_kernel<<<dim3(16, 4), dim3(256), 0, stream>>>(G, P.p[41], P.p[42], out);
}

// Round 9
// 1179.223 us; speedup vs baseline: 1.3206x; 1.1211x over previous
//
#include <hip/hip_runtime.h>

#define S 16384
#define PI_F 3.14159265358979f

struct Ptrs { const float* p[43]; };

// ---- workspace layout (float offsets) ----
enum : int {
  O_SBDC=0, O_SB1=256, O_SB2=512, O_SB3=768, O_SB4=1024, O_SB5=1280,
  O_SBWA=1536, O_SBF=1792, O_SBOA=2048,
  O_M=2304, O_C5=2816, O_NRM=3072, O_GRAM=3328, O_ATT2=7424, O_BEFF=11520,
  O_WB=16384,        // packed hi/lo bf16 weights for dil/oa convs
  O_PART=147456,     // gram/norm partials [256][80]
  O_H=180224,        // gate hidden H[4][4][S] (1 MB)
  O_A=524288,        // [4][128][S]  xd, later concat(of,ol)
  O_FIN=8912896,     // [4][256][S]  c1 | F2 | F3 | F4
  O_CC=25690112,     // [4][64][S]   c2/c3/c4, later fused; conv_dc WH/WL live here early
  O_DRE=29884416, O_DIMG=34078720,   // f (complex, SoA); XT lives here pre-FFT
  O_ERE=38273024, O_EIM=42467328,    // scratch complex; dil/oa XP lives here transiently
  O_G=46661632       // [4][64][S]   later t (oa out, 32ch)
};

typedef short bfrag __attribute__((ext_vector_type(8)));   // 8 bf16 = 4 VGPR
typedef float ffrag __attribute__((ext_vector_type(4)));   // 4 fp32 acc

__device__ __forceinline__ float bf2f(unsigned short u){
  union { unsigned int i; float f; } v; v.i = ((unsigned int)u) << 16; return v.f;
}
__device__ __forceinline__ unsigned short f2bf(float f){
  unsigned int x = __float_as_uint(f);
  unsigned int r = x + 0x7fffu + ((x >> 16) & 1u);
  return (unsigned short)(r >> 16);
}

// ---------------- param prep: fold BN (eval-mode) into scale/bias ----------------
__global__ void prep_sb_kernel(Ptrs P, float* ws){
  const float r = rsqrtf(1.0f + 1e-5f);
  int bi=0, si=0, oi=0, C=0, dst=0;
  switch (blockIdx.x){
    case 0: bi=2; si=3; oi=4; C=128; dst=O_SBDC; break;
    case 1: bi=6; si=7; oi=8; C=64; dst=O_SB1; break;
    case 2: bi=10; si=11; oi=12; C=64; dst=O_SB2; break;
    case 3: bi=14; si=15; oi=16; C=64; dst=O_SB3; break;
    case 4: bi=18; si=19; oi=20; C=64; dst=O_SB4; break;
    case 5: bi=22; si=23; oi=24; C=64; dst=O_SB5; break;
    case 6: bi=28; si=29; oi=30; C=4;  dst=O_SBWA; break;
    case 7: bi=34; si=35; oi=36; C=64; dst=O_SBF; break;
    default: bi=38; si=39; oi=40; C=32; dst=O_SBOA; break;
  }
  for (int c = threadIdx.x; c < C; c += 256){
    float bb = P.p[bi][c], ss = P.p[si][c], oo = P.p[oi][c];
    float sc = ss * r;
    ws[dst + c] = sc;
    ws[dst + C + c] = bb * sc + oo;
  }
}

// ---------------- conv_dc prepacks ----------------
__global__ __launch_bounds__(256) void xpad_kernel(const float* __restrict__ x,
    unsigned short* __restrict__ XT){
  int yy = blockIdx.x, b = blockIdx.y;
  long obase = ((long)(b*130) + yy) * (130L*256);
  int tid = threadIdx.x;
  if (yy == 0 || yy == 129){
    uint4 z; z.x=0; z.y=0; z.z=0; z.w=0;
    for (int i = tid; i < 130*256/8; i += 256)
      *(uint4*)(XT + obase + (long)i*8) = z;
    return;
  }
  __shared__ float LT[64][129];
  int y = yy - 1;
  for (int c0 = 0; c0 < 256; c0 += 64){
    for (int idx = tid; idx < 64*128; idx += 256){
      int ci = idx >> 7, xx = idx & 127;
      LT[ci][xx] = x[((long)(b*256 + c0 + ci)*128 + y)*128 + xx];
    }
    __syncthreads();
    for (int idx = tid; idx < 128*16; idx += 256){
      int xp = idx >> 4, c4 = (idx & 15)*4;
      ushort4 v;
      v.x = f2bf(LT[c4][xp]);   v.y = f2bf(LT[c4+1][xp]);
      v.z = f2bf(LT[c4+2][xp]); v.w = f2bf(LT[c4+3][xp]);
      *(ushort4*)(XT + obase + (long)(xp+1)*256 + c0 + c4) = v;
    }
    __syncthreads();
  }
  if (tid < 64){
    ushort4 z; z.x=0; z.y=0; z.z=0; z.w=0;
    *(ushort4*)(XT + obase + tid*4) = z;
    *(ushort4*)(XT + obase + 129L*256 + tid*4) = z;
  }
}

__global__ void wt_kernel(const float* __restrict__ w, unsigned short* __restrict__ WH,
    unsigned short* __restrict__ WL){
  for (int e = blockIdx.x*256 + threadIdx.x; e < 294912; e += gridDim.x*256){
    int c32 = e & 31, co = (e >> 5) & 127, kc = (e >> 12) & 7, sh = e >> 15;
    int ky = sh / 3, kx = sh - ky*3;
    int ci = kc*32 + c32;
    float v = w[((long)(co*256 + ci)*3 + ky)*3 + kx];
    unsigned short h = f2bf(v);
    WH[e] = h;
    WL[e] = f2bf(v - bf2f(h));
  }
}

__global__ void wtg_kernel(Ptrs P, unsigned short* __restrict__ WB){
  const float* w; int cout; long off;
  switch (blockIdx.y){
    case 0: w = P.p[9];  cout = 64; off = 0;      break;
    case 1: w = P.p[13]; cout = 64; off = 73728;  break;
    case 2: w = P.p[17]; cout = 64; off = 147456; break;
    default: w = P.p[37]; cout = 32; off = 221184; break;
  }
  int total = 576*cout;
  unsigned short* WH = WB + off;
  unsigned short* WL = WH + total;
  for (int e = blockIdx.x*256 + threadIdx.x; e < total; e += gridDim.x*256){
    int c32 = e & 31;
    int co = (e >> 5) & (cout - 1);
    int kc = (e / (32*cout)) & 1;
    int sh = e / (64*cout);
    int ky = sh/3, kx = sh - ky*3;
    int ci = kc*32 + c32;
    float v = w[((long)(co*64 + ci)*3 + ky)*3 + kx];
    unsigned short h = f2bf(v);
    WH[e] = h;
    WL[e] = f2bf(v - bf2f(h));
  }
}

template<int DIL>
__global__ __launch_bounds__(256) void xpad64_kernel(const float* __restrict__ in1,
    const float* __restrict__ in2, long in_bs, unsigned short* __restrict__ XP){
  constexpr int TW = 128 + 2*DIL;
  int yy = blockIdx.x, b = blockIdx.y;
  long obase = (long)(b*TW + yy) * TW * 64;
  int tid = threadIdx.x;
  if (yy < DIL || yy >= 128 + DIL){
    uint4 z; z.x=0; z.y=0; z.z=0; z.w=0;
    for (int i = tid; i < TW*8; i += 256)
      *(uint4*)(XP + obase + (long)i*8) = z;
    return;
  }
  __shared__ float LT[64][129];
  int y = yy - DIL;
  const float* p1 = in1 + (long)b*in_bs + (long)y*128;
  const float* p2 = in2 ? in2 + (long)b*in_bs + (long)y*128 : nullptr;
  for (int idx = tid; idx < 64*128; idx += 256){
    int ci = idx >> 7, xx = idx & 127;
    float v = p1[(long)ci*S + xx];
    if (p2) v += p2[(long)ci*S + xx];
    LT[ci][xx] = v;
  }
  __syncthreads();
  for (int i = tid; i < 2*DIL*16; i += 256){
    int side = i / (DIL*16);
    int r = i - side*(DIL*16);
    int xcol = side ? (128 + DIL + (r >> 4)) : (r >> 4);
    ushort4 z; z.x=0; z.y=0; z.z=0; z.w=0;
    *(ushort4*)(XP + obase + (long)xcol*64 + (r & 15)*4) = z;
  }
  for (int idx = tid; idx < 128*16; idx += 256){
    int xp = idx >> 4, c4 = (idx & 15)*4;
    ushort4 v;
    v.x = f2bf(LT[c4][xp]);   v.y = f2bf(LT[c4+1][xp]);
    v.z = f2bf(LT[c4+2][xp]); v.w = f2bf(LT[c4+3][xp]);
    *(ushort4*)(XP + obase + (long)(xp + DIL)*64 + c4) = v;
  }
}

// ---------------- unified 3x3 conv via MFMA implicit GEMM ------
// LDA = 36 shorts (72 B = 18 banks): both the staging-write phase pattern
// ((t>>2)*18+(t&3)*4 mod 32) and the frag-read phase pattern (r*18 mod 32)
// are distinct within every 16-lane phase -> ~conflict-free.
template<int DIL, int KC, int NBLK>
__global__ __launch_bounds__(256) void conv3x3_mfma_kernel(
    const unsigned short* __restrict__ XP,
    const unsigned short* __restrict__ WH, const unsigned short* __restrict__ WL,
    const float* __restrict__ scbi, float* __restrict__ out){
  constexpr int CIN = KC*32;
  constexpr int TW = 128 + 2*DIL;
  constexpr int STEPS = 9*KC;
  constexpr int MI = (NBLK == 64) ? 4 : 2;
  constexpr int LDA = 36;
  __shared__ unsigned short Als[128*LDA];
  __shared__ unsigned short BHs[NBLK*LDA];
  __shared__ unsigned short BLs[NBLK*LDA];
  int bid = blockIdx.x;
  int y = (bid & 7)*16 + ((bid >> 3) & 15);
  int b = (bid >> 7) & 3;
  int n2 = bid >> 9;
  int nb = gridDim.x >> 9; if (nb == 0) nb = 1;
  int coutTotal = nb * NBLK;
  int tid = threadIdx.x, wv = tid >> 6, lane = tid & 63;
  int mt0 = (NBLK == 64) ? (wv & 1)*4 : wv*2;
  int nt0 = (NBLK == 64) ? (wv >> 1)*2 : 0;
  ffrag acc[MI][2];
  #pragma unroll
  for (int i = 0; i < MI; i++)
    #pragma unroll
    for (int j = 0; j < 2; j++)
      #pragma unroll
      for (int r = 0; r < 4; r++) acc[i][j][r] = 0.f;

  int pixq = tid >> 2, qq = tid & 3;
  int kq = (lane >> 4)*8, rown = lane & 15;
  int wrA0 = pixq*LDA + qq*8;
  int wrA1 = (pixq + 64)*LDA + qq*8;
  int wrB  = (tid >> 2)*LDA + qq*8;

  uint4 A0, A1, BHr, BLr;
  {
    long abase = ((long)(b*TW + y)*TW)*CIN + qq*8;
    A0 = *(const uint4*)(XP + abase + (long)pixq*CIN);
    A1 = *(const uint4*)(XP + abase + (long)(pixq + 64)*CIN);
    long gw = (long)n2*NBLK*32;
    if (NBLK == 64 || tid < 128){
      BHr = *(const uint4*)(WH + gw + tid*8);
      BLr = *(const uint4*)(WL + gw + tid*8);
    }
  }
  for (int step = 0; step < STEPS; step++){
    __syncthreads();
    *(uint4*)&Als[wrA0] = A0;
    *(uint4*)&Als[wrA1] = A1;
    if (NBLK == 64 || tid < 128){
      *(uint4*)&BHs[wrB] = BHr;
      *(uint4*)&BLs[wrB] = BLr;
    }
    __syncthreads();
    if (step + 1 < STEPS){
      int s2 = step + 1;
      int sh = s2 / KC, kc = s2 - sh*KC;
      int ky = sh / 3, kx = sh - ky*3;
      long abase = ((long)(b*TW + y + ky*DIL)*TW + kx*DIL)*CIN + kc*32 + qq*8;
      A0 = *(const uint4*)(XP + abase + (long)pixq*CIN);
      A1 = *(const uint4*)(XP + abase + (long)(pixq + 64)*CIN);
      long gw = ((long)s2*coutTotal + n2*NBLK)*32;
      if (NBLK == 64 || tid < 128){
        BHr = *(const uint4*)(WH + gw + tid*8);
        BLr = *(const uint4*)(WL + gw + tid*8);
      }
    }
    bfrag af[MI], bhf[2], blf[2];
    #pragma unroll
    for (int i = 0; i < MI; i++)
      af[i] = *(const bfrag*)&Als[((mt0 + i)*16 + rown)*LDA + kq];
    #pragma unroll
    for (int j = 0; j < 2; j++){
      bhf[j] = *(const bfrag*)&BHs[((nt0 + j)*16 + rown)*LDA + kq];
      blf[j] = *(const bfrag*)&BLs[((nt0 + j)*16 + rown)*LDA + kq];
    }
    #pragma unroll
    for (int i = 0; i < MI; i++)
      #pragma unroll
      for (int j = 0; j < 2; j++){
        acc[i][j] = __builtin_amdgcn_mfma_f32_16x16x32_bf16(af[i], blf[j], acc[i][j], 0, 0, 0);
        acc[i][j] = __builtin_amdgcn_mfma_f32_16x16x32_bf16(af[i], bhf[j], acc[i][j], 0, 0, 0);
      }
  }
  #pragma unroll
  for (int i = 0; i < MI; i++){
    int pixel = (mt0 + i)*16 + (lane >> 4)*4;
    #pragma unroll
    for (int j = 0; j < 2; j++){
      int co = n2*NBLK + (nt0 + j)*16 + (lane & 15);
      float sc = scbi[co], bb = scbi[coutTotal + co];
      float* op = out + ((long)(b*coutTotal + co))*S + y*128 + pixel;
      #pragma unroll
      for (int r = 0; r < 4; r++)
        op[r] = fmaxf(acc[i][j][r]*sc + bb, 0.f);
    }
  }
}

// ---------------- generic 1x1 conv (NCO co per block for occupancy) ----------------
template<int MODE, int NCO>
__global__ __launch_bounds__(256) void conv1x1_kernel(const float* __restrict__ in, int in_bs,
    const float* __restrict__ W, int cin, int wstride, const float* __restrict__ scbi,
    const float* __restrict__ beff, const float* __restrict__ res, int res_bs,
    float* __restrict__ out, int out_bs){
  int b = blockIdx.z, cog = blockIdx.y;
  int px = blockIdx.x*1024 + (threadIdx.x & 63)*4 + (threadIdx.x >> 6)*256;
  const float* ib = in + (long)b*in_bs + px;
  float4 acc[NCO];
  #pragma unroll
  for (int i = 0; i < NCO; i++){ acc[i].x = 0.f; acc[i].y = 0.f; acc[i].z = 0.f; acc[i].w = 0.f; }
  for (int c4 = 0; c4 < cin/4; c4++){
    float4 x0 = *(const float4*)(ib + (long)(c4*4+0)*S);
    float4 x1 = *(const float4*)(ib + (long)(c4*4+1)*S);
    float4 x2 = *(const float4*)(ib + (long)(c4*4+2)*S);
    float4 x3 = *(const float4*)(ib + (long)(c4*4+3)*S);
    const float* wr = W + (long)cog*NCO*wstride + c4*4;
    #pragma unroll
    for (int co = 0; co < NCO; co++){
      float4 w = *(const float4*)(wr + (long)co*wstride);
      acc[co].x += w.x*x0.x + w.y*x1.x + w.z*x2.x + w.w*x3.x;
      acc[co].y += w.x*x0.y + w.y*x1.y + w.z*x2.y + w.w*x3.y;
      acc[co].z += w.x*x0.z + w.y*x1.z + w.z*x2.z + w.w*x3.z;
      acc[co].w += w.x*x0.w + w.y*x1.w + w.z*x2.w + w.w*x3.w;
    }
  }
  int cout = gridDim.y * NCO;
  #pragma unroll
  for (int co = 0; co < NCO; co++){
    int c = cog*NCO + co;
    float4 v = acc[co];
    if (MODE == 0){
      float sc = scbi[c], bb = scbi[cout + c];
      v.x = fmaxf(v.x*sc + bb, 0.f); v.y = fmaxf(v.y*sc + bb, 0.f);
      v.z = fmaxf(v.z*sc + bb, 0.f); v.w = fmaxf(v.w*sc + bb, 0.f);
    } else if (MODE == 1){
      float4 r = *(const float4*)(res + (long)b*res_bs + (long)c*S + px);
      v.x += r.x; v.y += r.y; v.z += r.z; v.w += r.w;
    } else {
      float sc = scbi[c], bb = beff[b*64 + c];
      v.x = fmaxf(v.x*sc + bb, 0.f); v.y = fmaxf(v.y*sc + bb, 0.f);
      v.z = fmaxf(v.z*sc + bb, 0.f); v.w = fmaxf(v.w*sc + bb, 0.f);
    }
    *(float4*)(out + (long)b*out_bs + (long)c*S + px) = v;
  }
}

// ---------------- FFT-128 with hoisted lane twiddles ----------------
__device__ __forceinline__ void fft128_mk_tw(float (&tws)[8], float (&twc)[8],
                                             float sign, int lane){
  float a0 = sign * (2.0f*PI_F/128.0f) * (float)lane;
  __sincosf(a0, &tws[0], &twc[0]);
  int i = 1;
  #pragma unroll
  for (int h = 32; h >= 1; h >>= 1, i++){
    int j = lane & (h - 1);
    float a = sign * (2.0f*PI_F/128.0f) * (float)(j * (64/h));
    __sincosf(a, &tws[i], &twc[i]);
  }
}

__device__ __forceinline__ void fft128(float& z0r, float& z0i, float& z1r, float& z1i,
    const float (&tws)[8], const float (&twc)[8], int lane){
  {
    float ar = z0r, ai = z0i, br = z1r, bi = z1i;
    z0r = ar + br; z0i = ai + bi;
    float dr = ar - br, di = ai - bi;
    float s = tws[0], c = twc[0];
    z1r = dr*c - di*s; z1i = dr*s + di*c;
  }
  int idx = 1;
  #pragma unroll
  for (int h = 32; h >= 1; h >>= 1, idx++){
    float s = tws[idx], c = twc[idx];
    bool up = (lane & h) != 0;
    float pr, pi, nr, ni;
    pr = __shfl_xor(z0r, h, 64); pi = __shfl_xor(z0i, h, 64);
    if (!up){ nr = z0r + pr; ni = z0i + pi; }
    else { float dr = pr - z0r, di = pi - z0i; nr = dr*c - di*s; ni = dr*s + di*c; }
    z0r = nr; z0i = ni;
    pr = __shfl_xor(z1r, h, 64); pi = __shfl_xor(z1i, h, 64);
    if (!up){ nr = z1r + pr; ni = z1i + pi; }
    else { float dr = pr - z1r, di = pi - z1i; nr = dr*c - di*s; ni = dr*s + di*c; }
    z1r = nr; z1i = ni;
  }
}

__global__ __launch_bounds__(256) void fft_rows_fwd_kernel(const float* __restrict__ in,
    float* __restrict__ outRe, float* __restrict__ outIm){
  int line = blockIdx.x*4 + (threadIdx.x >> 6);
  int lane = threadIdx.x & 63;
  float tws[8], twc[8];
  fft128_mk_tw(tws, twc, -1.0f, lane);
  long ib = (long)line * 128;
  float z0r = in[ib + lane], z0i = 0.f;
  float z1r = in[ib + lane + 64], z1i = 0.f;
  fft128(z0r, z0i, z1r, z1i, tws, twc, lane);
  int k = __brev(lane) >> 25;
  outRe[ib + k] = z0r;   outIm[ib + k] = z0i;
  outRe[ib + k + 1] = z1r; outIm[ib + k + 1] = z1i;
}

// MODE 0: fwd cols. MODE 1: premul inline-gate (H + wb + bwb), ifft cols.
// MODE 2: ifft cols + 4-step twiddle.
template<int MODE>
__global__ __launch_bounds__(256) void fft_cols_kernel(const float* inRe, const float* inIm,
    float* outRe, float* outIm, const float* gate, const float* wb, const float* bwb){
  __shared__ float lre[128][17];
  __shared__ float lim[128][17];
  int plane = blockIdx.y;
  int cb = blockIdx.x * 16;
  int tid = threadIdx.x;
  long pbase = (long)plane * S;
  float w0=0.f, w1=0.f, w2=0.f, w3=0.f, bw=0.f;
  const float* Hb = nullptr;
  if (MODE == 1){
    int co = plane & 63;
    w0 = wb[co*4]; w1 = wb[co*4+1]; w2 = wb[co*4+2]; w3 = wb[co*4+3];
    bw = bwb[co];
    Hb = gate + (long)(plane >> 6) * 4 * S;
  }
  #pragma unroll
  for (int i = 0; i < 8; i++){
    int idx = tid + i*256;
    int r = idx >> 4, c = idx & 15;
    int pxl = r*128 + cb + c;
    long a = pbase + pxl;
    float re = inRe[a], im = inIm[a];
    if (MODE == 1){
      float hv = bw + w0*Hb[pxl] + w1*Hb[S + pxl] + w2*Hb[2*S + pxl] + w3*Hb[3*S + pxl];
      float g = 1.0f / (1.0f + __expf(-hv));
      re *= g; im *= g;
    }
    lre[r][c] = re; lim[r][c] = im;
  }
  __syncthreads();
  int wv = tid >> 6, lane = tid & 63;
  const float sign = (MODE == 0) ? -1.0f : 1.0f;
  float tws[8], twc[8];
  fft128_mk_tw(tws, twc, sign, lane);
  #pragma unroll
  for (int cc = 0; cc < 4; cc++){
    int c = wv*4 + cc;
    float z0r = lre[lane][c], z0i = lim[lane][c];
    float z1r = lre[lane + 64][c], z1i = lim[lane + 64][c];
    fft128(z0r, z0i, z1r, z1i, tws, twc, lane);
    int k = __brev(lane) >> 25;
    if (MODE == 2){
      int n2 = cb + c;
      float s, co;
      float a0 = (2.0f*PI_F/16384.0f) * (float)(n2 * k);
      __sincosf(a0, &s, &co);
      float t = z0r*co - z0i*s; z0i = z0r*s + z0i*co; z0r = t;
      float a1 = (2.0f*PI_F/16384.0f) * (float)(n2 * (k + 1));
      __sincosf(a1, &s, &co);
      t = z1r*co - z1i*s; z1i = z1r*s + z1i*co; z1r = t;
    }
    lre[k][c] = z0r;     lim[k][c] = z0i;
    lre[k + 1][c] = z1r; lim[k + 1][c] = z1i;
  }
  __syncthreads();
  #pragma unroll
  for (int i = 0; i < 8; i++){
    int idx = tid + i*256;
    int r = idx >> 4, c = idx & 15;
    long a = pbase + r*128 + cb + c;
    outRe[a] = lre[r][c]; outIm[a] = lim[r][c];
  }
}

__global__ __launch_bounds__(256) void ifft_rows_abs_ol_kernel(const float* __restrict__ Ere,
    const float* __restrict__ Eim, float* __restrict__ A){
  int line = blockIdx.x*4 + (threadIdx.x >> 6);
  int lane = threadIdx.x & 63;
  float tws[8], twc[8];
  fft128_mk_tw(tws, twc, 1.0f, lane);
  int plane = line >> 7, row = line & 127;
  long ib = (long)plane*S + row*128;
  float z0r = Ere[ib + lane], z0i = Eim[ib + lane];
  float z1r = Ere[ib + lane + 64], z1i = Eim[ib + lane + 64];
  fft128(z0r, z0i, z1r, z1i, tws, twc, lane);
  int b = plane >> 6, ch = plane & 63;
  float* out = A + ((long)(b*128 + 64 + ch)) * S + row*128;
  int k = __brev(lane) >> 25;
  out[k]     = sqrtf(z0r*z0r + z0i*z0i) * (1.0f/16384.0f);
  out[k + 1] = sqrtf(z1r*z1r + z1i*z1i) * (1.0f/16384.0f);
}

__global__ __launch_bounds__(256) void ifft_rows_abs_ofT_kernel(const float* __restrict__ Ere,
    const float* __restrict__ Eim, float* __restrict__ A){
  __shared__ float T[128][17];
  int plane = blockIdx.y;       // b*64 + h*8 + c
  int r0 = blockIdx.x * 16;     // k1 base
  int wv = threadIdx.x >> 6, lane = threadIdx.x & 63;
  float tws[8], twc[8];
  fft128_mk_tw(tws, twc, 1.0f, lane);
  #pragma unroll
  for (int i = 0; i < 4; i++){
    int rl = wv*4 + i;
    int row = r0 + rl;
    long ib = (long)plane*S + row*128;
    float z0r = Ere[ib + lane], z0i = Eim[ib + lane];
    float z1r = Ere[ib + lane + 64], z1i = Eim[ib + lane + 64];
    fft128(z0r, z0i, z1r, z1i, tws, twc, lane);
    int k = __brev(lane) >> 25;
    T[k][rl]     = sqrtf(z0r*z0r + z0i*z0i) * (1.0f/16384.0f);
    T[k + 1][rl] = sqrtf(z1r*z1r + z1i*z1i) * (1.0f/16384.0f);
  }
  __syncthreads();
  int b = plane >> 6, ch = plane & 63;
  float* out = A + ((long)(b*128 + ch)) * S + r0;
  #pragma unroll
  for (int i = 0; i < 8; i++){
    int idx = threadIdx.x + i*256;
    int k2 = idx >> 4, rl = idx & 15;
    out[(long)k2*128 + rl] = T[k2][rl];
  }
}

// ---------------- attention stats: fused norms+gram partials ----------------
__global__ __launch_bounds__(256) void gram_part_kernel(const float* __restrict__ Dre,
    const float* __restrict__ Dim, float* __restrict__ PART){
  int bh = blockIdx.x, slab = blockIdx.y;
  long base = (long)bh * 8 * S;
  int n0 = slab * 2048;
  float accr[36], acci[36], nsq[8];
  #pragma unroll
  for (int i = 0; i < 36; i++){ accr[i] = 0.f; acci[i] = 0.f; }
  #pragma unroll
  for (int i = 0; i < 8; i++) nsq[i] = 0.f;
  for (int it = 0; it < 8; it++){
    int n = n0 + it*256 + threadIdx.x;
    float xr[8], xi[8];
    #pragma unroll
    for (int c = 0; c < 8; c++){
      xr[c] = Dre[base + (long)c*S + n];
      xi[c] = Dim[base + (long)c*S + n];
      nsq[c] += xr[c]*xr[c] + xi[c]*xi[c];
    }
    int t = 0;
    #pragma unroll
    for (int c = 0; c < 8; c++)
      #pragma unroll
      for (int d = c; d < 8; d++){
        accr[t] += xr[c]*xr[d] - xi[c]*xi[d];
        acci[t] += xr[c]*xi[d] + xi[c]*xr[d];
        t++;
      }
  }
  __shared__ float red[4][80];
  int wv = threadIdx.x >> 6, lane = threadIdx.x & 63;
  #pragma unroll
  for (int i = 0; i < 80; i++){
    float v = (i < 36) ? accr[i] : (i < 72) ? acci[i - 36] : nsq[i - 72];
    #pragma unroll
    for (int o = 32; o; o >>= 1) v += __shfl_xor(v, o, 64);
    if (lane == 0) red[wv][i] = v;
  }
  __syncthreads();
  if (threadIdx.x < 80){
    int i = threadIdx.x;
    PART[(long)(bh*8 + slab)*80 + i] = red[0][i] + red[1][i] + red[2][i] + red[3][i];
  }
}

// attn2: reduce PART in-kernel, then per-(c,d) lane softmax + F8^{-1} fold
__global__ void attn2f_kernel(const float* __restrict__ PART,
    const float* __restrict__ temp, float* __restrict__ ATT2){
  __shared__ float ssum[80];
  __shared__ float sar[64], sai[64];
  int bh = blockIdx.x;
  int t = threadIdx.x;           // 0..127
  if (t < 80){
    float s = 0.f;
    for (int i = 0; i < 8; i++) s += PART[(long)(bh*8 + i)*80 + t];
    ssum[t] = s;
  }
  __syncthreads();
  if (t >= 64) return;
  int lane = t;
  int c = lane >> 3, d = lane & 7;
  int lo = min(c, d), hi = max(c, d);
  int t2 = lo*8 - lo*(lo - 1)/2 + (hi - lo);
  float nnc = fmaxf(sqrtf(ssum[72 + c]), 1e-12f);
  float nnd = fmaxf(sqrtf(ssum[72 + d]), 1e-12f);
  float inv = temp[bh & 7] / (nnc * nnd);
  float ar = ssum[t2] * inv, ai = ssum[36 + t2] * inv;
  float m = ar;
  m = fmaxf(m, __shfl_xor(m, 1, 64)); m = fmaxf(m, __shfl_xor(m, 2, 64)); m = fmaxf(m, __shfl_xor(m, 4, 64));
  float e = __expf(ar - m);
  float su = e;
  su += __shfl_xor(su, 1, 64); su += __shfl_xor(su, 2, 64); su += __shfl_xor(su, 4, 64);
  ar = e / su;
  m = ai;
  m = fmaxf(m, __shfl_xor(m, 1, 64)); m = fmaxf(m, __shfl_xor(m, 2, 64)); m = fmaxf(m, __shfl_xor(m, 4, 64));
  e = __expf(ai - m);
  su = e;
  su += __shfl_xor(su, 1, 64); su += __shfl_xor(su, 2, 64); su += __shfl_xor(su, 4, 64);
  ai = e / su;
  sar[lane] = ar; sai[lane] = ai;
  __syncthreads();
  const float ct[8] = {1.f, 0.70710678f, 0.f, -0.70710678f, -1.f, -0.70710678f, 0.f, 0.70710678f};
  const float st[8] = {0.f, 0.70710678f, 1.f, 0.70710678f, 0.f, -0.70710678f, -1.f, -0.70710678f};
  int cp = c;
  float sr = 0.f, si = 0.f;
  #pragma unroll
  for (int cc = 0; cc < 8; cc++){
    int k = (cc * cp) & 7;
    float a = sar[cc*8 + d], b2 = sai[cc*8 + d];
    sr += ct[k]*a - st[k]*b2;
    si += ct[k]*b2 + st[k]*a;
  }
  float2 v; v.x = sr * 0.125f; v.y = si * 0.125f;
  ((float2*)ATT2)[bh*64 + lane] = v;
}

__global__ __launch_bounds__(256) void apply_attn_kernel(const float* __restrict__ Dre,
    const float* __restrict__ Dim, const float* __restrict__ ATT2,
    float* __restrict__ Ere, float* __restrict__ Eim){
  int bh = blockIdx.y;
  int px = blockIdx.x*1024 + (threadIdx.x & 63)*4 + (threadIdx.x >> 6)*256;
  long base = (long)bh * 8 * S + px;
  float4 ar[8], ai[8];
  #pragma unroll
  for (int i = 0; i < 8; i++){
    ar[i].x = ar[i].y = ar[i].z = ar[i].w = 0.f;
    ai[i].x = ai[i].y = ai[i].z = ai[i].w = 0.f;
  }
  #pragma unroll
  for (int d = 0; d < 8; d++){
    float4 xr = *(const float4*)(Dre + base + (long)d*S);
    float4 xi = *(const float4*)(Dim + base + (long)d*S);
    #pragma unroll
    for (int cp = 0; cp < 8; cp++){
      float wr = ATT2[bh*128 + (cp*8 + d)*2];
      float wi = ATT2[bh*128 + (cp*8 + d)*2 + 1];
      ar[cp].x += wr*xr.x - wi*xi.x;  ai[cp].x += wr*xi.x + wi*xr.x;
      ar[cp].y += wr*xr.y - wi*xi.y;  ai[cp].y += wr*xi.y + wi*xr.y;
      ar[cp].z += wr*xr.z - wi*xi.z;  ai[cp].z += wr*xi.z + wi*xr.z;
      ar[cp].w += wr*xr.w - wi*xi.w;  ai[cp].w += wr*xi.w + wi*xr.w;
    }
  }
  #pragma unroll
  for (int cp = 0; cp < 8; cp++){
    *(float4*)(Ere + base + (long)cp*S) = ar[cp];
    *(float4*)(Eim + base + (long)cp*S) = ai[cp];
  }
}

// gate hidden: H[b][j][px] = relu(bn(wa_j . f.real))  (4 ch only)
__global__ __launch_bounds__(256) void gateh_kernel(const float* __restrict__ Dre,
    const float* __restrict__ wa, const float* __restrict__ sbwa, float* __restrict__ H){
  int b = blockIdx.y;
  int px = blockIdx.x*256 + threadIdx.x;
  long base = (long)b * 64 * S + px;
  float h0 = 0.f, h1 = 0.f, h2 = 0.f, h3 = 0.f;
  for (int ci = 0; ci < 64; ci++){
    float x = Dre[base + (long)ci*S];
    h0 += wa[ci]*x; h1 += wa[64 + ci]*x; h2 += wa[128 + ci]*x; h3 += wa[192 + ci]*x;
  }
  long ob = (long)b * 4 * S + px;
  H[ob]       = fmaxf(h0*sbwa[0] + sbwa[4], 0.f);
  H[ob + S]   = fmaxf(h1*sbwa[1] + sbwa[5], 0.f);
  H[ob + 2*S] = fmaxf(h2*sbwa[2] + sbwa[6], 0.f);
  H[ob + 3*S] = fmaxf(h3*sbwa[3] + sbwa[7], 0.f);
}

// ---------------- small kernels ----------------
__global__ __launch_bounds__(256) void mean_kernel(const float* __restrict__ A, float* __restrict__ M){
  int p = blockIdx.x;
  long base = (long)p * S;
  float s = 0.f;
  for (int n = threadIdx.x; n < S; n += 256) s += A[base + n];
  #pragma unroll
  for (int o = 32; o; o >>= 1) s += __shfl_xor(s, o, 64);
  __shared__ float sm[4];
  if ((threadIdx.x & 63) == 0) sm[threadIdx.x >> 6] = s;
  __syncthreads();
  if (threadIdx.x == 0) M[p] = (sm[0] + sm[1] + sm[2] + sm[3]) * (1.0f/16384.0f);
}

__global__ void c5_kernel(const float* __restrict__ W5, const float* __restrict__ sb5,
    const float* __restrict__ M, float* __restrict__ C5){
  int t = threadIdx.x;
  if (t >= 256) return;
  int b = t >> 6, co = t & 63;
  float s = 0.f;
  for (int ci = 0; ci < 128; ci++) s += W5[co*128 + ci] * M[b*128 + ci];
  C5[t] = fmaxf(s * sb5[co] + sb5[64 + co], 0.f);
}

__global__ void beff_kernel(const float* __restrict__ WF, const float* __restrict__ sbf,
    const float* __restrict__ C5, float* __restrict__ BEFF){
  int t = threadIdx.x;
  if (t >= 256) return;
  int b = t >> 6, co = t & 63;
  float s = 0.f;
  for (int j = 0; j < 64; j++) s += WF[co*320 + 256 + j] * C5[b*64 + j];
  BEFF[t] = s * sbf[co] + sbf[64 + co];
}

// output is FLOAT32 — write float4
__global__ __launch_bounds__(256) void ob_kernel(const float* __restrict__ Tin,
    const float* __restrict__ wob, const float* __restrict__ bob, float* __restrict__ out){
  int b = blockIdx.y;
  int px = blockIdx.x*1024 + (threadIdx.x & 63)*4 + (threadIdx.x >> 6)*256;
  float b0 = bob[0];
  float4 a; a.x = b0; a.y = b0; a.z = b0; a.w = b0;
  for (int ci = 0; ci < 32; ci++){
    float4 v = *(const float4*)(Tin + ((long)b*32 + ci)*S + px);
    float w = wob[ci];
    a.x += w*v.x; a.y += w*v.y; a.z += w*v.z; a.w += w*v.w;
  }
  *(float4*)(out + (long)b*S + px) = a;
}

// ---------------- launch ----------------
extern "C" void kernel_launch(void* const* d_in, const int* in_sizes, int n_in,
                              void* d_out, int out_size, void* d_ws, size_t ws_size,
                              hipStream_t stream){
  float* ws = (float*)d_ws;
  Ptrs P;
  for (int i = 0; i < 43 && i < n_in; i++) P.p[i] = (const float*)d_in[i];
  float* out = (float*)d_out;

  float* A   = ws + O_A;
  float* FIN = ws + O_FIN;
  float* CC  = ws + O_CC;
  float* DRE = ws + O_DRE;
  float* DIMp= ws + O_DIMG;
  float* ERE = ws + O_ERE;
  float* EIM = ws + O_EIM;
  float* G   = ws + O_G;
  float* H   = ws + O_H;

  unsigned short* XT  = (unsigned short*)(ws + O_DRE);
  unsigned short* WHd = (unsigned short*)(ws + O_CC);
  unsigned short* WLd = (unsigned short*)(ws + O_CC + 147456);
  unsigned short* WB  = (unsigned short*)(ws + O_WB);
  unsigned short* XP  = (unsigned short*)(ws + O_ERE);

  prep_sb_kernel<<<dim3(9), dim3(256), 0, stream>>>(P, ws);
  xpad_kernel<<<dim3(130, 4), dim3(256), 0, stream>>>(P.p[0], XT);
  wt_kernel<<<dim3(128), dim3(256), 0, stream>>>(P.p[1], WHd, WLd);
  wtg_kernel<<<dim3(16, 4), dim3(256), 0, stream>>>(P, WB);

  conv3x3_mfma_kernel<1,8,64><<<dim3(1024), dim3(256), 0, stream>>>(
      XT, WHd, WLd, ws + O_SBDC, A);

  mean_kernel<<<dim3(512), dim3(256), 0, stream>>>(A, ws + O_M);
  c5_kernel<<<dim3(1), dim3(256), 0, stream>>>(P.p[21], ws + O_SB5, ws + O_M, ws + O_C5);
  beff_kernel<<<dim3(1), dim3(256), 0, stream>>>(P.p[33], ws + O_SBF, ws + O_C5, ws + O_BEFF);

  conv1x1_kernel<0,8><<<dim3(16, 8, 4), dim3(256), 0, stream>>>(
      A, 128*S, P.p[5], 128, 128, ws + O_SB1, nullptr, nullptr, 0, FIN, 256*S);

  for (int k = 0; k < 3; k++){
    const float* sb = ws + (k == 0 ? O_SB2 : k == 1 ? O_SB3 : O_SB4);
    const float* in2 = (k == 0) ? nullptr : FIN + (long)(64*k)*S;
    unsigned short* wh = WB + (k == 0 ? 0 : k == 1 ? 73728 : 147456);
    if (k == 0){
      xpad64_kernel<3><<<dim3(134, 4), dim3(256), 0, stream>>>(FIN, in2, 256*S, XP);
      conv3x3_mfma_kernel<3,2,64><<<dim3(512), dim3(256), 0, stream>>>(
          XP, wh, wh + 36864, sb, CC);
    } else if (k == 1){
      xpad64_kernel<5><<<dim3(138, 4), dim3(256), 0, stream>>>(FIN, in2, 256*S, XP);
      conv3x3_mfma_kernel<5,2,64><<<dim3(512), dim3(256), 0, stream>>>(
          XP, wh, wh + 36864, sb, CC);
    } else {
      xpad64_kernel<7><<<dim3(142, 4), dim3(256), 0, stream>>>(FIN, in2, 256*S, XP);
      conv3x3_mfma_kernel<7,2,64><<<dim3(512), dim3(256), 0, stream>>>(
          XP, wh, wh + 36864, sb, CC);
    }

    // f = fft2(c)
    fft_rows_fwd_kernel<<<dim3(8192), dim3(256), 0, stream>>>(CC, DRE, DIMp);
    fft_cols_kernel<0><<<dim3(8, 256), dim3(256), 0, stream>>>(
        DRE, DIMp, DRE, DIMp, nullptr, nullptr, nullptr);
    // attention stats
    gram_part_kernel<<<dim3(32, 8), dim3(256), 0, stream>>>(DRE, DIMp, ws + O_PART);
    attn2f_kernel<<<dim3(32), dim3(128), 0, stream>>>(ws + O_PART, P.p[25], ws + O_ATT2);
    // gate hidden (4 ch) from f.real
    gateh_kernel<<<dim3(64, 4), dim3(256), 0, stream>>>(DRE, P.p[27], ws + O_SBWA, H);
    // ol = |ifft2(sigmoid(wb.h+bwb) * f)| -> A channels [64,128)
    fft_cols_kernel<1><<<dim3(8, 256), dim3(256), 0, stream>>>(
        DRE, DIMp, ERE, EIM, H, P.p[31], P.p[32]);
    ifft_rows_abs_ol_kernel<<<dim3(8192), dim3(256), 0, stream>>>(ERE, EIM, A);
    // of = |ifft_{c,n}(attn @ qkv)| -> A channels [0,64)
    apply_attn_kernel<<<dim3(16, 32), dim3(256), 0, stream>>>(DRE, DIMp, ws + O_ATT2, ERE, EIM);
    fft_cols_kernel<2><<<dim3(8, 256), dim3(256), 0, stream>>>(
        ERE, EIM, ERE, EIM, nullptr, nullptr, nullptr);
    ifft_rows_abs_ofT_kernel<<<dim3(8, 256), dim3(256), 0, stream>>>(ERE, EIM, A);
    // F_k = w_po @ concat(of, ol) + c
    conv1x1_kernel<1,8><<<dim3(16, 8, 4), dim3(256), 0, stream>>>(
        A, 128*S, P.p[26], 128, 128, nullptr, nullptr, CC, 64*S,
        FIN + (long)(64*(k + 1))*S, 256*S);
  }

  conv1x1_kernel<2,8><<<dim3(16, 8, 4), dim3(256), 0, stream>>>(
      FIN, 256*S, P.p[33], 256, 320, ws + O_SBF, ws + O_BEFF, nullptr, 0, CC, 64*S);
  xpad64_kernel<1><<<dim3(130, 4), dim3(256), 0, stream>>>(CC, nullptr, 64*S, XP);
  conv3x3_mfma_kernel<1,2,32><<<dim3(512), dim3(256), 0, stream>>>(
      XP, WB + 221184, WB + 221184 + 18432, ws + O_SBOA, G);
  ob_kernel<<<dim3(16, 4), dim3(256), 0, stream>>>(G, P.p[41], P.p[42], out);
}

// Round 10
// 1074.859 us; speedup vs baseline: 1.4488x; 1.0971x over previous
//
#include <hip/hip_runtime.h>

#define S 16384
#define PI_F 3.14159265358979f

struct Ptrs { const float* p[43]; };

// ---- workspace layout (float offsets) ----
enum : int {
  O_SBDC=0, O_SB1=256, O_SB2=512, O_SB3=768, O_SB4=1024, O_SB5=1280,
  O_SBWA=1536, O_SBF=1792, O_SBOA=2048,
  O_M=2304, O_C5=2816, O_NRM=3072, O_GRAM=3328, O_ATT2=7424, O_BEFF=11520,
  O_WB=16384,        // packed hi/lo bf16 weights for dil/oa convs
  O_PART=147456,     // gram/norm partials [256][80]
  O_H=180224,        // gate hidden H[4][4][S] (1 MB, ends 442368)
  O_WP=442368,       // packed hi/lo bf16 1x1 weights (w1|po|wf, 128 KB)
  O_A=524288,        // [4][128][S]  xd, later concat(of,ol)
  O_FIN=8912896,     // [4][256][S]  c1 | F2 | F3 | F4
  O_CC=25690112,     // [4][64][S]   c2/c3/c4, later fused; conv_dc WH/WL live here early
  O_DRE=29884416, O_DIMG=34078720,   // f (complex, SoA); XT lives here pre-FFT
  O_ERE=38273024, O_EIM=42467328,    // scratch complex; dil/oa XP lives here transiently
  O_G=46661632       // [4][64][S]   later t (oa out, 32ch)
};

typedef short bfrag __attribute__((ext_vector_type(8)));   // 8 bf16 = 4 VGPR
typedef float ffrag __attribute__((ext_vector_type(4)));   // 4 fp32 acc

__device__ __forceinline__ float bf2f(unsigned short u){
  union { unsigned int i; float f; } v; v.i = ((unsigned int)u) << 16; return v.f;
}
__device__ __forceinline__ unsigned short f2bf(float f){
  unsigned int x = __float_as_uint(f);
  unsigned int r = x + 0x7fffu + ((x >> 16) & 1u);
  return (unsigned short)(r >> 16);
}

// ---------------- param prep: fold BN (eval-mode) into scale/bias ----------------
__global__ void prep_sb_kernel(Ptrs P, float* ws){
  const float r = rsqrtf(1.0f + 1e-5f);
  int bi=0, si=0, oi=0, C=0, dst=0;
  switch (blockIdx.x){
    case 0: bi=2; si=3; oi=4; C=128; dst=O_SBDC; break;
    case 1: bi=6; si=7; oi=8; C=64; dst=O_SB1; break;
    case 2: bi=10; si=11; oi=12; C=64; dst=O_SB2; break;
    case 3: bi=14; si=15; oi=16; C=64; dst=O_SB3; break;
    case 4: bi=18; si=19; oi=20; C=64; dst=O_SB4; break;
    case 5: bi=22; si=23; oi=24; C=64; dst=O_SB5; break;
    case 6: bi=28; si=29; oi=30; C=4;  dst=O_SBWA; break;
    case 7: bi=34; si=35; oi=36; C=64; dst=O_SBF; break;
    default: bi=38; si=39; oi=40; C=32; dst=O_SBOA; break;
  }
  for (int c = threadIdx.x; c < C; c += 256){
    float bb = P.p[bi][c], ss = P.p[si][c], oo = P.p[oi][c];
    float sc = ss * r;
    ws[dst + c] = sc;
    ws[dst + C + c] = bb * sc + oo;
  }
}

// ---------------- conv_dc prepacks ----------------
__global__ __launch_bounds__(256) void xpad_kernel(const float* __restrict__ x,
    unsigned short* __restrict__ XT){
  int yy = blockIdx.x, b = blockIdx.y;
  long obase = ((long)(b*130) + yy) * (130L*256);
  int tid = threadIdx.x;
  if (yy == 0 || yy == 129){
    uint4 z; z.x=0; z.y=0; z.z=0; z.w=0;
    for (int i = tid; i < 130*256/8; i += 256)
      *(uint4*)(XT + obase + (long)i*8) = z;
    return;
  }
  __shared__ float LT[64][129];
  int y = yy - 1;
  for (int c0 = 0; c0 < 256; c0 += 64){
    for (int idx = tid; idx < 64*128; idx += 256){
      int ci = idx >> 7, xx = idx & 127;
      LT[ci][xx] = x[((long)(b*256 + c0 + ci)*128 + y)*128 + xx];
    }
    __syncthreads();
    for (int idx = tid; idx < 128*16; idx += 256){
      int xp = idx >> 4, c4 = (idx & 15)*4;
      ushort4 v;
      v.x = f2bf(LT[c4][xp]);   v.y = f2bf(LT[c4+1][xp]);
      v.z = f2bf(LT[c4+2][xp]); v.w = f2bf(LT[c4+3][xp]);
      *(ushort4*)(XT + obase + (long)(xp+1)*256 + c0 + c4) = v;
    }
    __syncthreads();
  }
  if (tid < 64){
    ushort4 z; z.x=0; z.y=0; z.z=0; z.w=0;
    *(ushort4*)(XT + obase + tid*4) = z;
    *(ushort4*)(XT + obase + 129L*256 + tid*4) = z;
  }
}

__global__ void wt_kernel(const float* __restrict__ w, unsigned short* __restrict__ WH,
    unsigned short* __restrict__ WL){
  for (int e = blockIdx.x*256 + threadIdx.x; e < 294912; e += gridDim.x*256){
    int c32 = e & 31, co = (e >> 5) & 127, kc = (e >> 12) & 7, sh = e >> 15;
    int ky = sh / 3, kx = sh - ky*3;
    int ci = kc*32 + c32;
    float v = w[((long)(co*256 + ci)*3 + ky)*3 + kx];
    unsigned short h = f2bf(v);
    WH[e] = h;
    WL[e] = f2bf(v - bf2f(h));
  }
}

__global__ void wtg_kernel(Ptrs P, unsigned short* __restrict__ WB){
  const float* w; int cout; long off;
  switch (blockIdx.y){
    case 0: w = P.p[9];  cout = 64; off = 0;      break;
    case 1: w = P.p[13]; cout = 64; off = 73728;  break;
    case 2: w = P.p[17]; cout = 64; off = 147456; break;
    default: w = P.p[37]; cout = 32; off = 221184; break;
  }
  int total = 576*cout;
  unsigned short* WH = WB + off;
  unsigned short* WL = WH + total;
  for (int e = blockIdx.x*256 + threadIdx.x; e < total; e += gridDim.x*256){
    int c32 = e & 31;
    int co = (e >> 5) & (cout - 1);
    int kc = (e / (32*cout)) & 1;
    int sh = e / (64*cout);
    int ky = sh/3, kx = sh - ky*3;
    int ci = kc*32 + c32;
    float v = w[((long)(co*64 + ci)*3 + ky)*3 + kx];
    unsigned short h = f2bf(v);
    WH[e] = h;
    WL[e] = f2bf(v - bf2f(h));
  }
}

// 1x1 conv weights -> [kc][64co][32] hi|lo at WP offsets (w1: 0, po: 16384, wf: 32768)
__global__ void wtp_kernel(Ptrs P, unsigned short* __restrict__ WP){
  const float* w; int KC, wstr; long off;
  switch (blockIdx.y){
    case 0: w = P.p[5];  KC = 4; wstr = 128; off = 0;     break;
    case 1: w = P.p[26]; KC = 4; wstr = 128; off = 16384; break;
    default: w = P.p[33]; KC = 8; wstr = 320; off = 32768; break;
  }
  int total = KC*64*32;
  unsigned short* WH = WP + off;
  unsigned short* WL = WH + total;
  for (int e = blockIdx.x*256 + threadIdx.x; e < total; e += gridDim.x*256){
    int c32 = e & 31, co = (e >> 5) & 63, kc = e >> 11;
    float v = w[(long)co*wstr + kc*32 + c32];
    unsigned short h = f2bf(v);
    WH[e] = h;
    WL[e] = f2bf(v - bf2f(h));
  }
}

template<int DIL>
__global__ __launch_bounds__(256) void xpad64_kernel(const float* __restrict__ in1,
    const float* __restrict__ in2, long in_bs, unsigned short* __restrict__ XP){
  constexpr int TW = 128 + 2*DIL;
  int yy = blockIdx.x, b = blockIdx.y;
  long obase = (long)(b*TW + yy) * TW * 64;
  int tid = threadIdx.x;
  if (yy < DIL || yy >= 128 + DIL){
    uint4 z; z.x=0; z.y=0; z.z=0; z.w=0;
    for (int i = tid; i < TW*8; i += 256)
      *(uint4*)(XP + obase + (long)i*8) = z;
    return;
  }
  __shared__ float LT[64][129];
  int y = yy - DIL;
  const float* p1 = in1 + (long)b*in_bs + (long)y*128;
  const float* p2 = in2 ? in2 + (long)b*in_bs + (long)y*128 : nullptr;
  for (int idx = tid; idx < 64*128; idx += 256){
    int ci = idx >> 7, xx = idx & 127;
    float v = p1[(long)ci*S + xx];
    if (p2) v += p2[(long)ci*S + xx];
    LT[ci][xx] = v;
  }
  __syncthreads();
  for (int i = tid; i < 2*DIL*16; i += 256){
    int side = i / (DIL*16);
    int r = i - side*(DIL*16);
    int xcol = side ? (128 + DIL + (r >> 4)) : (r >> 4);
    ushort4 z; z.x=0; z.y=0; z.z=0; z.w=0;
    *(ushort4*)(XP + obase + (long)xcol*64 + (r & 15)*4) = z;
  }
  for (int idx = tid; idx < 128*16; idx += 256){
    int xp = idx >> 4, c4 = (idx & 15)*4;
    ushort4 v;
    v.x = f2bf(LT[c4][xp]);   v.y = f2bf(LT[c4+1][xp]);
    v.z = f2bf(LT[c4+2][xp]); v.w = f2bf(LT[c4+3][xp]);
    *(ushort4*)(XP + obase + (long)(xp + DIL)*64 + c4) = v;
  }
}

// ---------------- unified 3x3 conv via MFMA implicit GEMM ------
template<int DIL, int KC, int NBLK>
__global__ __launch_bounds__(256) void conv3x3_mfma_kernel(
    const unsigned short* __restrict__ XP,
    const unsigned short* __restrict__ WH, const unsigned short* __restrict__ WL,
    const float* __restrict__ scbi, float* __restrict__ out){
  constexpr int CIN = KC*32;
  constexpr int TW = 128 + 2*DIL;
  constexpr int STEPS = 9*KC;
  constexpr int MI = (NBLK == 64) ? 4 : 2;
  constexpr int LDA = 36;
  __shared__ unsigned short Als[128*LDA];
  __shared__ unsigned short BHs[NBLK*LDA];
  __shared__ unsigned short BLs[NBLK*LDA];
  int bid = blockIdx.x;
  int y = (bid & 7)*16 + ((bid >> 3) & 15);
  int b = (bid >> 7) & 3;
  int n2 = bid >> 9;
  int nb = gridDim.x >> 9; if (nb == 0) nb = 1;
  int coutTotal = nb * NBLK;
  int tid = threadIdx.x, wv = tid >> 6, lane = tid & 63;
  int mt0 = (NBLK == 64) ? (wv & 1)*4 : wv*2;
  int nt0 = (NBLK == 64) ? (wv >> 1)*2 : 0;
  ffrag acc[MI][2];
  #pragma unroll
  for (int i = 0; i < MI; i++)
    #pragma unroll
    for (int j = 0; j < 2; j++)
      #pragma unroll
      for (int r = 0; r < 4; r++) acc[i][j][r] = 0.f;

  int pixq = tid >> 2, qq = tid & 3;
  int kq = (lane >> 4)*8, rown = lane & 15;
  int wrA0 = pixq*LDA + qq*8;
  int wrA1 = (pixq + 64)*LDA + qq*8;
  int wrB  = (tid >> 2)*LDA + qq*8;

  uint4 A0, A1, BHr, BLr;
  {
    long abase = ((long)(b*TW + y)*TW)*CIN + qq*8;
    A0 = *(const uint4*)(XP + abase + (long)pixq*CIN);
    A1 = *(const uint4*)(XP + abase + (long)(pixq + 64)*CIN);
    long gw = (long)n2*NBLK*32;
    if (NBLK == 64 || tid < 128){
      BHr = *(const uint4*)(WH + gw + tid*8);
      BLr = *(const uint4*)(WL + gw + tid*8);
    }
  }
  for (int step = 0; step < STEPS; step++){
    __syncthreads();
    *(uint4*)&Als[wrA0] = A0;
    *(uint4*)&Als[wrA1] = A1;
    if (NBLK == 64 || tid < 128){
      *(uint4*)&BHs[wrB] = BHr;
      *(uint4*)&BLs[wrB] = BLr;
    }
    __syncthreads();
    if (step + 1 < STEPS){
      int s2 = step + 1;
      int sh = s2 / KC, kc = s2 - sh*KC;
      int ky = sh / 3, kx = sh - ky*3;
      long abase = ((long)(b*TW + y + ky*DIL)*TW + kx*DIL)*CIN + kc*32 + qq*8;
      A0 = *(const uint4*)(XP + abase + (long)pixq*CIN);
      A1 = *(const uint4*)(XP + abase + (long)(pixq + 64)*CIN);
      long gw = ((long)s2*coutTotal + n2*NBLK)*32;
      if (NBLK == 64 || tid < 128){
        BHr = *(const uint4*)(WH + gw + tid*8);
        BLr = *(const uint4*)(WL + gw + tid*8);
      }
    }
    bfrag af[MI], bhf[2], blf[2];
    #pragma unroll
    for (int i = 0; i < MI; i++)
      af[i] = *(const bfrag*)&Als[((mt0 + i)*16 + rown)*LDA + kq];
    #pragma unroll
    for (int j = 0; j < 2; j++){
      bhf[j] = *(const bfrag*)&BHs[((nt0 + j)*16 + rown)*LDA + kq];
      blf[j] = *(const bfrag*)&BLs[((nt0 + j)*16 + rown)*LDA + kq];
    }
    #pragma unroll
    for (int i = 0; i < MI; i++)
      #pragma unroll
      for (int j = 0; j < 2; j++){
        acc[i][j] = __builtin_amdgcn_mfma_f32_16x16x32_bf16(af[i], blf[j], acc[i][j], 0, 0, 0);
        acc[i][j] = __builtin_amdgcn_mfma_f32_16x16x32_bf16(af[i], bhf[j], acc[i][j], 0, 0, 0);
      }
  }
  #pragma unroll
  for (int i = 0; i < MI; i++){
    int pixel = (mt0 + i)*16 + (lane >> 4)*4;
    #pragma unroll
    for (int j = 0; j < 2; j++){
      int co = n2*NBLK + (nt0 + j)*16 + (lane & 15);
      float sc = scbi[co], bb = scbi[coutTotal + co];
      float* op = out + ((long)(b*coutTotal + co))*S + y*128 + pixel;
      #pragma unroll
      for (int r = 0; r < 4; r++)
        op[r] = fmaxf(acc[i][j][r]*sc + bb, 0.f);
    }
  }
}

// ---------------- 1x1 conv via MFMA (fp32 planar in, bf16 LDS staging, split-W) ----
// MODE 0: bn_relu | MODE 1: + residual | MODE 2: bn w/ per-(b,co) bias, relu
// tile: 128 pix (row y) x 64 co; grid 512 (y-swizzled, b)
template<int MODE, int KC>
__global__ __launch_bounds__(256) void conv1x1_mfma_kernel(
    const float* __restrict__ in, long in_bs,
    const unsigned short* __restrict__ WH, const unsigned short* __restrict__ WL,
    const float* __restrict__ scbi, const float* __restrict__ beff,
    const float* __restrict__ res, long res_bs,
    float* __restrict__ out, long out_bs){
  constexpr int LDA = 36;
  __shared__ unsigned short Als[128*LDA];
  __shared__ unsigned short BHs[64*LDA];
  __shared__ unsigned short BLs[64*LDA];
  int bid = blockIdx.x;
  int y = (bid & 7)*16 + ((bid >> 3) & 15);
  int b = bid >> 7;
  int tid = threadIdx.x, wv = tid >> 6, lane = tid & 63;
  int mt0 = (wv & 1)*4, nt0 = (wv >> 1)*2;
  ffrag acc[4][2];
  #pragma unroll
  for (int i = 0; i < 4; i++)
    #pragma unroll
    for (int j = 0; j < 2; j++)
      #pragma unroll
      for (int r = 0; r < 4; r++) acc[i][j][r] = 0.f;
  int pq = tid & 31, cg = tid >> 5;     // pixel phase (0..31), channel quad (0..7)
  int kq = (lane >> 4)*8, rown = lane & 15;
  int wrB = (tid >> 2)*LDA + (tid & 3)*8;
  const float* ib = in + (long)b*in_bs + y*128;
  float a[16];
  uint4 BHr, BLr;
  #pragma unroll
  for (int cc = 0; cc < 4; cc++)
    #pragma unroll
    for (int i = 0; i < 4; i++)
      a[cc*4 + i] = ib[(long)(cg*4 + cc)*S + pq + 32*i];
  BHr = *(const uint4*)(WH + tid*8);
  BLr = *(const uint4*)(WL + tid*8);
  for (int kc = 0; kc < KC; kc++){
    __syncthreads();
    #pragma unroll
    for (int i = 0; i < 4; i++){
      ushort4 v;
      v.x = f2bf(a[0 + i]);  v.y = f2bf(a[4 + i]);
      v.z = f2bf(a[8 + i]);  v.w = f2bf(a[12 + i]);
      *(ushort4*)&Als[(pq + 32*i)*LDA + cg*4] = v;
    }
    *(uint4*)&BHs[wrB] = BHr;
    *(uint4*)&BLs[wrB] = BLr;
    __syncthreads();
    if (kc + 1 < KC){
      #pragma unroll
      for (int cc = 0; cc < 4; cc++)
        #pragma unroll
        for (int i = 0; i < 4; i++)
          a[cc*4 + i] = ib[(long)((kc + 1)*32 + cg*4 + cc)*S + pq + 32*i];
      long gw = (long)(kc + 1)*2048;
      BHr = *(const uint4*)(WH + gw + tid*8);
      BLr = *(const uint4*)(WL + gw + tid*8);
    }
    bfrag af[4], bhf[2], blf[2];
    #pragma unroll
    for (int i = 0; i < 4; i++)
      af[i] = *(const bfrag*)&Als[((mt0 + i)*16 + rown)*LDA + kq];
    #pragma unroll
    for (int j = 0; j < 2; j++){
      bhf[j] = *(const bfrag*)&BHs[((nt0 + j)*16 + rown)*LDA + kq];
      blf[j] = *(const bfrag*)&BLs[((nt0 + j)*16 + rown)*LDA + kq];
    }
    #pragma unroll
    for (int i = 0; i < 4; i++)
      #pragma unroll
      for (int j = 0; j < 2; j++){
        acc[i][j] = __builtin_amdgcn_mfma_f32_16x16x32_bf16(af[i], blf[j], acc[i][j], 0, 0, 0);
        acc[i][j] = __builtin_amdgcn_mfma_f32_16x16x32_bf16(af[i], bhf[j], acc[i][j], 0, 0, 0);
      }
  }
  #pragma unroll
  for (int i = 0; i < 4; i++){
    int pixel = (mt0 + i)*16 + (lane >> 4)*4;
    #pragma unroll
    for (int j = 0; j < 2; j++){
      int co = (nt0 + j)*16 + (lane & 15);
      float* op = out + (long)b*out_bs + (long)co*S + y*128 + pixel;
      #pragma unroll
      for (int r = 0; r < 4; r++){
        float v = acc[i][j][r];
        if (MODE == 0){
          v = fmaxf(v*scbi[co] + scbi[64 + co], 0.f);
        } else if (MODE == 1){
          v += res[(long)b*res_bs + (long)co*S + y*128 + pixel + r];
        } else {
          v = fmaxf(v*scbi[co] + beff[b*64 + co], 0.f);
        }
        op[r] = v;
      }
    }
  }
}

// ---------------- FFT-128 with hoisted lane twiddles ----------------
__device__ __forceinline__ void fft128_mk_tw(float (&tws)[8], float (&twc)[8],
                                             float sign, int lane){
  float a0 = sign * (2.0f*PI_F/128.0f) * (float)lane;
  __sincosf(a0, &tws[0], &twc[0]);
  int i = 1;
  #pragma unroll
  for (int h = 32; h >= 1; h >>= 1, i++){
    int j = lane & (h - 1);
    float a = sign * (2.0f*PI_F/128.0f) * (float)(j * (64/h));
    __sincosf(a, &tws[i], &twc[i]);
  }
}

__device__ __forceinline__ void fft128(float& z0r, float& z0i, float& z1r, float& z1i,
    const float (&tws)[8], const float (&twc)[8], int lane){
  {
    float ar = z0r, ai = z0i, br = z1r, bi = z1i;
    z0r = ar + br; z0i = ai + bi;
    float dr = ar - br, di = ai - bi;
    float s = tws[0], c = twc[0];
    z1r = dr*c - di*s; z1i = dr*s + di*c;
  }
  int idx = 1;
  #pragma unroll
  for (int h = 32; h >= 1; h >>= 1, idx++){
    float s = tws[idx], c = twc[idx];
    bool up = (lane & h) != 0;
    float pr, pi, nr, ni;
    pr = __shfl_xor(z0r, h, 64); pi = __shfl_xor(z0i, h, 64);
    if (!up){ nr = z0r + pr; ni = z0i + pi; }
    else { float dr = pr - z0r, di = pi - z0i; nr = dr*c - di*s; ni = dr*s + di*c; }
    z0r = nr; z0i = ni;
    pr = __shfl_xor(z1r, h, 64); pi = __shfl_xor(z1i, h, 64);
    if (!up){ nr = z1r + pr; ni = z1i + pi; }
    else { float dr = pr - z1r, di = pi - z1i; nr = dr*c - di*s; ni = dr*s + di*c; }
    z1r = nr; z1i = ni;
  }
}

__global__ __launch_bounds__(256) void fft_rows_fwd_kernel(const float* __restrict__ in,
    float* __restrict__ outRe, float* __restrict__ outIm){
  int line = blockIdx.x*4 + (threadIdx.x >> 6);
  int lane = threadIdx.x & 63;
  float tws[8], twc[8];
  fft128_mk_tw(tws, twc, -1.0f, lane);
  long ib = (long)line * 128;
  float z0r = in[ib + lane], z0i = 0.f;
  float z1r = in[ib + lane + 64], z1i = 0.f;
  fft128(z0r, z0i, z1r, z1i, tws, twc, lane);
  int k = __brev(lane) >> 25;
  outRe[ib + k] = z0r;   outIm[ib + k] = z0i;
  outRe[ib + k + 1] = z1r; outIm[ib + k + 1] = z1i;
}

// MODE 0: fwd cols. MODE 1: premul inline-gate (H + wb + bwb), ifft cols.
// MODE 2: ifft cols + 4-step twiddle.
template<int MODE>
__global__ __launch_bounds__(256) void fft_cols_kernel(const float* inRe, const float* inIm,
    float* outRe, float* outIm, const float* gate, const float* wb, const float* bwb){
  __shared__ float lre[128][17];
  __shared__ float lim[128][17];
  int plane = blockIdx.y;
  int cb = blockIdx.x * 16;
  int tid = threadIdx.x;
  long pbase = (long)plane * S;
  float w0=0.f, w1=0.f, w2=0.f, w3=0.f, bw=0.f;
  const float* Hb = nullptr;
  if (MODE == 1){
    int co = plane & 63;
    w0 = wb[co*4]; w1 = wb[co*4+1]; w2 = wb[co*4+2]; w3 = wb[co*4+3];
    bw = bwb[co];
    Hb = gate + (long)(plane >> 6) * 4 * S;
  }
  #pragma unroll
  for (int i = 0; i < 8; i++){
    int idx = tid + i*256;
    int r = idx >> 4, c = idx & 15;
    int pxl = r*128 + cb + c;
    long a = pbase + pxl;
    float re = inRe[a], im = inIm[a];
    if (MODE == 1){
      float hv = bw + w0*Hb[pxl] + w1*Hb[S + pxl] + w2*Hb[2*S + pxl] + w3*Hb[3*S + pxl];
      float g = 1.0f / (1.0f + __expf(-hv));
      re *= g; im *= g;
    }
    lre[r][c] = re; lim[r][c] = im;
  }
  __syncthreads();
  int wv = tid >> 6, lane = tid & 63;
  const float sign = (MODE == 0) ? -1.0f : 1.0f;
  float tws[8], twc[8];
  fft128_mk_tw(tws, twc, sign, lane);
  #pragma unroll
  for (int cc = 0; cc < 4; cc++){
    int c = wv*4 + cc;
    float z0r = lre[lane][c], z0i = lim[lane][c];
    float z1r = lre[lane + 64][c], z1i = lim[lane + 64][c];
    fft128(z0r, z0i, z1r, z1i, tws, twc, lane);
    int k = __brev(lane) >> 25;
    if (MODE == 2){
      int n2 = cb + c;
      float s, co;
      float a0 = (2.0f*PI_F/16384.0f) * (float)(n2 * k);
      __sincosf(a0, &s, &co);
      float t = z0r*co - z0i*s; z0i = z0r*s + z0i*co; z0r = t;
      float a1 = (2.0f*PI_F/16384.0f) * (float)(n2 * (k + 1));
      __sincosf(a1, &s, &co);
      t = z1r*co - z1i*s; z1i = z1r*s + z1i*co; z1r = t;
    }
    lre[k][c] = z0r;     lim[k][c] = z0i;
    lre[k + 1][c] = z1r; lim[k + 1][c] = z1i;
  }
  __syncthreads();
  #pragma unroll
  for (int i = 0; i < 8; i++){
    int idx = tid + i*256;
    int r = idx >> 4, c = idx & 15;
    long a = pbase + r*128 + cb + c;
    outRe[a] = lre[r][c]; outIm[a] = lim[r][c];
  }
}

__global__ __launch_bounds__(256) void ifft_rows_abs_ol_kernel(const float* __restrict__ Ere,
    const float* __restrict__ Eim, float* __restrict__ A){
  int line = blockIdx.x*4 + (threadIdx.x >> 6);
  int lane = threadIdx.x & 63;
  float tws[8], twc[8];
  fft128_mk_tw(tws, twc, 1.0f, lane);
  int plane = line >> 7, row = line & 127;
  long ib = (long)plane*S + row*128;
  float z0r = Ere[ib + lane], z0i = Eim[ib + lane];
  float z1r = Ere[ib + lane + 64], z1i = Eim[ib + lane + 64];
  fft128(z0r, z0i, z1r, z1i, tws, twc, lane);
  int b = plane >> 6, ch = plane & 63;
  float* out = A + ((long)(b*128 + 64 + ch)) * S + row*128;
  int k = __brev(lane) >> 25;
  out[k]     = sqrtf(z0r*z0r + z0i*z0i) * (1.0f/16384.0f);
  out[k + 1] = sqrtf(z1r*z1r + z1i*z1i) * (1.0f/16384.0f);
}

__global__ __launch_bounds__(256) void ifft_rows_abs_ofT_kernel(const float* __restrict__ Ere,
    const float* __restrict__ Eim, float* __restrict__ A){
  __shared__ float T[128][17];
  int plane = blockIdx.y;       // b*64 + h*8 + c
  int r0 = blockIdx.x * 16;     // k1 base
  int wv = threadIdx.x >> 6, lane = threadIdx.x & 63;
  float tws[8], twc[8];
  fft128_mk_tw(tws, twc, 1.0f, lane);
  #pragma unroll
  for (int i = 0; i < 4; i++){
    int rl = wv*4 + i;
    int row = r0 + rl;
    long ib = (long)plane*S + row*128;
    float z0r = Ere[ib + lane], z0i = Eim[ib + lane];
    float z1r = Ere[ib + lane + 64], z1i = Eim[ib + lane + 64];
    fft128(z0r, z0i, z1r, z1i, tws, twc, lane);
    int k = __brev(lane) >> 25;
    T[k][rl]     = sqrtf(z0r*z0r + z0i*z0i) * (1.0f/16384.0f);
    T[k + 1][rl] = sqrtf(z1r*z1r + z1i*z1i) * (1.0f/16384.0f);
  }
  __syncthreads();
  int b = plane >> 6, ch = plane & 63;
  float* out = A + ((long)(b*128 + ch)) * S + r0;
  #pragma unroll
  for (int i = 0; i < 8; i++){
    int idx = threadIdx.x + i*256;
    int k2 = idx >> 4, rl = idx & 15;
    out[(long)k2*128 + rl] = T[k2][rl];
  }
}

// ---------------- attention stats: fused norms+gram partials ----------------
__global__ __launch_bounds__(256) void gram_part_kernel(const float* __restrict__ Dre,
    const float* __restrict__ Dim, float* __restrict__ PART){
  int bh = blockIdx.x, slab = blockIdx.y;
  long base = (long)bh * 8 * S;
  int n0 = slab * 2048;
  float accr[36], acci[36], nsq[8];
  #pragma unroll
  for (int i = 0; i < 36; i++){ accr[i] = 0.f; acci[i] = 0.f; }
  #pragma unroll
  for (int i = 0; i < 8; i++) nsq[i] = 0.f;
  for (int it = 0; it < 8; it++){
    int n = n0 + it*256 + threadIdx.x;
    float xr[8], xi[8];
    #pragma unroll
    for (int c = 0; c < 8; c++){
      xr[c] = Dre[base + (long)c*S + n];
      xi[c] = Dim[base + (long)c*S + n];
      nsq[c] += xr[c]*xr[c] + xi[c]*xi[c];
    }
    int t = 0;
    #pragma unroll
    for (int c = 0; c < 8; c++)
      #pragma unroll
      for (int d = c; d < 8; d++){
        accr[t] += xr[c]*xr[d] - xi[c]*xi[d];
        acci[t] += xr[c]*xi[d] + xi[c]*xr[d];
        t++;
      }
  }
  __shared__ float red[4][80];
  int wv = threadIdx.x >> 6, lane = threadIdx.x & 63;
  #pragma unroll
  for (int i = 0; i < 80; i++){
    float v = (i < 36) ? accr[i] : (i < 72) ? acci[i - 36] : nsq[i - 72];
    #pragma unroll
    for (int o = 32; o; o >>= 1) v += __shfl_xor(v, o, 64);
    if (lane == 0) red[wv][i] = v;
  }
  __syncthreads();
  if (threadIdx.x < 80){
    int i = threadIdx.x;
    PART[(long)(bh*8 + slab)*80 + i] = red[0][i] + red[1][i] + red[2][i] + red[3][i];
  }
}

// attn2: reduce PART in-kernel, then per-(c,d) lane softmax + F8^{-1} fold
__global__ void attn2f_kernel(const float* __restrict__ PART,
    const float* __restrict__ temp, float* __restrict__ ATT2){
  __shared__ float ssum[80];
  __shared__ float sar[64], sai[64];
  int bh = blockIdx.x;
  int t = threadIdx.x;           // 0..127
  if (t < 80){
    float s = 0.f;
    for (int i = 0; i < 8; i++) s += PART[(long)(bh*8 + i)*80 + t];
    ssum[t] = s;
  }
  __syncthreads();
  if (t >= 64) return;
  int lane = t;
  int c = lane >> 3, d = lane & 7;
  int lo = min(c, d), hi = max(c, d);
  int t2 = lo*8 - lo*(lo - 1)/2 + (hi - lo);
  float nnc = fmaxf(sqrtf(ssum[72 + c]), 1e-12f);
  float nnd = fmaxf(sqrtf(ssum[72 + d]), 1e-12f);
  float inv = temp[bh & 7] / (nnc * nnd);
  float ar = ssum[t2] * inv, ai = ssum[36 + t2] * inv;
  float m = ar;
  m = fmaxf(m, __shfl_xor(m, 1, 64)); m = fmaxf(m, __shfl_xor(m, 2, 64)); m = fmaxf(m, __shfl_xor(m, 4, 64));
  float e = __expf(ar - m);
  float su = e;
  su += __shfl_xor(su, 1, 64); su += __shfl_xor(su, 2, 64); su += __shfl_xor(su, 4, 64);
  ar = e / su;
  m = ai;
  m = fmaxf(m, __shfl_xor(m, 1, 64)); m = fmaxf(m, __shfl_xor(m, 2, 64)); m = fmaxf(m, __shfl_xor(m, 4, 64));
  e = __expf(ai - m);
  su = e;
  su += __shfl_xor(su, 1, 64); su += __shfl_xor(su, 2, 64); su += __shfl_xor(su, 4, 64);
  ai = e / su;
  sar[lane] = ar; sai[lane] = ai;
  __syncthreads();
  const float ct[8] = {1.f, 0.70710678f, 0.f, -0.70710678f, -1.f, -0.70710678f, 0.f, 0.70710678f};
  const float st[8] = {0.f, 0.70710678f, 1.f, 0.70710678f, 0.f, -0.70710678f, -1.f, -0.70710678f};
  int cp = c;
  float sr = 0.f, si = 0.f;
  #pragma unroll
  for (int cc = 0; cc < 8; cc++){
    int k = (cc * cp) & 7;
    float a = sar[cc*8 + d], b2 = sai[cc*8 + d];
    sr += ct[k]*a - st[k]*b2;
    si += ct[k]*b2 + st[k]*a;
  }
  float2 v; v.x = sr * 0.125f; v.y = si * 0.125f;
  ((float2*)ATT2)[bh*64 + lane] = v;
}

__global__ __launch_bounds__(256) void apply_attn_kernel(const float* __restrict__ Dre,
    const float* __restrict__ Dim, const float* __restrict__ ATT2,
    float* __restrict__ Ere, float* __restrict__ Eim){
  int bh = blockIdx.y;
  int px = blockIdx.x*1024 + (threadIdx.x & 63)*4 + (threadIdx.x >> 6)*256;
  long base = (long)bh * 8 * S + px;
  float4 ar[8], ai[8];
  #pragma unroll
  for (int i = 0; i < 8; i++){
    ar[i].x = ar[i].y = ar[i].z = ar[i].w = 0.f;
    ai[i].x = ai[i].y = ai[i].z = ai[i].w = 0.f;
  }
  #pragma unroll
  for (int d = 0; d < 8; d++){
    float4 xr = *(const float4*)(Dre + base + (long)d*S);
    float4 xi = *(const float4*)(Dim + base + (long)d*S);
    #pragma unroll
    for (int cp = 0; cp < 8; cp++){
      float wr = ATT2[bh*128 + (cp*8 + d)*2];
      float wi = ATT2[bh*128 + (cp*8 + d)*2 + 1];
      ar[cp].x += wr*xr.x - wi*xi.x;  ai[cp].x += wr*xi.x + wi*xr.x;
      ar[cp].y += wr*xr.y - wi*xi.y;  ai[cp].y += wr*xi.y + wi*xr.y;
      ar[cp].z += wr*xr.z - wi*xi.z;  ai[cp].z += wr*xi.z + wi*xr.z;
      ar[cp].w += wr*xr.w - wi*xi.w;  ai[cp].w += wr*xi.w + wi*xr.w;
    }
  }
  #pragma unroll
  for (int cp = 0; cp < 8; cp++){
    *(float4*)(Ere + base + (long)cp*S) = ar[cp];
    *(float4*)(Eim + base + (long)cp*S) = ai[cp];
  }
}

// gate hidden: H[b][j][px] = relu(bn(wa_j . f.real))  (4 ch only)
__global__ __launch_bounds__(256) void gateh_kernel(const float* __restrict__ Dre,
    const float* __restrict__ wa, const float* __restrict__ sbwa, float* __restrict__ H){
  int b = blockIdx.y;
  int px = blockIdx.x*256 + threadIdx.x;
  long base = (long)b * 64 * S + px;
  float h0 = 0.f, h1 = 0.f, h2 = 0.f, h3 = 0.f;
  for (int ci = 0; ci < 64; ci++){
    float x = Dre[base + (long)ci*S];
    h0 += wa[ci]*x; h1 += wa[64 + ci]*x; h2 += wa[128 + ci]*x; h3 += wa[192 + ci]*x;
  }
  long ob = (long)b * 4 * S + px;
  H[ob]       = fmaxf(h0*sbwa[0] + sbwa[4], 0.f);
  H[ob + S]   = fmaxf(h1*sbwa[1] + sbwa[5], 0.f);
  H[ob + 2*S] = fmaxf(h2*sbwa[2] + sbwa[6], 0.f);
  H[ob + 3*S] = fmaxf(h3*sbwa[3] + sbwa[7], 0.f);
}

// ---------------- small kernels ----------------
__global__ __launch_bounds__(256) void mean_kernel(const float* __restrict__ A, float* __restrict__ M){
  int p = blockIdx.x;
  long base = (long)p * S;
  float s = 0.f;
  for (int n = threadIdx.x; n < S; n += 256) s += A[base + n];
  #pragma unroll
  for (int o = 32; o; o >>= 1) s += __shfl_xor(s, o, 64);
  __shared__ float sm[4];
  if ((threadIdx.x & 63) == 0) sm[threadIdx.x >> 6] = s;
  __syncthreads();
  if (threadIdx.x == 0) M[p] = (sm[0] + sm[1] + sm[2] + sm[3]) * (1.0f/16384.0f);
}

__global__ void c5_kernel(const float* __restrict__ W5, const float* __restrict__ sb5,
    const float* __restrict__ M, float* __restrict__ C5){
  int t = threadIdx.x;
  if (t >= 256) return;
  int b = t >> 6, co = t & 63;
  float s = 0.f;
  for (int ci = 0; ci < 128; ci++) s += W5[co*128 + ci] * M[b*128 + ci];
  C5[t] = fmaxf(s * sb5[co] + sb5[64 + co], 0.f);
}

__global__ void beff_kernel(const float* __restrict__ WF, const float* __restrict__ sbf,
    const float* __restrict__ C5, float* __restrict__ BEFF){
  int t = threadIdx.x;
  if (t >= 256) return;
  int b = t >> 6, co = t & 63;
  float s = 0.f;
  for (int j = 0; j < 64; j++) s += WF[co*320 + 256 + j] * C5[b*64 + j];
  BEFF[t] = s * sbf[co] + sbf[64 + co];
}

// output is FLOAT32 — write float4
__global__ __launch_bounds__(256) void ob_kernel(const float* __restrict__ Tin,
    const float* __restrict__ wob, const float* __restrict__ bob, float* __restrict__ out){
  int b = blockIdx.y;
  int px = blockIdx.x*1024 + (threadIdx.x & 63)*4 + (threadIdx.x >> 6)*256;
  float b0 = bob[0];
  float4 a; a.x = b0; a.y = b0; a.z = b0; a.w = b0;
  for (int ci = 0; ci < 32; ci++){
    float4 v = *(const float4*)(Tin + ((long)b*32 + ci)*S + px);
    float w = wob[ci];
    a.x += w*v.x; a.y += w*v.y; a.z += w*v.z; a.w += w*v.w;
  }
  *(float4*)(out + (long)b*S + px) = a;
}

// ---------------- launch ----------------
extern "C" void kernel_launch(void* const* d_in, const int* in_sizes, int n_in,
                              void* d_out, int out_size, void* d_ws, size_t ws_size,
                              hipStream_t stream){
  float* ws = (float*)d_ws;
  Ptrs P;
  for (int i = 0; i < 43 && i < n_in; i++) P.p[i] = (const float*)d_in[i];
  float* out = (float*)d_out;

  float* A   = ws + O_A;
  float* FIN = ws + O_FIN;
  float* CC  = ws + O_CC;
  float* DRE = ws + O_DRE;
  float* DIMp= ws + O_DIMG;
  float* ERE = ws + O_ERE;
  float* EIM = ws + O_EIM;
  float* G   = ws + O_G;
  float* H   = ws + O_H;

  unsigned short* XT  = (unsigned short*)(ws + O_DRE);
  unsigned short* WHd = (unsigned short*)(ws + O_CC);
  unsigned short* WLd = (unsigned short*)(ws + O_CC + 147456);
  unsigned short* WB  = (unsigned short*)(ws + O_WB);
  unsigned short* WP  = (unsigned short*)(ws + O_WP);
  unsigned short* XP  = (unsigned short*)(ws + O_ERE);

  prep_sb_kernel<<<dim3(9), dim3(256), 0, stream>>>(P, ws);
  xpad_kernel<<<dim3(130, 4), dim3(256), 0, stream>>>(P.p[0], XT);
  wt_kernel<<<dim3(128), dim3(256), 0, stream>>>(P.p[1], WHd, WLd);
  wtg_kernel<<<dim3(16, 4), dim3(256), 0, stream>>>(P, WB);
  wtp_kernel<<<dim3(8, 3), dim3(256), 0, stream>>>(P, WP);

  conv3x3_mfma_kernel<1,8,64><<<dim3(1024), dim3(256), 0, stream>>>(
      XT, WHd, WLd, ws + O_SBDC, A);

  mean_kernel<<<dim3(512), dim3(256), 0, stream>>>(A, ws + O_M);
  c5_kernel<<<dim3(1), dim3(256), 0, stream>>>(P.p[21], ws + O_SB5, ws + O_M, ws + O_C5);
  beff_kernel<<<dim3(1), dim3(256), 0, stream>>>(P.p[33], ws + O_SBF, ws + O_C5, ws + O_BEFF);

  // c1 -> FIN channels [0,64)  (MFMA)
  conv1x1_mfma_kernel<0,4><<<dim3(512), dim3(256), 0, stream>>>(
      A, 128*S, WP, WP + 8192, ws + O_SB1, nullptr, nullptr, 0, FIN, 256*S);

  for (int k = 0; k < 3; k++){
    const float* sb = ws + (k == 0 ? O_SB2 : k == 1 ? O_SB3 : O_SB4);
    const float* in2 = (k == 0) ? nullptr : FIN + (long)(64*k)*S;
    unsigned short* wh = WB + (k == 0 ? 0 : k == 1 ? 73728 : 147456);
    if (k == 0){
      xpad64_kernel<3><<<dim3(134, 4), dim3(256), 0, stream>>>(FIN, in2, 256*S, XP);
      conv3x3_mfma_kernel<3,2,64><<<dim3(512), dim3(256), 0, stream>>>(
          XP, wh, wh + 36864, sb, CC);
    } else if (k == 1){
      xpad64_kernel<5><<<dim3(138, 4), dim3(256), 0, stream>>>(FIN, in2, 256*S, XP);
      conv3x3_mfma_kernel<5,2,64><<<dim3(512), dim3(256), 0, stream>>>(
          XP, wh, wh + 36864, sb, CC);
    } else {
      xpad64_kernel<7><<<dim3(142, 4), dim3(256), 0, stream>>>(FIN, in2, 256*S, XP);
      conv3x3_mfma_kernel<7,2,64><<<dim3(512), dim3(256), 0, stream>>>(
          XP, wh, wh + 36864, sb, CC);
    }

    // f = fft2(c)
    fft_rows_fwd_kernel<<<dim3(8192), dim3(256), 0, stream>>>(CC, DRE, DIMp);
    fft_cols_kernel<0><<<dim3(8, 256), dim3(256), 0, stream>>>(
        DRE, DIMp, DRE, DIMp, nullptr, nullptr, nullptr);
    // attention stats
    gram_part_kernel<<<dim3(32, 8), dim3(256), 0, stream>>>(DRE, DIMp, ws + O_PART);
    attn2f_kernel<<<dim3(32), dim3(128), 0, stream>>>(ws + O_PART, P.p[25], ws + O_ATT2);
    // gate hidden (4 ch) from f.real
    gateh_kernel<<<dim3(64, 4), dim3(256), 0, stream>>>(DRE, P.p[27], ws + O_SBWA, H);
    // ol = |ifft2(sigmoid(wb.h+bwb) * f)| -> A channels [64,128)
    fft_cols_kernel<1><<<dim3(8, 256), dim3(256), 0, stream>>>(
        DRE, DIMp, ERE, EIM, H, P.p[31], P.p[32]);
    ifft_rows_abs_ol_kernel<<<dim3(8192), dim3(256), 0, stream>>>(ERE, EIM, A);
    // of = |ifft_{c,n}(attn @ qkv)| -> A channels [0,64)
    apply_attn_kernel<<<dim3(16, 32), dim3(256), 0, stream>>>(DRE, DIMp, ws + O_ATT2, ERE, EIM);
    fft_cols_kernel<2><<<dim3(8, 256), dim3(256), 0, stream>>>(
        ERE, EIM, ERE, EIM, nullptr, nullptr, nullptr);
    ifft_rows_abs_ofT_kernel<<<dim3(8, 256), dim3(256), 0, stream>>>(ERE, EIM, A);
    // F_k = w_po @ concat(of, ol) + c  (MFMA)
    conv1x1_mfma_kernel<1,4><<<dim3(512), dim3(256), 0, stream>>>(
        A, 128*S, WP + 16384, WP + 24576, nullptr, nullptr, CC, 64*S,
        FIN + (long)(64*(k + 1))*S, 256*S);
  }

  // fused = bn_relu(w_f @ concat(c1,F2,F3,F4) + bias_eff(c5)) -> CC  (MFMA)
  conv1x1_mfma_kernel<2,8><<<dim3(512), dim3(256), 0, stream>>>(
      FIN, 256*S, WP + 32768, WP + 49152, ws + O_SBF, ws + O_BEFF, nullptr, 0, CC, 64*S);
  xpad64_kernel<1><<<dim3(130, 4), dim3(256), 0, stream>>>(CC, nullptr, 64*S, XP);
  conv3x3_mfma_kernel<1,2,32><<<dim3(512), dim3(256), 0, stream>>>(
      XP, WB + 221184, WB + 221184 + 18432, ws + O_SBOA, G);
  ob_kernel<<<dim3(16, 4), dim3(256), 0, stream>>>(G, P.p[41], P.p[42], out);
}

// Round 11
// 984.307 us; speedup vs baseline: 1.5821x; 1.0920x over previous
//
#include <hip/hip_runtime.h>

#define S 16384
#define PI_F 3.14159265358979f

struct Ptrs { const float* p[43]; };

// ---- workspace layout (float offsets) ----
enum : int {
  O_SBDC=0, O_SB1=256, O_SB2=512, O_SB3=768, O_SB4=1024, O_SB5=1280,
  O_SBWA=1536, O_SBF=1792, O_SBOA=2048,
  O_M=2304, O_C5=2816, O_NRM=3072, O_GRAM=3328, O_ATT2=7424, O_BEFF=11520,
  O_WB=16384,        // packed hi/lo bf16 weights for dil/oa convs
  O_PART=147456,     // gram/norm partials [256][80]
  O_H=180224,        // gate hidden H[4][4][S] (1 MB)
  O_WP=442368,       // packed hi/lo bf16 1x1 weights (w1|po|wf, 128 KB)
  O_A=524288,        // [4][128][S] fp32 xd; later AB bf16 [4][128][S] (of|ol) overlays
  O_FIN=8912896,     // [4][256][S]  c1 | F2 | F3 | F4
  O_CC=25690112,     // [4][64][S]   c2/c3/c4, later fused; conv_dc WH/WL live here early
  O_DRE=29884416, O_DIMG=34078720,   // f (complex, bf16 SoA); XT lives here pre-FFT
  O_ERE=38273024, O_EIM=42467328,    // scratch complex bf16; dil/oa XP lives here transiently
  O_G=46661632       // [4][64][S]   later t (oa out, 32ch)
};

typedef short bfrag __attribute__((ext_vector_type(8)));   // 8 bf16 = 4 VGPR
typedef float ffrag __attribute__((ext_vector_type(4)));   // 4 fp32 acc

__device__ __forceinline__ float bf2f(unsigned short u){
  union { unsigned int i; float f; } v; v.i = ((unsigned int)u) << 16; return v.f;
}
__device__ __forceinline__ unsigned short f2bf(float f){
  unsigned int x = __float_as_uint(f);
  unsigned int r = x + 0x7fffu + ((x >> 16) & 1u);
  return (unsigned short)(r >> 16);
}

// ---------------- param prep ----------------
__global__ void prep_sb_kernel(Ptrs P, float* ws){
  const float r = rsqrtf(1.0f + 1e-5f);
  int bi=0, si=0, oi=0, C=0, dst=0;
  switch (blockIdx.x){
    case 0: bi=2; si=3; oi=4; C=128; dst=O_SBDC; break;
    case 1: bi=6; si=7; oi=8; C=64; dst=O_SB1; break;
    case 2: bi=10; si=11; oi=12; C=64; dst=O_SB2; break;
    case 3: bi=14; si=15; oi=16; C=64; dst=O_SB3; break;
    case 4: bi=18; si=19; oi=20; C=64; dst=O_SB4; break;
    case 5: bi=22; si=23; oi=24; C=64; dst=O_SB5; break;
    case 6: bi=28; si=29; oi=30; C=4;  dst=O_SBWA; break;
    case 7: bi=34; si=35; oi=36; C=64; dst=O_SBF; break;
    default: bi=38; si=39; oi=40; C=32; dst=O_SBOA; break;
  }
  for (int c = threadIdx.x; c < C; c += 256){
    float bb = P.p[bi][c], ss = P.p[si][c], oo = P.p[oi][c];
    float sc = ss * r;
    ws[dst + c] = sc;
    ws[dst + C + c] = bb * sc + oo;
  }
}

// ---------------- conv_dc prepacks ----------------
__global__ __launch_bounds__(256) void xpad_kernel(const float* __restrict__ x,
    unsigned short* __restrict__ XT){
  int yy = blockIdx.x, b = blockIdx.y;
  long obase = ((long)(b*130) + yy) * (130L*256);
  int tid = threadIdx.x;
  if (yy == 0 || yy == 129){
    uint4 z; z.x=0; z.y=0; z.z=0; z.w=0;
    for (int i = tid; i < 130*256/8; i += 256)
      *(uint4*)(XT + obase + (long)i*8) = z;
    return;
  }
  __shared__ float LT[64][129];
  int y = yy - 1;
  for (int c0 = 0; c0 < 256; c0 += 64){
    for (int idx = tid; idx < 64*128; idx += 256){
      int ci = idx >> 7, xx = idx & 127;
      LT[ci][xx] = x[((long)(b*256 + c0 + ci)*128 + y)*128 + xx];
    }
    __syncthreads();
    for (int idx = tid; idx < 128*16; idx += 256){
      int xp = idx >> 4, c4 = (idx & 15)*4;
      ushort4 v;
      v.x = f2bf(LT[c4][xp]);   v.y = f2bf(LT[c4+1][xp]);
      v.z = f2bf(LT[c4+2][xp]); v.w = f2bf(LT[c4+3][xp]);
      *(ushort4*)(XT + obase + (long)(xp+1)*256 + c0 + c4) = v;
    }
    __syncthreads();
  }
  if (tid < 64){
    ushort4 z; z.x=0; z.y=0; z.z=0; z.w=0;
    *(ushort4*)(XT + obase + tid*4) = z;
    *(ushort4*)(XT + obase + 129L*256 + tid*4) = z;
  }
}

__global__ void wt_kernel(const float* __restrict__ w, unsigned short* __restrict__ WH,
    unsigned short* __restrict__ WL){
  for (int e = blockIdx.x*256 + threadIdx.x; e < 294912; e += gridDim.x*256){
    int c32 = e & 31, co = (e >> 5) & 127, kc = (e >> 12) & 7, sh = e >> 15;
    int ky = sh / 3, kx = sh - ky*3;
    int ci = kc*32 + c32;
    float v = w[((long)(co*256 + ci)*3 + ky)*3 + kx];
    unsigned short h = f2bf(v);
    WH[e] = h;
    WL[e] = f2bf(v - bf2f(h));
  }
}

__global__ void wtg_kernel(Ptrs P, unsigned short* __restrict__ WB){
  const float* w; int cout; long off;
  switch (blockIdx.y){
    case 0: w = P.p[9];  cout = 64; off = 0;      break;
    case 1: w = P.p[13]; cout = 64; off = 73728;  break;
    case 2: w = P.p[17]; cout = 64; off = 147456; break;
    default: w = P.p[37]; cout = 32; off = 221184; break;
  }
  int total = 576*cout;
  unsigned short* WH = WB + off;
  unsigned short* WL = WH + total;
  for (int e = blockIdx.x*256 + threadIdx.x; e < total; e += gridDim.x*256){
    int c32 = e & 31;
    int co = (e >> 5) & (cout - 1);
    int kc = (e / (32*cout)) & 1;
    int sh = e / (64*cout);
    int ky = sh/3, kx = sh - ky*3;
    int ci = kc*32 + c32;
    float v = w[((long)(co*64 + ci)*3 + ky)*3 + kx];
    unsigned short h = f2bf(v);
    WH[e] = h;
    WL[e] = f2bf(v - bf2f(h));
  }
}

// 1x1 conv weights -> [kc][64co][32] hi|lo at WP offsets (w1: 0, po: 16384, wf: 32768)
__global__ void wtp_kernel(Ptrs P, unsigned short* __restrict__ WP){
  const float* w; int KC, wstr; long off;
  switch (blockIdx.y){
    case 0: w = P.p[5];  KC = 4; wstr = 128; off = 0;     break;
    case 1: w = P.p[26]; KC = 4; wstr = 128; off = 16384; break;
    default: w = P.p[33]; KC = 8; wstr = 320; off = 32768; break;
  }
  int total = KC*64*32;
  unsigned short* WH = WP + off;
  unsigned short* WL = WH + total;
  for (int e = blockIdx.x*256 + threadIdx.x; e < total; e += gridDim.x*256){
    int c32 = e & 31, co = (e >> 5) & 63, kc = e >> 11;
    float v = w[(long)co*wstr + kc*32 + c32];
    unsigned short h = f2bf(v);
    WH[e] = h;
    WL[e] = f2bf(v - bf2f(h));
  }
}

template<int DIL>
__global__ __launch_bounds__(256) void xpad64_kernel(const float* __restrict__ in1,
    const float* __restrict__ in2, long in_bs, unsigned short* __restrict__ XP){
  constexpr int TW = 128 + 2*DIL;
  int yy = blockIdx.x, b = blockIdx.y;
  long obase = (long)(b*TW + yy) * TW * 64;
  int tid = threadIdx.x;
  if (yy < DIL || yy >= 128 + DIL){
    uint4 z; z.x=0; z.y=0; z.z=0; z.w=0;
    for (int i = tid; i < TW*8; i += 256)
      *(uint4*)(XP + obase + (long)i*8) = z;
    return;
  }
  __shared__ float LT[64][129];
  int y = yy - DIL;
  const float* p1 = in1 + (long)b*in_bs + (long)y*128;
  const float* p2 = in2 ? in2 + (long)b*in_bs + (long)y*128 : nullptr;
  for (int idx = tid; idx < 64*128; idx += 256){
    int ci = idx >> 7, xx = idx & 127;
    float v = p1[(long)ci*S + xx];
    if (p2) v += p2[(long)ci*S + xx];
    LT[ci][xx] = v;
  }
  __syncthreads();
  for (int i = tid; i < 2*DIL*16; i += 256){
    int side = i / (DIL*16);
    int r = i - side*(DIL*16);
    int xcol = side ? (128 + DIL + (r >> 4)) : (r >> 4);
    ushort4 z; z.x=0; z.y=0; z.z=0; z.w=0;
    *(ushort4*)(XP + obase + (long)xcol*64 + (r & 15)*4) = z;
  }
  for (int idx = tid; idx < 128*16; idx += 256){
    int xp = idx >> 4, c4 = (idx & 15)*4;
    ushort4 v;
    v.x = f2bf(LT[c4][xp]);   v.y = f2bf(LT[c4+1][xp]);
    v.z = f2bf(LT[c4+2][xp]); v.w = f2bf(LT[c4+3][xp]);
    *(ushort4*)(XP + obase + (long)(xp + DIL)*64 + c4) = v;
  }
}

// ---------------- unified 3x3 conv via MFMA implicit GEMM ------
template<int DIL, int KC, int NBLK>
__global__ __launch_bounds__(256) void conv3x3_mfma_kernel(
    const unsigned short* __restrict__ XP,
    const unsigned short* __restrict__ WH, const unsigned short* __restrict__ WL,
    const float* __restrict__ scbi, float* __restrict__ out){
  constexpr int CIN = KC*32;
  constexpr int TW = 128 + 2*DIL;
  constexpr int STEPS = 9*KC;
  constexpr int MI = (NBLK == 64) ? 4 : 2;
  constexpr int LDA = 36;
  __shared__ unsigned short Als[128*LDA];
  __shared__ unsigned short BHs[NBLK*LDA];
  __shared__ unsigned short BLs[NBLK*LDA];
  int bid = blockIdx.x;
  int y = (bid & 7)*16 + ((bid >> 3) & 15);
  int b = (bid >> 7) & 3;
  int n2 = bid >> 9;
  int nb = gridDim.x >> 9; if (nb == 0) nb = 1;
  int coutTotal = nb * NBLK;
  int tid = threadIdx.x, wv = tid >> 6, lane = tid & 63;
  int mt0 = (NBLK == 64) ? (wv & 1)*4 : wv*2;
  int nt0 = (NBLK == 64) ? (wv >> 1)*2 : 0;
  ffrag acc[MI][2];
  #pragma unroll
  for (int i = 0; i < MI; i++)
    #pragma unroll
    for (int j = 0; j < 2; j++)
      #pragma unroll
      for (int r = 0; r < 4; r++) acc[i][j][r] = 0.f;

  int pixq = tid >> 2, qq = tid & 3;
  int kq = (lane >> 4)*8, rown = lane & 15;
  int wrA0 = pixq*LDA + qq*8;
  int wrA1 = (pixq + 64)*LDA + qq*8;
  int wrB  = (tid >> 2)*LDA + qq*8;

  uint4 A0, A1, BHr, BLr;
  {
    long abase = ((long)(b*TW + y)*TW)*CIN + qq*8;
    A0 = *(const uint4*)(XP + abase + (long)pixq*CIN);
    A1 = *(const uint4*)(XP + abase + (long)(pixq + 64)*CIN);
    long gw = (long)n2*NBLK*32;
    if (NBLK == 64 || tid < 128){
      BHr = *(const uint4*)(WH + gw + tid*8);
      BLr = *(const uint4*)(WL + gw + tid*8);
    }
  }
  for (int step = 0; step < STEPS; step++){
    __syncthreads();
    *(uint4*)&Als[wrA0] = A0;
    *(uint4*)&Als[wrA1] = A1;
    if (NBLK == 64 || tid < 128){
      *(uint4*)&BHs[wrB] = BHr;
      *(uint4*)&BLs[wrB] = BLr;
    }
    __syncthreads();
    if (step + 1 < STEPS){
      int s2 = step + 1;
      int sh = s2 / KC, kc = s2 - sh*KC;
      int ky = sh / 3, kx = sh - ky*3;
      long abase = ((long)(b*TW + y + ky*DIL)*TW + kx*DIL)*CIN + kc*32 + qq*8;
      A0 = *(const uint4*)(XP + abase + (long)pixq*CIN);
      A1 = *(const uint4*)(XP + abase + (long)(pixq + 64)*CIN);
      long gw = ((long)s2*coutTotal + n2*NBLK)*32;
      if (NBLK == 64 || tid < 128){
        BHr = *(const uint4*)(WH + gw + tid*8);
        BLr = *(const uint4*)(WL + gw + tid*8);
      }
    }
    bfrag af[MI], bhf[2], blf[2];
    #pragma unroll
    for (int i = 0; i < MI; i++)
      af[i] = *(const bfrag*)&Als[((mt0 + i)*16 + rown)*LDA + kq];
    #pragma unroll
    for (int j = 0; j < 2; j++){
      bhf[j] = *(const bfrag*)&BHs[((nt0 + j)*16 + rown)*LDA + kq];
      blf[j] = *(const bfrag*)&BLs[((nt0 + j)*16 + rown)*LDA + kq];
    }
    #pragma unroll
    for (int i = 0; i < MI; i++)
      #pragma unroll
      for (int j = 0; j < 2; j++){
        acc[i][j] = __builtin_amdgcn_mfma_f32_16x16x32_bf16(af[i], blf[j], acc[i][j], 0, 0, 0);
        acc[i][j] = __builtin_amdgcn_mfma_f32_16x16x32_bf16(af[i], bhf[j], acc[i][j], 0, 0, 0);
      }
  }
  #pragma unroll
  for (int i = 0; i < MI; i++){
    int pixel = (mt0 + i)*16 + (lane >> 4)*4;
    #pragma unroll
    for (int j = 0; j < 2; j++){
      int co = n2*NBLK + (nt0 + j)*16 + (lane & 15);
      float sc = scbi[co], bb = scbi[coutTotal + co];
      float* op = out + ((long)(b*coutTotal + co))*S + y*128 + pixel;
      #pragma unroll
      for (int r = 0; r < 4; r++)
        op[r] = fmaxf(acc[i][j][r]*sc + bb, 0.f);
    }
  }
}

// ---------------- 1x1 conv via MFMA (fp32 or bf16 planar in) ----
// MODE 0: bn_relu | MODE 1: + residual | MODE 2: bn w/ per-(b,co) bias, relu
template<int MODE, int KC, int BF16IN>
__global__ __launch_bounds__(256) void conv1x1_mfma_kernel(
    const void* __restrict__ inv, long in_bs,
    const unsigned short* __restrict__ WH, const unsigned short* __restrict__ WL,
    const float* __restrict__ scbi, const float* __restrict__ beff,
    const float* __restrict__ res, long res_bs,
    float* __restrict__ out, long out_bs){
  constexpr int LDA = 36;
  __shared__ unsigned short Als[128*LDA];
  __shared__ unsigned short BHs[64*LDA];
  __shared__ unsigned short BLs[64*LDA];
  int bid = blockIdx.x;
  int y = (bid & 7)*16 + ((bid >> 3) & 15);
  int b = bid >> 7;
  int tid = threadIdx.x, wv = tid >> 6, lane = tid & 63;
  int mt0 = (wv & 1)*4, nt0 = (wv >> 1)*2;
  ffrag acc[4][2];
  #pragma unroll
  for (int i = 0; i < 4; i++)
    #pragma unroll
    for (int j = 0; j < 2; j++)
      #pragma unroll
      for (int r = 0; r < 4; r++) acc[i][j][r] = 0.f;
  int pq = tid & 31, cg = tid >> 5;
  int kq = (lane >> 4)*8, rown = lane & 15;
  int wrB = (tid >> 2)*LDA + (tid & 3)*8;
  const float* ibf = (const float*)inv + (long)b*in_bs + y*128;
  const unsigned short* ibs = (const unsigned short*)inv + (long)b*in_bs + y*128;
  unsigned short a[16];
  uint4 BHr, BLr;
  #pragma unroll
  for (int cc = 0; cc < 4; cc++)
    #pragma unroll
    for (int i = 0; i < 4; i++){
      if (BF16IN) a[cc*4 + i] = ibs[(long)(cg*4 + cc)*S + pq + 32*i];
      else        a[cc*4 + i] = f2bf(ibf[(long)(cg*4 + cc)*S + pq + 32*i]);
    }
  BHr = *(const uint4*)(WH + tid*8);
  BLr = *(const uint4*)(WL + tid*8);
  for (int kc = 0; kc < KC; kc++){
    __syncthreads();
    #pragma unroll
    for (int i = 0; i < 4; i++){
      ushort4 v;
      v.x = a[0 + i];  v.y = a[4 + i];
      v.z = a[8 + i];  v.w = a[12 + i];
      *(ushort4*)&Als[(pq + 32*i)*LDA + cg*4] = v;
    }
    *(uint4*)&BHs[wrB] = BHr;
    *(uint4*)&BLs[wrB] = BLr;
    __syncthreads();
    if (kc + 1 < KC){
      #pragma unroll
      for (int cc = 0; cc < 4; cc++)
        #pragma unroll
        for (int i = 0; i < 4; i++){
          long off = (long)((kc + 1)*32 + cg*4 + cc)*S + pq + 32*i;
          if (BF16IN) a[cc*4 + i] = ibs[off];
          else        a[cc*4 + i] = f2bf(ibf[off]);
        }
      long gw = (long)(kc + 1)*2048;
      BHr = *(const uint4*)(WH + gw + tid*8);
      BLr = *(const uint4*)(WL + gw + tid*8);
    }
    bfrag af[4], bhf[2], blf[2];
    #pragma unroll
    for (int i = 0; i < 4; i++)
      af[i] = *(const bfrag*)&Als[((mt0 + i)*16 + rown)*LDA + kq];
    #pragma unroll
    for (int j = 0; j < 2; j++){
      bhf[j] = *(const bfrag*)&BHs[((nt0 + j)*16 + rown)*LDA + kq];
      blf[j] = *(const bfrag*)&BLs[((nt0 + j)*16 + rown)*LDA + kq];
    }
    #pragma unroll
    for (int i = 0; i < 4; i++)
      #pragma unroll
      for (int j = 0; j < 2; j++){
        acc[i][j] = __builtin_amdgcn_mfma_f32_16x16x32_bf16(af[i], blf[j], acc[i][j], 0, 0, 0);
        acc[i][j] = __builtin_amdgcn_mfma_f32_16x16x32_bf16(af[i], bhf[j], acc[i][j], 0, 0, 0);
      }
  }
  #pragma unroll
  for (int i = 0; i < 4; i++){
    int pixel = (mt0 + i)*16 + (lane >> 4)*4;
    #pragma unroll
    for (int j = 0; j < 2; j++){
      int co = (nt0 + j)*16 + (lane & 15);
      float* op = out + (long)b*out_bs + (long)co*S + y*128 + pixel;
      #pragma unroll
      for (int r = 0; r < 4; r++){
        float v = acc[i][j][r];
        if (MODE == 0){
          v = fmaxf(v*scbi[co] + scbi[64 + co], 0.f);
        } else if (MODE == 1){
          v += res[(long)b*res_bs + (long)co*S + y*128 + pixel + r];
        } else {
          v = fmaxf(v*scbi[co] + beff[b*64 + co], 0.f);
        }
        op[r] = v;
      }
    }
  }
}

// ---------------- FFT-128 with hoisted lane twiddles ----------------
__device__ __forceinline__ void fft128_mk_tw(float (&tws)[8], float (&twc)[8],
                                             float sign, int lane){
  float a0 = sign * (2.0f*PI_F/128.0f) * (float)lane;
  __sincosf(a0, &tws[0], &twc[0]);
  int i = 1;
  #pragma unroll
  for (int h = 32; h >= 1; h >>= 1, i++){
    int j = lane & (h - 1);
    float a = sign * (2.0f*PI_F/128.0f) * (float)(j * (64/h));
    __sincosf(a, &tws[i], &twc[i]);
  }
}

__device__ __forceinline__ void fft128(float& z0r, float& z0i, float& z1r, float& z1i,
    const float (&tws)[8], const float (&twc)[8], int lane){
  {
    float ar = z0r, ai = z0i, br = z1r, bi = z1i;
    z0r = ar + br; z0i = ai + bi;
    float dr = ar - br, di = ai - bi;
    float s = tws[0], c = twc[0];
    z1r = dr*c - di*s; z1i = dr*s + di*c;
  }
  int idx = 1;
  #pragma unroll
  for (int h = 32; h >= 1; h >>= 1, idx++){
    float s = tws[idx], c = twc[idx];
    bool up = (lane & h) != 0;
    float pr, pi, nr, ni;
    pr = __shfl_xor(z0r, h, 64); pi = __shfl_xor(z0i, h, 64);
    if (!up){ nr = z0r + pr; ni = z0i + pi; }
    else { float dr = pr - z0r, di = pi - z0i; nr = dr*c - di*s; ni = dr*s + di*c; }
    z0r = nr; z0i = ni;
    pr = __shfl_xor(z1r, h, 64); pi = __shfl_xor(z1i, h, 64);
    if (!up){ nr = z1r + pr; ni = z1i + pi; }
    else { float dr = pr - z1r, di = pi - z1i; nr = dr*c - di*s; ni = dr*s + di*c; }
    z1r = nr; z1i = ni;
  }
}

// fp32 in -> bf16 complex out (k even -> ushort2 aligned)
__global__ __launch_bounds__(256) void fft_rows_fwd_kernel(const float* __restrict__ in,
    unsigned short* __restrict__ outRe, unsigned short* __restrict__ outIm){
  int line = blockIdx.x*4 + (threadIdx.x >> 6);
  int lane = threadIdx.x & 63;
  float tws[8], twc[8];
  fft128_mk_tw(tws, twc, -1.0f, lane);
  long ib = (long)line * 128;
  float z0r = in[ib + lane], z0i = 0.f;
  float z1r = in[ib + lane + 64], z1i = 0.f;
  fft128(z0r, z0i, z1r, z1i, tws, twc, lane);
  int k = __brev(lane) >> 25;
  ushort2 vr; vr.x = f2bf(z0r); vr.y = f2bf(z1r);
  ushort2 vi; vi.x = f2bf(z0i); vi.y = f2bf(z1i);
  *(ushort2*)(outRe + ib + k) = vr;
  *(ushort2*)(outIm + ib + k) = vi;
}

// MODE 0: fwd cols. MODE 1: premul inline-gate (H + wb + bwb), ifft cols.
// MODE 2: ifft cols + 4-step twiddle.  bf16 in/out.
template<int MODE>
__global__ __launch_bounds__(256) void fft_cols_kernel(
    const unsigned short* inRe, const unsigned short* inIm,
    unsigned short* outRe, unsigned short* outIm,
    const float* gate, const float* wb, const float* bwb){
  __shared__ float lre[128][17];
  __shared__ float lim[128][17];
  int plane = blockIdx.y;
  int cb = blockIdx.x * 16;
  int tid = threadIdx.x;
  long pbase = (long)plane * S;
  float w0=0.f, w1=0.f, w2=0.f, w3=0.f, bw=0.f;
  const float* Hb = nullptr;
  if (MODE == 1){
    int co = plane & 63;
    w0 = wb[co*4]; w1 = wb[co*4+1]; w2 = wb[co*4+2]; w3 = wb[co*4+3];
    bw = bwb[co];
    Hb = gate + (long)(plane >> 6) * 4 * S;
  }
  #pragma unroll
  for (int i = 0; i < 8; i++){
    int idx = tid + i*256;
    int r = idx >> 4, c = idx & 15;
    int pxl = r*128 + cb + c;
    long a = pbase + pxl;
    float re = bf2f(inRe[a]), im = bf2f(inIm[a]);
    if (MODE == 1){
      float hv = bw + w0*Hb[pxl] + w1*Hb[S + pxl] + w2*Hb[2*S + pxl] + w3*Hb[3*S + pxl];
      float g = 1.0f / (1.0f + __expf(-hv));
      re *= g; im *= g;
    }
    lre[r][c] = re; lim[r][c] = im;
  }
  __syncthreads();
  int wv = tid >> 6, lane = tid & 63;
  const float sign = (MODE == 0) ? -1.0f : 1.0f;
  float tws[8], twc[8];
  fft128_mk_tw(tws, twc, sign, lane);
  #pragma unroll
  for (int cc = 0; cc < 4; cc++){
    int c = wv*4 + cc;
    float z0r = lre[lane][c], z0i = lim[lane][c];
    float z1r = lre[lane + 64][c], z1i = lim[lane + 64][c];
    fft128(z0r, z0i, z1r, z1i, tws, twc, lane);
    int k = __brev(lane) >> 25;
    if (MODE == 2){
      int n2 = cb + c;
      float s, co;
      float a0 = (2.0f*PI_F/16384.0f) * (float)(n2 * k);
      __sincosf(a0, &s, &co);
      float t = z0r*co - z0i*s; z0i = z0r*s + z0i*co; z0r = t;
      float a1 = (2.0f*PI_F/16384.0f) * (float)(n2 * (k + 1));
      __sincosf(a1, &s, &co);
      t = z1r*co - z1i*s; z1i = z1r*s + z1i*co; z1r = t;
    }
    lre[k][c] = z0r;     lim[k][c] = z0i;
    lre[k + 1][c] = z1r; lim[k + 1][c] = z1i;
  }
  __syncthreads();
  #pragma unroll
  for (int i = 0; i < 8; i++){
    int idx = tid + i*256;
    int r = idx >> 4, c = idx & 15;
    long a = pbase + r*128 + cb + c;
    outRe[a] = f2bf(lre[r][c]); outIm[a] = f2bf(lim[r][c]);
  }
}

// ol -> AB channels [64,128)  (bf16 in, bf16 out)
__global__ __launch_bounds__(256) void ifft_rows_abs_ol_kernel(
    const unsigned short* __restrict__ Ere, const unsigned short* __restrict__ Eim,
    unsigned short* __restrict__ AB){
  int line = blockIdx.x*4 + (threadIdx.x >> 6);
  int lane = threadIdx.x & 63;
  float tws[8], twc[8];
  fft128_mk_tw(tws, twc, 1.0f, lane);
  int plane = line >> 7, row = line & 127;
  long ib = (long)plane*S + row*128;
  float z0r = bf2f(Ere[ib + lane]), z0i = bf2f(Eim[ib + lane]);
  float z1r = bf2f(Ere[ib + lane + 64]), z1i = bf2f(Eim[ib + lane + 64]);
  fft128(z0r, z0i, z1r, z1i, tws, twc, lane);
  int b = plane >> 6, ch = plane & 63;
  unsigned short* out = AB + ((long)(b*128 + 64 + ch)) * S + row*128;
  int k = __brev(lane) >> 25;
  ushort2 v;
  v.x = f2bf(sqrtf(z0r*z0r + z0i*z0i) * (1.0f/16384.0f));
  v.y = f2bf(sqrtf(z1r*z1r + z1i*z1i) * (1.0f/16384.0f));
  *(ushort2*)(out + k) = v;
}

// of -> AB channels [0,64)  (bf16 in, bf16 out, transposed store)
__global__ __launch_bounds__(256) void ifft_rows_abs_ofT_kernel(
    const unsigned short* __restrict__ Ere, const unsigned short* __restrict__ Eim,
    unsigned short* __restrict__ AB){
  __shared__ float T[128][17];
  int plane = blockIdx.y;       // b*64 + h*8 + c
  int r0 = blockIdx.x * 16;     // k1 base
  int wv = threadIdx.x >> 6, lane = threadIdx.x & 63;
  float tws[8], twc[8];
  fft128_mk_tw(tws, twc, 1.0f, lane);
  #pragma unroll
  for (int i = 0; i < 4; i++){
    int rl = wv*4 + i;
    int row = r0 + rl;
    long ib = (long)plane*S + row*128;
    float z0r = bf2f(Ere[ib + lane]), z0i = bf2f(Eim[ib + lane]);
    float z1r = bf2f(Ere[ib + lane + 64]), z1i = bf2f(Eim[ib + lane + 64]);
    fft128(z0r, z0i, z1r, z1i, tws, twc, lane);
    int k = __brev(lane) >> 25;
    T[k][rl]     = sqrtf(z0r*z0r + z0i*z0i) * (1.0f/16384.0f);
    T[k + 1][rl] = sqrtf(z1r*z1r + z1i*z1i) * (1.0f/16384.0f);
  }
  __syncthreads();
  int b = plane >> 6, ch = plane & 63;
  unsigned short* out = AB + ((long)(b*128 + ch)) * S + r0;
  #pragma unroll
  for (int i = 0; i < 8; i++){
    int idx = threadIdx.x + i*256;
    int k2 = idx >> 4, rl = idx & 15;
    out[(long)k2*128 + rl] = f2bf(T[k2][rl]);
  }
}

// ---------------- attention stats (bf16 f) ----------------
__global__ __launch_bounds__(256) void gram_part_kernel(
    const unsigned short* __restrict__ Dre, const unsigned short* __restrict__ Dim,
    float* __restrict__ PART){
  int bh = blockIdx.x, slab = blockIdx.y;
  long base = (long)bh * 8 * S;
  int n0 = slab * 2048;
  float accr[36], acci[36], nsq[8];
  #pragma unroll
  for (int i = 0; i < 36; i++){ accr[i] = 0.f; acci[i] = 0.f; }
  #pragma unroll
  for (int i = 0; i < 8; i++) nsq[i] = 0.f;
  for (int it = 0; it < 8; it++){
    int n = n0 + it*256 + threadIdx.x;
    float xr[8], xi[8];
    #pragma unroll
    for (int c = 0; c < 8; c++){
      xr[c] = bf2f(Dre[base + (long)c*S + n]);
      xi[c] = bf2f(Dim[base + (long)c*S + n]);
      nsq[c] += xr[c]*xr[c] + xi[c]*xi[c];
    }
    int t = 0;
    #pragma unroll
    for (int c = 0; c < 8; c++)
      #pragma unroll
      for (int d = c; d < 8; d++){
        accr[t] += xr[c]*xr[d] - xi[c]*xi[d];
        acci[t] += xr[c]*xi[d] + xi[c]*xr[d];
        t++;
      }
  }
  __shared__ float red[4][80];
  int wv = threadIdx.x >> 6, lane = threadIdx.x & 63;
  #pragma unroll
  for (int i = 0; i < 80; i++){
    float v = (i < 36) ? accr[i] : (i < 72) ? acci[i - 36] : nsq[i - 72];
    #pragma unroll
    for (int o = 32; o; o >>= 1) v += __shfl_xor(v, o, 64);
    if (lane == 0) red[wv][i] = v;
  }
  __syncthreads();
  if (threadIdx.x < 80){
    int i = threadIdx.x;
    PART[(long)(bh*8 + slab)*80 + i] = red[0][i] + red[1][i] + red[2][i] + red[3][i];
  }
}

__global__ void attn2f_kernel(const float* __restrict__ PART,
    const float* __restrict__ temp, float* __restrict__ ATT2){
  __shared__ float ssum[80];
  __shared__ float sar[64], sai[64];
  int bh = blockIdx.x;
  int t = threadIdx.x;
  if (t < 80){
    float s = 0.f;
    for (int i = 0; i < 8; i++) s += PART[(long)(bh*8 + i)*80 + t];
    ssum[t] = s;
  }
  __syncthreads();
  if (t >= 64) return;
  int lane = t;
  int c = lane >> 3, d = lane & 7;
  int lo = min(c, d), hi = max(c, d);
  int t2 = lo*8 - lo*(lo - 1)/2 + (hi - lo);
  float nnc = fmaxf(sqrtf(ssum[72 + c]), 1e-12f);
  float nnd = fmaxf(sqrtf(ssum[72 + d]), 1e-12f);
  float inv = temp[bh & 7] / (nnc * nnd);
  float ar = ssum[t2] * inv, ai = ssum[36 + t2] * inv;
  float m = ar;
  m = fmaxf(m, __shfl_xor(m, 1, 64)); m = fmaxf(m, __shfl_xor(m, 2, 64)); m = fmaxf(m, __shfl_xor(m, 4, 64));
  float e = __expf(ar - m);
  float su = e;
  su += __shfl_xor(su, 1, 64); su += __shfl_xor(su, 2, 64); su += __shfl_xor(su, 4, 64);
  ar = e / su;
  m = ai;
  m = fmaxf(m, __shfl_xor(m, 1, 64)); m = fmaxf(m, __shfl_xor(m, 2, 64)); m = fmaxf(m, __shfl_xor(m, 4, 64));
  e = __expf(ai - m);
  su = e;
  su += __shfl_xor(su, 1, 64); su += __shfl_xor(su, 2, 64); su += __shfl_xor(su, 4, 64);
  ai = e / su;
  sar[lane] = ar; sai[lane] = ai;
  __syncthreads();
  const float ct[8] = {1.f, 0.70710678f, 0.f, -0.70710678f, -1.f, -0.70710678f, 0.f, 0.70710678f};
  const float st[8] = {0.f, 0.70710678f, 1.f, 0.70710678f, 0.f, -0.70710678f, -1.f, -0.70710678f};
  int cp = c;
  float sr = 0.f, si = 0.f;
  #pragma unroll
  for (int cc = 0; cc < 8; cc++){
    int k = (cc * cp) & 7;
    float a = sar[cc*8 + d], b2 = sai[cc*8 + d];
    sr += ct[k]*a - st[k]*b2;
    si += ct[k]*b2 + st[k]*a;
  }
  float2 v; v.x = sr * 0.125f; v.y = si * 0.125f;
  ((float2*)ATT2)[bh*64 + lane] = v;
}

// bf16 in/out, ushort4 vectorized
__global__ __launch_bounds__(256) void apply_attn_kernel(
    const unsigned short* __restrict__ Dre, const unsigned short* __restrict__ Dim,
    const float* __restrict__ ATT2,
    unsigned short* __restrict__ Ere, unsigned short* __restrict__ Eim){
  int bh = blockIdx.y;
  int px = blockIdx.x*1024 + (threadIdx.x & 63)*4 + (threadIdx.x >> 6)*256;
  long base = (long)bh * 8 * S + px;
  float4 ar[8], ai[8];
  #pragma unroll
  for (int i = 0; i < 8; i++){
    ar[i].x = ar[i].y = ar[i].z = ar[i].w = 0.f;
    ai[i].x = ai[i].y = ai[i].z = ai[i].w = 0.f;
  }
  #pragma unroll
  for (int d = 0; d < 8; d++){
    ushort4 ur = *(const ushort4*)(Dre + base + (long)d*S);
    ushort4 ui = *(const ushort4*)(Dim + base + (long)d*S);
    float4 xr, xi;
    xr.x = bf2f(ur.x); xr.y = bf2f(ur.y); xr.z = bf2f(ur.z); xr.w = bf2f(ur.w);
    xi.x = bf2f(ui.x); xi.y = bf2f(ui.y); xi.z = bf2f(ui.z); xi.w = bf2f(ui.w);
    #pragma unroll
    for (int cp = 0; cp < 8; cp++){
      float wr = ATT2[bh*128 + (cp*8 + d)*2];
      float wi = ATT2[bh*128 + (cp*8 + d)*2 + 1];
      ar[cp].x += wr*xr.x - wi*xi.x;  ai[cp].x += wr*xi.x + wi*xr.x;
      ar[cp].y += wr*xr.y - wi*xi.y;  ai[cp].y += wr*xi.y + wi*xr.y;
      ar[cp].z += wr*xr.z - wi*xi.z;  ai[cp].z += wr*xi.z + wi*xr.z;
      ar[cp].w += wr*xr.w - wi*xi.w;  ai[cp].w += wr*xi.w + wi*xr.w;
    }
  }
  #pragma unroll
  for (int cp = 0; cp < 8; cp++){
    ushort4 vr, vi;
    vr.x = f2bf(ar[cp].x); vr.y = f2bf(ar[cp].y); vr.z = f2bf(ar[cp].z); vr.w = f2bf(ar[cp].w);
    vi.x = f2bf(ai[cp].x); vi.y = f2bf(ai[cp].y); vi.z = f2bf(ai[cp].z); vi.w = f2bf(ai[cp].w);
    *(ushort4*)(Ere + base + (long)cp*S) = vr;
    *(ushort4*)(Eim + base + (long)cp*S) = vi;
  }
}

// gate hidden: H[b][j][px] = relu(bn(wa_j . f.real))  (bf16 f)
__global__ __launch_bounds__(256) void gateh_kernel(const unsigned short* __restrict__ Dre,
    const float* __restrict__ wa, const float* __restrict__ sbwa, float* __restrict__ H){
  int b = blockIdx.y;
  int px = blockIdx.x*256 + threadIdx.x;
  long base = (long)b * 64 * S + px;
  float h0 = 0.f, h1 = 0.f, h2 = 0.f, h3 = 0.f;
  for (int ci = 0; ci < 64; ci++){
    float x = bf2f(Dre[base + (long)ci*S]);
    h0 += wa[ci]*x; h1 += wa[64 + ci]*x; h2 += wa[128 + ci]*x; h3 += wa[192 + ci]*x;
  }
  long ob = (long)b * 4 * S + px;
  H[ob]       = fmaxf(h0*sbwa[0] + sbwa[4], 0.f);
  H[ob + S]   = fmaxf(h1*sbwa[1] + sbwa[5], 0.f);
  H[ob + 2*S] = fmaxf(h2*sbwa[2] + sbwa[6], 0.f);
  H[ob + 3*S] = fmaxf(h3*sbwa[3] + sbwa[7], 0.f);
}

// ---------------- small kernels ----------------
__global__ __launch_bounds__(256) void mean_kernel(const float* __restrict__ A, float* __restrict__ M){
  int p = blockIdx.x;
  long base = (long)p * S;
  float s = 0.f;
  for (int n = threadIdx.x; n < S; n += 256) s += A[base + n];
  #pragma unroll
  for (int o = 32; o; o >>= 1) s += __shfl_xor(s, o, 64);
  __shared__ float sm[4];
  if ((threadIdx.x & 63) == 0) sm[threadIdx.x >> 6] = s;
  __syncthreads();
  if (threadIdx.x == 0) M[p] = (sm[0] + sm[1] + sm[2] + sm[3]) * (1.0f/16384.0f);
}

__global__ void c5_kernel(const float* __restrict__ W5, const float* __restrict__ sb5,
    const float* __restrict__ M, float* __restrict__ C5){
  int t = threadIdx.x;
  if (t >= 256) return;
  int b = t >> 6, co = t & 63;
  float s = 0.f;
  for (int ci = 0; ci < 128; ci++) s += W5[co*128 + ci] * M[b*128 + ci];
  C5[t] = fmaxf(s * sb5[co] + sb5[64 + co], 0.f);
}

__global__ void beff_kernel(const float* __restrict__ WF, const float* __restrict__ sbf,
    const float* __restrict__ C5, float* __restrict__ BEFF){
  int t = threadIdx.x;
  if (t >= 256) return;
  int b = t >> 6, co = t & 63;
  float s = 0.f;
  for (int j = 0; j < 64; j++) s += WF[co*320 + 256 + j] * C5[b*64 + j];
  BEFF[t] = s * sbf[co] + sbf[64 + co];
}

// output is FLOAT32 — write float4
__global__ __launch_bounds__(256) void ob_kernel(const float* __restrict__ Tin,
    const float* __restrict__ wob, const float* __restrict__ bob, float* __restrict__ out){
  int b = blockIdx.y;
  int px = blockIdx.x*1024 + (threadIdx.x & 63)*4 + (threadIdx.x >> 6)*256;
  float b0 = bob[0];
  float4 a; a.x = b0; a.y = b0; a.z = b0; a.w = b0;
  for (int ci = 0; ci < 32; ci++){
    float4 v = *(const float4*)(Tin + ((long)b*32 + ci)*S + px);
    float w = wob[ci];
    a.x += w*v.x; a.y += w*v.y; a.z += w*v.z; a.w += w*v.w;
  }
  *(float4*)(out + (long)b*S + px) = a;
}

// ---------------- launch ----------------
extern "C" void kernel_launch(void* const* d_in, const int* in_sizes, int n_in,
                              void* d_out, int out_size, void* d_ws, size_t ws_size,
                              hipStream_t stream){
  float* ws = (float*)d_ws;
  Ptrs P;
  for (int i = 0; i < 43 && i < n_in; i++) P.p[i] = (const float*)d_in[i];
  float* out = (float*)d_out;

  float* A   = ws + O_A;          // fp32 xd (consumed by mean/c1 before branches)
  float* FIN = ws + O_FIN;
  float* CC  = ws + O_CC;
  float* G   = ws + O_G;
  float* H   = ws + O_H;

  unsigned short* DRE16 = (unsigned short*)(ws + O_DRE);
  unsigned short* DIM16 = (unsigned short*)(ws + O_DIMG);
  unsigned short* ERE16 = (unsigned short*)(ws + O_ERE);
  unsigned short* EIM16 = (unsigned short*)(ws + O_EIM);
  unsigned short* AB    = (unsigned short*)(ws + O_A);   // bf16 of|ol, overlays xd after c1

  unsigned short* XT  = (unsigned short*)(ws + O_DRE);   // conv_dc input (pre-FFT)
  unsigned short* WHd = (unsigned short*)(ws + O_CC);
  unsigned short* WLd = (unsigned short*)(ws + O_CC + 147456);
  unsigned short* WB  = (unsigned short*)(ws + O_WB);
  unsigned short* WP  = (unsigned short*)(ws + O_WP);
  unsigned short* XP  = (unsigned short*)(ws + O_ERE);   // dil/oa input (pre-FFT per branch)

  prep_sb_kernel<<<dim3(9), dim3(256), 0, stream>>>(P, ws);
  xpad_kernel<<<dim3(130, 4), dim3(256), 0, stream>>>(P.p[0], XT);
  wt_kernel<<<dim3(128), dim3(256), 0, stream>>>(P.p[1], WHd, WLd);
  wtg_kernel<<<dim3(16, 4), dim3(256), 0, stream>>>(P, WB);
  wtp_kernel<<<dim3(8, 3), dim3(256), 0, stream>>>(P, WP);

  conv3x3_mfma_kernel<1,8,64><<<dim3(1024), dim3(256), 0, stream>>>(
      XT, WHd, WLd, ws + O_SBDC, A);

  mean_kernel<<<dim3(512), dim3(256), 0, stream>>>(A, ws + O_M);
  c5_kernel<<<dim3(1), dim3(256), 0, stream>>>(P.p[21], ws + O_SB5, ws + O_M, ws + O_C5);
  beff_kernel<<<dim3(1), dim3(256), 0, stream>>>(P.p[33], ws + O_SBF, ws + O_C5, ws + O_BEFF);

  // c1 -> FIN channels [0,64)  (MFMA, fp32 in)
  conv1x1_mfma_kernel<0,4,0><<<dim3(512), dim3(256), 0, stream>>>(
      A, 128*S, WP, WP + 8192, ws + O_SB1, nullptr, nullptr, 0, FIN, 256*S);

  for (int k = 0; k < 3; k++){
    const float* sb = ws + (k == 0 ? O_SB2 : k == 1 ? O_SB3 : O_SB4);
    const float* in2 = (k == 0) ? nullptr : FIN + (long)(64*k)*S;
    unsigned short* wh = WB + (k == 0 ? 0 : k == 1 ? 73728 : 147456);
    if (k == 0){
      xpad64_kernel<3><<<dim3(134, 4), dim3(256), 0, stream>>>(FIN, in2, 256*S, XP);
      conv3x3_mfma_kernel<3,2,64><<<dim3(512), dim3(256), 0, stream>>>(
          XP, wh, wh + 36864, sb, CC);
    } else if (k == 1){
      xpad64_kernel<5><<<dim3(138, 4), dim3(256), 0, stream>>>(FIN, in2, 256*S, XP);
      conv3x3_mfma_kernel<5,2,64><<<dim3(512), dim3(256), 0, stream>>>(
          XP, wh, wh + 36864, sb, CC);
    } else {
      xpad64_kernel<7><<<dim3(142, 4), dim3(256), 0, stream>>>(FIN, in2, 256*S, XP);
      conv3x3_mfma_kernel<7,2,64><<<dim3(512), dim3(256), 0, stream>>>(
          XP, wh, wh + 36864, sb, CC);
    }

    // f = fft2(c) -> bf16
    fft_rows_fwd_kernel<<<dim3(8192), dim3(256), 0, stream>>>(CC, DRE16, DIM16);
    fft_cols_kernel<0><<<dim3(8, 256), dim3(256), 0, stream>>>(
        DRE16, DIM16, DRE16, DIM16, nullptr, nullptr, nullptr);
    // attention stats
    gram_part_kernel<<<dim3(32, 8), dim3(256), 0, stream>>>(DRE16, DIM16, ws + O_PART);
    attn2f_kernel<<<dim3(32), dim3(128), 0, stream>>>(ws + O_PART, P.p[25], ws + O_ATT2);
    // gate hidden (4 ch) from f.real
    gateh_kernel<<<dim3(64, 4), dim3(256), 0, stream>>>(DRE16, P.p[27], ws + O_SBWA, H);
    // ol = |ifft2(sigmoid(wb.h+bwb) * f)| -> AB channels [64,128)
    fft_cols_kernel<1><<<dim3(8, 256), dim3(256), 0, stream>>>(
        DRE16, DIM16, ERE16, EIM16, H, P.p[31], P.p[32]);
    ifft_rows_abs_ol_kernel<<<dim3(8192), dim3(256), 0, stream>>>(ERE16, EIM16, AB);
    // of = |ifft_{c,n}(attn @ qkv)| -> AB channels [0,64)
    apply_attn_kernel<<<dim3(16, 32), dim3(256), 0, stream>>>(DRE16, DIM16, ws + O_ATT2, ERE16, EIM16);
    fft_cols_kernel<2><<<dim3(8, 256), dim3(256), 0, stream>>>(
        ERE16, EIM16, ERE16, EIM16, nullptr, nullptr, nullptr);
    ifft_rows_abs_ofT_kernel<<<dim3(8, 256), dim3(256), 0, stream>>>(ERE16, EIM16, AB);
    // F_k = w_po @ concat(of, ol) + c  (MFMA, bf16 in)
    conv1x1_mfma_kernel<1,4,1><<<dim3(512), dim3(256), 0, stream>>>(
        AB, 128*S, WP + 16384, WP + 24576, nullptr, nullptr, CC, 64*S,
        FIN + (long)(64*(k + 1))*S, 256*S);
  }

  // fused = bn_relu(w_f @ concat(c1,F2,F3,F4) + bias_eff(c5)) -> CC  (MFMA)
  conv1x1_mfma_kernel<2,8,0><<<dim3(512), dim3(256), 0, stream>>>(
      FIN, 256*S, WP + 32768, WP + 49152, ws + O_SBF, ws + O_BEFF, nullptr, 0, CC, 64*S);
  xpad64_kernel<1><<<dim3(130, 4), dim3(256), 0, stream>>>(CC, nullptr, 64*S, XP);
  conv3x3_mfma_kernel<1,2,32><<<dim3(512), dim3(256), 0, stream>>>(
      XP, WB + 221184, WB + 221184 + 18432, ws + O_SBOA, G);
  ob_kernel<<<dim3(16, 4), dim3(256), 0, stream>>>(G, P.p[41], P.p[42], out);
}